// Round 1
// baseline (7252.893 us; speedup 1.0000x reference)
//
#include <hip/hip_runtime.h>
#include <math.h>

#define NN 50000
#define NE 1600000
#define AVG_DEG_LOG 3.4965075614664802f

__device__ __forceinline__ float lrelu(float x){ return x > 0.f ? x : 0.2f*x; }

__device__ __forceinline__ void atomicMaxF(float* a, float v){
    if (v >= 0.f) atomicMax((int*)a, __float_as_int(v));
    else          atomicMin((unsigned int*)a, __float_as_uint(v));
}
__device__ __forceinline__ void atomicMinF(float* a, float v){
    if (v >= 0.f) atomicMin((int*)a, __float_as_int(v));
    else          atomicMax((unsigned int*)a, __float_as_uint(v));
}

// ---------------- init ----------------
__global__ void k_init(float* pna_sum, float* pna_sumsq, float* pna_min, float* pna_max,
                       float* cnt, float* easum){
    int i = blockIdx.x*blockDim.x + threadIdx.x;
    if (i < NN*5){ pna_sum[i]=0.f; pna_sumsq[i]=0.f; pna_min[i]=INFINITY; pna_max[i]=-INFINITY; }
    if (i < NN){ cnt[i]=0.f; easum[i]=0.f; }
}

// ---------------- PNA edge pass ----------------
__global__ void k_pna_edge(const float* __restrict__ x, const int* __restrict__ src,
                           const int* __restrict__ dst, const float* __restrict__ ea,
                           const float* __restrict__ W_ee, const float* __restrict__ b_ee,
                           const float* __restrict__ W_pre, const float* __restrict__ b_pre,
                           float* pna_sum, float* pna_sumsq, float* pna_min, float* pna_max,
                           float* cnt, float* easum){
    int e = blockIdx.x*blockDim.x + threadIdx.x;
    if (e >= NE) return;
    int s = src[e], d = dst[e];
    float w = ea[e];
    float h[15];
    #pragma unroll
    for (int j=0;j<5;j++) h[j]    = x[d*5+j];
    #pragma unroll
    for (int j=0;j<5;j++) h[5+j]  = x[s*5+j];
    #pragma unroll
    for (int j=0;j<5;j++) h[10+j] = w*W_ee[j] + b_ee[j];
    #pragma unroll
    for (int j=0;j<5;j++){
        float m = b_pre[j];
        #pragma unroll
        for (int k=0;k<15;k++) m += h[k]*W_pre[k*5+j];
        atomicAdd(&pna_sum[d*5+j], m);
        atomicAdd(&pna_sumsq[d*5+j], m*m);
        atomicMinF(&pna_min[d*5+j], m);
        atomicMaxF(&pna_max[d*5+j], m);
    }
    atomicAdd(&cnt[d], 1.0f);
    atomicAdd(&easum[d], w);
}

// ------------- PNA node finalize + GAT1 prep -------------
__global__ void k_pna_node(const float* __restrict__ x, const float* __restrict__ pna_sum,
                           const float* __restrict__ pna_sumsq, const float* __restrict__ pna_min,
                           const float* __restrict__ pna_max, const float* __restrict__ cnt,
                           float* ea_mean,
                           const float* __restrict__ W_post, const float* __restrict__ b_post,
                           const float* __restrict__ W_pna, const float* __restrict__ b_pna,
                           const float* __restrict__ W1l, const float* __restrict__ b1l,
                           const float* __restrict__ W1r, const float* __restrict__ b1r,
                           const float* __restrict__ W1e, const float* __restrict__ att1,
                           float* nf0, float* xl1, float* xr1,
                           float* aself, float* nmax, float* nden, float* acc1){
    int i = blockIdx.x*blockDim.x + threadIdx.x;
    if (i >= NN) return;
    float c  = cnt[i];
    float cc = fmaxf(c, 1.0f);
    float out[65];
    #pragma unroll
    for (int j=0;j<5;j++) out[j] = x[i*5+j];
    float amp = logf(cc + 1.0f) * (1.0f/AVG_DEG_LOG);
    #pragma unroll
    for (int j=0;j<5;j++){
        float mean = pna_sum[i*5+j]/cc;
        float msq  = pna_sumsq[i*5+j]/cc;
        float sd   = sqrtf(fmaxf(msq - mean*mean, 0.f) + 1e-5f);
        float mnv  = (c > 0.f) ? pna_min[i*5+j] : 0.f;
        float mxv  = (c > 0.f) ? pna_max[i*5+j] : 0.f;
        out[5+j]=mean; out[10+j]=mnv; out[15+j]=mxv; out[20+j]=sd;
    }
    #pragma unroll
    for (int j=0;j<20;j++){ out[25+j] = out[5+j]*amp; out[45+j] = out[5+j]/amp; }
    float t[8];
    #pragma unroll
    for (int o=0;o<8;o++){
        float a = b_post[o];
        for (int k=0;k<65;k++) a += out[k]*W_post[k*8+o];
        t[o]=a;
    }
    float nf[8];
    #pragma unroll
    for (int o=0;o<8;o++){
        float a = b_pna[o];
        #pragma unroll
        for (int k=0;k<8;k++) a += t[k]*W_pna[k*8+o];
        nf[o]=a; nf0[i*8+o]=a;
    }
    float eam = ea_mean[i]/cc;   // buffer held easum
    ea_mean[i] = eam;
    // GAT1 node transforms
    float vl[16], vr[16];
    #pragma unroll
    for (int o=0;o<16;o++){
        float a=b1l[o], b=b1r[o];
        #pragma unroll
        for (int k=0;k<8;k++){ a += nf[k]*W1l[k*16+o]; b += nf[k]*W1r[k*16+o]; }
        vl[o]=a; vr[o]=b; xl1[i*16+o]=a; xr1[i*16+o]=b;
    }
    #pragma unroll
    for (int h=0;h<4;h++){
        float a=0.f;
        #pragma unroll
        for (int c2=0;c2<4;c2++){
            float mm = lrelu(vl[h*4+c2]+vr[h*4+c2]+eam*W1e[h*4+c2]);
            a += mm*att1[h*4+c2];
        }
        aself[i*4+h]=a; nmax[i*4+h]=a; nden[i*4+h]=0.f;
    }
    #pragma unroll
    for (int o=0;o<16;o++) acc1[i*16+o]=0.f;
}

// ------------- GATv2 edge pass A: alpha -> atomicMax per (dst,h) -------------
template<int C>
__global__ void k_gat_edgeA(const int* __restrict__ src, const int* __restrict__ dst,
                            const float* __restrict__ ea,
                            const float* __restrict__ xl, const float* __restrict__ xr,
                            const float* __restrict__ We, const float* __restrict__ att,
                            float* nmax){
    int e = blockIdx.x*blockDim.x + threadIdx.x;
    if (e >= NE) return;
    int s = src[e], d = dst[e];
    float w = ea[e];
    #pragma unroll
    for (int h=0;h<4;h++){
        float a=0.f;
        #pragma unroll
        for (int c=0;c<C;c++){
            int idx = h*C+c;
            float mm = lrelu(xl[s*4*C+idx] + xr[d*4*C+idx] + w*We[idx]);
            a += mm*att[idx];
        }
        atomicMaxF(&nmax[d*4+h], a);
    }
}

// ------------- GATv2 edge pass B: exp + accumulate -------------
template<int C>
__global__ void k_gat_edgeB(const int* __restrict__ src, const int* __restrict__ dst,
                            const float* __restrict__ ea,
                            const float* __restrict__ xl, const float* __restrict__ xr,
                            const float* __restrict__ We, const float* __restrict__ att,
                            const float* __restrict__ nmax, float* nden, float* acc){
    int e = blockIdx.x*blockDim.x + threadIdx.x;
    if (e >= NE) return;
    int s = src[e], d = dst[e];
    float w = ea[e];
    #pragma unroll
    for (int h=0;h<4;h++){
        float a=0.f;
        float xls[C];
        #pragma unroll
        for (int c=0;c<C;c++){
            int idx = h*C+c;
            float v = xl[s*4*C+idx];
            xls[c]=v;
            float mm = lrelu(v + xr[d*4*C+idx] + w*We[idx]);
            a += mm*att[idx];
        }
        float el = expf(a - nmax[d*4+h]);
        #pragma unroll
        for (int c=0;c<C;c++) atomicAdd(&acc[d*4*C + h*C+c], el*xls[c]);
        atomicAdd(&nden[d*4+h], el);
    }
}

// ------------- GAT1 node finalize + GAT2 prep -------------
__global__ void k_gat1_node(const float* __restrict__ ea_mean, const float* __restrict__ xl1,
                            const float* __restrict__ aself1, const float* __restrict__ nmax1,
                            const float* __restrict__ nden1, const float* __restrict__ acc1,
                            const float* __restrict__ bias1,
                            const float* __restrict__ W2l, const float* __restrict__ b2l,
                            const float* __restrict__ W2r, const float* __restrict__ b2r,
                            const float* __restrict__ W2e, const float* __restrict__ att2,
                            float* xl2, float* xr2,
                            float* aself2, float* nmax2, float* nden2, float* acc2){
    int i = blockIdx.x*blockDim.x + threadIdx.x;
    if (i >= NN) return;
    float nf1[16];
    #pragma unroll
    for (int h=0;h<4;h++){
        float es  = expf(aself1[i*4+h] - nmax1[i*4+h]);
        float den = nden1[i*4+h] + es + 1e-16f;
        #pragma unroll
        for (int c=0;c<4;c++){
            int idx=h*4+c;
            float a = acc1[i*16+idx] + es*xl1[i*16+idx];
            float v = a/den + bias1[idx];
            nf1[idx] = v>0.f ? v : 0.f;
        }
    }
    float eam = ea_mean[i];
    float vl[32], vr[32];
    #pragma unroll
    for (int o=0;o<32;o++){
        float a=b2l[o], b=b2r[o];
        #pragma unroll
        for (int k=0;k<16;k++){ a += nf1[k]*W2l[k*32+o]; b += nf1[k]*W2r[k*32+o]; }
        vl[o]=a; vr[o]=b; xl2[i*32+o]=a; xr2[i*32+o]=b;
    }
    #pragma unroll
    for (int h=0;h<4;h++){
        float a=0.f;
        #pragma unroll
        for (int c=0;c<8;c++){
            int idx=h*8+c;
            float mm = lrelu(vl[idx]+vr[idx]+eam*W2e[idx]);
            a += mm*att2[idx];
        }
        aself2[i*4+h]=a; nmax2[i*4+h]=a; nden2[i*4+h]=0.f;
    }
    #pragma unroll
    for (int o=0;o<32;o++) acc2[i*32+o]=0.f;
}

// ------------- GAT2 node finalize + final MLP + softmax init -------------
__global__ void k_gat2_node(const float* __restrict__ aself2, const float* __restrict__ nmax2,
                            const float* __restrict__ nden2, const float* __restrict__ acc2,
                            const float* __restrict__ xl2,
                            const float* __restrict__ bias2,
                            const float* __restrict__ Wn, const float* __restrict__ bn,
                            float* nff, float* smax, float* sden){
    int i = blockIdx.x*blockDim.x + threadIdx.x;
    if (i >= NN) return;
    float nf2[32];
    #pragma unroll
    for (int h=0;h<4;h++){
        float es  = expf(aself2[i*4+h] - nmax2[i*4+h]);
        float den = nden2[i*4+h] + es + 1e-16f;
        #pragma unroll
        for (int c=0;c<8;c++){
            int idx=h*8+c;
            float a = acc2[i*32+idx] + es*xl2[i*32+idx];
            float v = a/den + bias2[idx];
            nf2[idx] = v>0.f ? v : 0.f;
        }
    }
    #pragma unroll
    for (int j=0;j<32;j++){
        float a = bn[j];
        #pragma unroll
        for (int k=0;k<32;k++) a += nf2[k]*Wn[k*32+j];
        nff[i*32+j] = a>0.f ? a : 0.f;
    }
    smax[i*2]=-INFINITY; smax[i*2+1]=-INFINITY; sden[i*2]=0.f; sden[i*2+1]=0.f;
}

// ------------- scores pass A: cols 0,1 + max per src -------------
__global__ void k_scA(const int* __restrict__ src, const int* __restrict__ dst,
                      const float* __restrict__ ea, const float* __restrict__ nff,
                      const float* __restrict__ We_fc, const float* __restrict__ be_fc,
                      float* sc, float* smax){
    int e = blockIdx.x*blockDim.x + threadIdx.x;
    if (e >= NE) return;
    int s = src[e], d = dst[e];
    float w = ea[e];
    float a0 = be_fc[0] + w*We_fc[0];
    float a1 = be_fc[1] + w*We_fc[1];
    #pragma unroll
    for (int k=0;k<32;k++){ float v=nff[s*32+k]; a0 += v*We_fc[(1+k)*32+0]; a1 += v*We_fc[(1+k)*32+1]; }
    #pragma unroll
    for (int k=0;k<32;k++){ float v=nff[d*32+k]; a0 += v*We_fc[(33+k)*32+0]; a1 += v*We_fc[(33+k)*32+1]; }
    sc[(size_t)e*2]=a0; sc[(size_t)e*2+1]=a1;
    atomicMaxF(&smax[s*2], a0);
    atomicMaxF(&smax[s*2+1], a1);
}

// ------------- scores pass B: exp + denom per src -------------
__global__ void k_scB(const int* __restrict__ src, float* sc,
                      const float* __restrict__ smax, float* sden){
    int e = blockIdx.x*blockDim.x + threadIdx.x;
    if (e >= NE) return;
    int s = src[e];
    float e0 = expf(sc[(size_t)e*2]   - smax[s*2]);
    float e1 = expf(sc[(size_t)e*2+1] - smax[s*2+1]);
    sc[(size_t)e*2]=e0; sc[(size_t)e*2+1]=e1;
    atomicAdd(&sden[s*2], e0);
    atomicAdd(&sden[s*2+1], e1);
}

// ------------- scores pass C: full 32-col GEMM + final write -------------
__global__ void k_scC(const int* __restrict__ src, const int* __restrict__ dst,
                      const float* __restrict__ ea, const float* __restrict__ nff,
                      const float* __restrict__ We_fc, const float* __restrict__ be_fc,
                      const float* __restrict__ sc, const float* __restrict__ sden,
                      float* __restrict__ out){
    __shared__ float sW[65*32];
    __shared__ float sB[32];
    for (int t=threadIdx.x; t<65*32; t+=blockDim.x) sW[t]=We_fc[t];
    if (threadIdx.x < 32) sB[threadIdx.x]=be_fc[threadIdx.x];
    __syncthreads();
    int e = blockIdx.x*blockDim.x + threadIdx.x;
    if (e >= NE) return;
    int s = src[e], d = dst[e];
    float w = ea[e];
    float o[32];
    #pragma unroll
    for (int j=0;j<32;j++) o[j] = sB[j] + w*sW[j];
    #pragma unroll
    for (int k=0;k<32;k++){
        float v = nff[s*32+k];
        #pragma unroll
        for (int j=0;j<32;j++) o[j] += v*sW[(1+k)*32+j];
    }
    #pragma unroll
    for (int k=0;k<32;k++){
        float v = nff[d*32+k];
        #pragma unroll
        for (int j=0;j<32;j++) o[j] += v*sW[(33+k)*32+j];
    }
    o[0] = sc[(size_t)e*2]   / (sden[s*2]   + 1e-16f);
    o[1] = sc[(size_t)e*2+1] / (sden[s*2+1] + 1e-16f);
    float* op = out + (size_t)e*32;
    #pragma unroll
    for (int j=0;j<8;j++){
        float4 v4; v4.x=o[j*4]; v4.y=o[j*4+1]; v4.z=o[j*4+2]; v4.w=o[j*4+3];
        *(float4*)(op + j*4) = v4;
    }
}

extern "C" void kernel_launch(void* const* d_in, const int* in_sizes, int n_in,
                              void* d_out, int out_size, void* d_ws, size_t ws_size,
                              hipStream_t stream) {
    const float* x     = (const float*)d_in[0];
    const int*   ei    = (const int*)  d_in[1];
    const float* ea    = (const float*)d_in[2];
    const float* W_ee  = (const float*)d_in[3];  const float* b_ee  = (const float*)d_in[4];
    const float* W_pre = (const float*)d_in[5];  const float* b_pre = (const float*)d_in[6];
    const float* W_post= (const float*)d_in[7];  const float* b_post= (const float*)d_in[8];
    const float* W_pna = (const float*)d_in[9];  const float* b_pna = (const float*)d_in[10];
    const float* W1l   = (const float*)d_in[11]; const float* b1l   = (const float*)d_in[12];
    const float* W1r   = (const float*)d_in[13]; const float* b1r   = (const float*)d_in[14];
    const float* W1e   = (const float*)d_in[15]; const float* att1  = (const float*)d_in[16];
    const float* bias1 = (const float*)d_in[17];
    const float* W2l   = (const float*)d_in[18]; const float* b2l   = (const float*)d_in[19];
    const float* W2r   = (const float*)d_in[20]; const float* b2r   = (const float*)d_in[21];
    const float* W2e   = (const float*)d_in[22]; const float* att2  = (const float*)d_in[23];
    const float* bias2 = (const float*)d_in[24];
    const float* Wn    = (const float*)d_in[25]; const float* bn    = (const float*)d_in[26];
    const float* We_fc = (const float*)d_in[27]; const float* be_fc = (const float*)d_in[28];
    const int* src = ei;
    const int* dst = ei + NE;
    float* out = (float*)d_out;

    float* ws = (float*)d_ws;
    size_t o = 0;
    float* pna_sum   = ws+o; o += (size_t)NN*5;
    float* pna_sumsq = ws+o; o += (size_t)NN*5;
    float* pna_min   = ws+o; o += (size_t)NN*5;
    float* pna_max   = ws+o; o += (size_t)NN*5;
    float* cnt       = ws+o; o += NN;
    float* ea_mean   = ws+o; o += NN;        // holds easum first
    float* nf0       = ws+o; o += (size_t)NN*8;
    float* xl1       = ws+o; o += (size_t)NN*16;
    float* xr1       = ws+o; o += (size_t)NN*16;
    float* xl2       = ws+o; o += (size_t)NN*32;
    float* xr2       = ws+o; o += (size_t)NN*32;
    float* aself     = ws+o; o += (size_t)NN*4;
    float* nmax      = ws+o; o += (size_t)NN*4;
    float* nden      = ws+o; o += (size_t)NN*4;
    float* acc1      = ws+o; o += (size_t)NN*16;
    float* acc2      = ws+o; o += (size_t)NN*32;
    float* nff       = ws+o; o += (size_t)NN*32;
    float* smax      = ws+o; o += (size_t)NN*2;
    float* sden      = ws+o; o += (size_t)NN*2;
    float* sc        = ws+o; o += (size_t)NE*2;

    const int BS = 256;
    const int gridE = (NE + BS - 1)/BS;
    const int gridN = (NN + BS - 1)/BS;
    const int gridI = (NN*5 + BS - 1)/BS;

    k_init<<<gridI, BS, 0, stream>>>(pna_sum, pna_sumsq, pna_min, pna_max, cnt, ea_mean);
    k_pna_edge<<<gridE, BS, 0, stream>>>(x, src, dst, ea, W_ee, b_ee, W_pre, b_pre,
                                         pna_sum, pna_sumsq, pna_min, pna_max, cnt, ea_mean);
    k_pna_node<<<gridN, BS, 0, stream>>>(x, pna_sum, pna_sumsq, pna_min, pna_max, cnt, ea_mean,
                                         W_post, b_post, W_pna, b_pna,
                                         W1l, b1l, W1r, b1r, W1e, att1,
                                         nf0, xl1, xr1, aself, nmax, nden, acc1);
    k_gat_edgeA<4><<<gridE, BS, 0, stream>>>(src, dst, ea, xl1, xr1, W1e, att1, nmax);
    k_gat_edgeB<4><<<gridE, BS, 0, stream>>>(src, dst, ea, xl1, xr1, W1e, att1, nmax, nden, acc1);
    k_gat1_node<<<gridN, BS, 0, stream>>>(ea_mean, xl1, aself, nmax, nden, acc1, bias1,
                                          W2l, b2l, W2r, b2r, W2e, att2,
                                          xl2, xr2, aself, nmax, nden, acc2);
    k_gat_edgeA<8><<<gridE, BS, 0, stream>>>(src, dst, ea, xl2, xr2, W2e, att2, nmax);
    k_gat_edgeB<8><<<gridE, BS, 0, stream>>>(src, dst, ea, xl2, xr2, W2e, att2, nmax, nden, acc2);
    k_gat2_node<<<gridN, BS, 0, stream>>>(aself, nmax, nden, acc2, xl2, bias2, Wn, bn,
                                          nff, smax, sden);
    k_scA<<<gridE, BS, 0, stream>>>(src, dst, ea, nff, We_fc, be_fc, sc, smax);
    k_scB<<<gridE, BS, 0, stream>>>(src, sc, smax, sden);
    k_scC<<<gridE, BS, 0, stream>>>(src, dst, ea, nff, We_fc, be_fc, sc, sden, out);
}

// Round 2
// 810.980 us; speedup vs baseline: 8.9434x; 8.9434x over previous
//
#include <hip/hip_runtime.h>
#include <math.h>

#define NN 50000
#define NE 1600000
#define AVG_DEG_LOG 3.4965075614664802f

__device__ __forceinline__ float lrelu(float x){ return x > 0.f ? x : 0.2f*x; }
__device__ __forceinline__ float relu(float x){ return x > 0.f ? x : 0.f; }

// ---------------- zero degree counters ----------------
__global__ void k_zero(int* cnt_d, int* cnt_s){
    int i = blockIdx.x*blockDim.x + threadIdx.x;
    if (i < NN){ cnt_d[i]=0; cnt_s[i]=0; }
}

// ---------------- count degrees ----------------
__global__ void k_count(const int* __restrict__ src, const int* __restrict__ dst,
                        int* cnt_d, int* cnt_s){
    int e = blockIdx.x*blockDim.x + threadIdx.x;
    if (e >= NE) return;
    atomicAdd(&cnt_d[dst[e]], 1);
    atomicAdd(&cnt_s[src[e]], 1);
}

// ---------------- exclusive scan (single block, wave-scan) ----------------
__global__ __launch_bounds__(1024) void k_scan(const int* __restrict__ cnt_d, const int* __restrict__ cnt_s,
                                               int* off_d, int* cur_d, int* off_s, int* cur_s){
    __shared__ int wsums[16];
    __shared__ int carry_s;
    const int tid = threadIdx.x;
    const int lane = tid & 63;
    const int wv = tid >> 6;
    for (int pass = 0; pass < 2; ++pass){
        const int* cnt = pass ? cnt_s : cnt_d;
        int* off = pass ? off_s : off_d;
        int* cur = pass ? cur_s : cur_d;
        if (tid == 0) carry_s = 0;
        __syncthreads();
        for (int base = 0; base < NN; base += 4096){
            int i0 = base + tid*4;
            int v0 = (i0+0 < NN) ? cnt[i0+0] : 0;
            int v1 = (i0+1 < NN) ? cnt[i0+1] : 0;
            int v2 = (i0+2 < NN) ? cnt[i0+2] : 0;
            int v3 = (i0+3 < NN) ? cnt[i0+3] : 0;
            int tsum = v0+v1+v2+v3;
            int sc = tsum;
            for (int d = 1; d < 64; d <<= 1){
                int t = __shfl_up(sc, d, 64);
                if (lane >= d) sc += t;
            }
            if (lane == 63) wsums[wv] = sc;
            __syncthreads();
            int woff = 0;
            #pragma unroll
            for (int k = 0; k < 16; ++k) woff += (k < wv) ? wsums[k] : 0;
            int carry_in = carry_s;
            __syncthreads();
            if (tid == 1023) carry_s = carry_in + woff + sc;
            int excl = carry_in + woff + (sc - tsum);
            int e0 = excl, e1 = e0+v0, e2 = e1+v1, e3 = e2+v2;
            if (i0+0 < NN){ off[i0+0]=e0; cur[i0+0]=e0; }
            if (i0+1 < NN){ off[i0+1]=e1; cur[i0+1]=e1; }
            if (i0+2 < NN){ off[i0+2]=e2; cur[i0+2]=e2; }
            if (i0+3 < NN){ off[i0+3]=e3; cur[i0+3]=e3; }
            __syncthreads();
        }
        __syncthreads();
    }
}

// ---------------- scatter edges into buckets ----------------
__global__ void k_scatter(const int* __restrict__ src, const int* __restrict__ dst,
                          const float* __restrict__ ea,
                          int* cur_d, int* cur_s,
                          int* bktd_s, float* bktd_w, int* bkts_d, float* bkts_w){
    int e = blockIdx.x*blockDim.x + threadIdx.x;
    if (e >= NE) return;
    int s = src[e], d = dst[e];
    float w = ea[e];
    int p = atomicAdd(&cur_d[d], 1);
    bktd_s[p] = s; bktd_w[p] = w;
    int q = atomicAdd(&cur_s[s], 1);
    bkts_d[q] = d; bkts_w[q] = w;
}

// ---------------- PNA gather + finalize + GAT1 transforms (8 lanes/node) ----------------
__global__ __launch_bounds__(256) void k_pna(
    const float* __restrict__ x,
    const int* __restrict__ cnt_d, const int* __restrict__ off_d,
    const int* __restrict__ bktd_s, const float* __restrict__ bktd_w,
    const float* __restrict__ W_ee, const float* __restrict__ b_ee,
    const float* __restrict__ W_pre, const float* __restrict__ b_pre,
    const float* __restrict__ W_post, const float* __restrict__ b_post,
    const float* __restrict__ W_pna, const float* __restrict__ b_pna,
    const float* __restrict__ W1l, const float* __restrict__ b1l,
    const float* __restrict__ W1r, const float* __restrict__ b1r,
    float* __restrict__ xl1, float* __restrict__ xr1, float* __restrict__ ea_mean)
{
    __shared__ float sWpre[75], sWpost[520], sWpna[64], sW1l[128], sW1r[128];
    __shared__ float sbpre[5], sWee[5], sbee[5], sbpost[8], sbpna[8], sb1l[16], sb1r[16];
    for (int t=threadIdx.x; t<75;  t+=256) sWpre[t]=W_pre[t];
    for (int t=threadIdx.x; t<520; t+=256) sWpost[t]=W_post[t];
    for (int t=threadIdx.x; t<64;  t+=256) sWpna[t]=W_pna[t];
    for (int t=threadIdx.x; t<128; t+=256){ sW1l[t]=W1l[t]; sW1r[t]=W1r[t]; }
    if (threadIdx.x<5){ sbpre[threadIdx.x]=b_pre[threadIdx.x]; sWee[threadIdx.x]=W_ee[threadIdx.x]; sbee[threadIdx.x]=b_ee[threadIdx.x]; }
    if (threadIdx.x<8){ sbpost[threadIdx.x]=b_post[threadIdx.x]; sbpna[threadIdx.x]=b_pna[threadIdx.x]; }
    if (threadIdx.x<16){ sb1l[threadIdx.x]=b1l[threadIdx.x]; sb1r[threadIdx.x]=b1r[threadIdx.x]; }
    __syncthreads();
    int node = blockIdx.x*32 + (threadIdx.x>>3);
    if (node >= NN) return;
    int g = threadIdx.x & 7;
    float xd[5];
    #pragma unroll
    for (int k=0;k<5;k++) xd[k] = x[node*5+k];
    // fold x_dst and edge-encoder terms into per-node constants:
    // m[c] = cb[c] + w*c1v[c] + sum_k x_src[k]*Wpre[(5+k)*5+c]
    float cb[5], c1v[5];
    #pragma unroll
    for (int c=0;c<5;c++){
        float a = sbpre[c], b = 0.f;
        #pragma unroll
        for (int k=0;k<5;k++){
            a += xd[k]*sWpre[k*5+c];
            a += sbee[k]*sWpre[(10+k)*5+c];
            b += sWee[k]*sWpre[(10+k)*5+c];
        }
        cb[c]=a; c1v[c]=b;
    }
    int deg = cnt_d[node], base = off_d[node];
    float sum[5], ssq[5], mn[5], mx[5];
    #pragma unroll
    for (int c=0;c<5;c++){ sum[c]=0.f; ssq[c]=0.f; mn[c]=1e30f; mx[c]=-1e30f; }
    float wsum = 0.f;
    for (int j=g; j<deg; j+=8){
        int s = bktd_s[base+j];
        float w = bktd_w[base+j];
        wsum += w;
        float xs[5];
        #pragma unroll
        for (int k=0;k<5;k++) xs[k] = x[s*5+k];
        #pragma unroll
        for (int c=0;c<5;c++){
            float m = cb[c] + w*c1v[c];
            #pragma unroll
            for (int k=0;k<5;k++) m += xs[k]*sWpre[(5+k)*5+c];
            sum[c]+=m; ssq[c]+=m*m; mn[c]=fminf(mn[c],m); mx[c]=fmaxf(mx[c],m);
        }
    }
    #pragma unroll
    for (int st=1; st<8; st<<=1){
        #pragma unroll
        for (int c=0;c<5;c++){
            sum[c] += __shfl_xor(sum[c], st);
            ssq[c] += __shfl_xor(ssq[c], st);
            mn[c] = fminf(mn[c], __shfl_xor(mn[c], st));
            mx[c] = fmaxf(mx[c], __shfl_xor(mx[c], st));
        }
        wsum += __shfl_xor(wsum, st);
    }
    float c = (float)deg, cc = fmaxf(c, 1.f);
    float amp = __logf(cc+1.f) * (1.f/AVG_DEG_LOG);
    float feat[65];
    #pragma unroll
    for (int k=0;k<5;k++) feat[k]=xd[k];
    #pragma unroll
    for (int j=0;j<5;j++){
        float mean = sum[j]/cc, msq = ssq[j]/cc;
        float sd = sqrtf(fmaxf(msq - mean*mean, 0.f) + 1e-5f);
        feat[5+j]=mean;
        feat[10+j]= (deg>0)? mn[j] : 0.f;
        feat[15+j]= (deg>0)? mx[j] : 0.f;
        feat[20+j]=sd;
    }
    #pragma unroll
    for (int j=0;j<20;j++){ feat[25+j]=feat[5+j]*amp; feat[45+j]=feat[5+j]/amp; }
    // W_post: lane g computes output g
    float t = sbpost[g];
    #pragma unroll
    for (int k=0;k<65;k++) t += feat[k]*sWpost[k*8+g];
    float nf = sbpna[g];
    #pragma unroll
    for (int k=0;k<8;k++) nf += __shfl(t, k, 8) * sWpna[k*8+g];
    float nfk[8];
    #pragma unroll
    for (int k=0;k<8;k++) nfk[k] = __shfl(nf, k, 8);
    #pragma unroll
    for (int u=0;u<2;u++){
        int o = 2*g+u;
        float a=sb1l[o], b2=sb1r[o];
        #pragma unroll
        for (int k=0;k<8;k++){ a += nfk[k]*sW1l[k*16+o]; b2 += nfk[k]*sW1r[k*16+o]; }
        xl1[node*16+o]=a; xr1[node*16+o]=b2;
    }
    if (g==0) ea_mean[node] = wsum/cc;
}

// ---------------- GAT layer 1 gather (online softmax, self-loop as virtual edge) ----------------
__global__ __launch_bounds__(256) void k_gat1(
    const int* __restrict__ cnt_d, const int* __restrict__ off_d,
    const int* __restrict__ bktd_s, const float* __restrict__ bktd_w,
    const float* __restrict__ xl1, const float* __restrict__ xr1,
    const float* __restrict__ ea_mean,
    const float* __restrict__ We1, const float* __restrict__ att1, const float* __restrict__ bias1,
    const float* __restrict__ W2l, const float* __restrict__ b2l,
    const float* __restrict__ W2r, const float* __restrict__ b2r,
    float* __restrict__ xl2, float* __restrict__ xr2)
{
    __shared__ float sWe[16], sAtt[16], sBias[16], sW2l[512], sW2r[512], sb2l[32], sb2r[32];
    for (int t=threadIdx.x; t<512; t+=256){ sW2l[t]=W2l[t]; sW2r[t]=W2r[t]; }
    if (threadIdx.x<16){ sWe[threadIdx.x]=We1[threadIdx.x]; sAtt[threadIdx.x]=att1[threadIdx.x]; sBias[threadIdx.x]=bias1[threadIdx.x]; }
    if (threadIdx.x<32){ sb2l[threadIdx.x]=b2l[threadIdx.x]; sb2r[threadIdx.x]=b2r[threadIdx.x]; }
    __syncthreads();
    int node = blockIdx.x*32 + (threadIdx.x>>3);
    if (node >= NN) return;
    int g = threadIdx.x & 7;
    float xr[16];
    #pragma unroll
    for (int k=0;k<4;k++){
        float4 v = *(const float4*)(xr1 + node*16 + k*4);
        xr[k*4]=v.x; xr[k*4+1]=v.y; xr[k*4+2]=v.z; xr[k*4+3]=v.w;
    }
    int deg = cnt_d[node], base = off_d[node];
    float eam = ea_mean[node];
    float m[4], ss[4], acc[16];
    #pragma unroll
    for (int h=0;h<4;h++){ m[h]=-1e30f; ss[h]=0.f; }
    #pragma unroll
    for (int k=0;k<16;k++) acc[k]=0.f;
    for (int j=g; j<=deg; j+=8){
        bool selfe = (j==deg);
        int s   = selfe ? node : bktd_s[base+j];
        float w = selfe ? eam  : bktd_w[base+j];
        float xls[16];
        #pragma unroll
        for (int k=0;k<4;k++){
            float4 v = *(const float4*)(xl1 + s*16 + k*4);
            xls[k*4]=v.x; xls[k*4+1]=v.y; xls[k*4+2]=v.z; xls[k*4+3]=v.w;
        }
        #pragma unroll
        for (int h=0;h<4;h++){
            float a = 0.f;
            #pragma unroll
            for (int ch=0;ch<4;ch++){
                int idx = h*4+ch;
                a += lrelu(xls[idx] + xr[idx] + w*sWe[idx]) * sAtt[idx];
            }
            float mn2 = fmaxf(m[h], a);
            float corr = __expf(m[h]-mn2);
            float p = __expf(a-mn2);
            ss[h] = ss[h]*corr + p;
            #pragma unroll
            for (int ch=0;ch<4;ch++){
                int idx = h*4+ch;
                acc[idx] = acc[idx]*corr + p*xls[idx];
            }
            m[h] = mn2;
        }
    }
    #pragma unroll
    for (int st=1; st<8; st<<=1){
        #pragma unroll
        for (int h=0;h<4;h++){
            float mo = __shfl_xor(m[h], st);
            float so = __shfl_xor(ss[h], st);
            float mn2 = fmaxf(m[h], mo);
            float ca = __expf(m[h]-mn2), cbb = __expf(mo-mn2);
            ss[h] = ss[h]*ca + so*cbb;
            #pragma unroll
            for (int ch=0;ch<4;ch++){
                int idx=h*4+ch;
                float ao = __shfl_xor(acc[idx], st);
                acc[idx] = acc[idx]*ca + ao*cbb;
            }
            m[h]=mn2;
        }
    }
    float nf1[16];
    #pragma unroll
    for (int h=0;h<4;h++){
        float den = ss[h] + 1e-16f;
        #pragma unroll
        for (int ch=0;ch<4;ch++){
            int idx=h*4+ch;
            nf1[idx] = relu(acc[idx]/den + sBias[idx]);
        }
    }
    #pragma unroll
    for (int u=0;u<4;u++){
        int o = g + 8*u;
        float a=sb2l[o], b=sb2r[o];
        #pragma unroll
        for (int k=0;k<16;k++){ a += nf1[k]*sW2l[k*32+o]; b += nf1[k]*sW2r[k*32+o]; }
        xl2[node*32+o]=a; xr2[node*32+o]=b;
    }
}

// ---------------- GAT layer 2 gather + Wn MLP ----------------
__global__ __launch_bounds__(256) void k_gat2(
    const int* __restrict__ cnt_d, const int* __restrict__ off_d,
    const int* __restrict__ bktd_s, const float* __restrict__ bktd_w,
    const float* __restrict__ xl2, const float* __restrict__ xr2,
    const float* __restrict__ ea_mean,
    const float* __restrict__ We2, const float* __restrict__ att2, const float* __restrict__ bias2,
    const float* __restrict__ Wn, const float* __restrict__ bn,
    float* __restrict__ nff)
{
    __shared__ float sWe[32], sAtt[32], sBias[32], sWn[1024], sbn[32];
    for (int t=threadIdx.x; t<1024; t+=256) sWn[t]=Wn[t];
    if (threadIdx.x<32){ sWe[threadIdx.x]=We2[threadIdx.x]; sAtt[threadIdx.x]=att2[threadIdx.x];
                         sBias[threadIdx.x]=bias2[threadIdx.x]; sbn[threadIdx.x]=bn[threadIdx.x]; }
    __syncthreads();
    int node = blockIdx.x*32 + (threadIdx.x>>3);
    if (node >= NN) return;
    int g = threadIdx.x & 7;
    float xr[32];
    #pragma unroll
    for (int k=0;k<8;k++){
        float4 v = *(const float4*)(xr2 + node*32 + k*4);
        xr[k*4]=v.x; xr[k*4+1]=v.y; xr[k*4+2]=v.z; xr[k*4+3]=v.w;
    }
    int deg = cnt_d[node], base = off_d[node];
    float eam = ea_mean[node];
    float m[4], ss[4], acc[32];
    #pragma unroll
    for (int h=0;h<4;h++){ m[h]=-1e30f; ss[h]=0.f; }
    #pragma unroll
    for (int k=0;k<32;k++) acc[k]=0.f;
    for (int j=g; j<=deg; j+=8){
        bool selfe = (j==deg);
        int s   = selfe ? node : bktd_s[base+j];
        float w = selfe ? eam  : bktd_w[base+j];
        float xls[32];
        #pragma unroll
        for (int k=0;k<8;k++){
            float4 v = *(const float4*)(xl2 + s*32 + k*4);
            xls[k*4]=v.x; xls[k*4+1]=v.y; xls[k*4+2]=v.z; xls[k*4+3]=v.w;
        }
        #pragma unroll
        for (int h=0;h<4;h++){
            float a = 0.f;
            #pragma unroll
            for (int ch=0;ch<8;ch++){
                int idx = h*8+ch;
                a += lrelu(xls[idx] + xr[idx] + w*sWe[idx]) * sAtt[idx];
            }
            float mn2 = fmaxf(m[h], a);
            float corr = __expf(m[h]-mn2);
            float p = __expf(a-mn2);
            ss[h] = ss[h]*corr + p;
            #pragma unroll
            for (int ch=0;ch<8;ch++){
                int idx = h*8+ch;
                acc[idx] = acc[idx]*corr + p*xls[idx];
            }
            m[h] = mn2;
        }
    }
    #pragma unroll
    for (int st=1; st<8; st<<=1){
        #pragma unroll
        for (int h=0;h<4;h++){
            float mo = __shfl_xor(m[h], st);
            float so = __shfl_xor(ss[h], st);
            float mn2 = fmaxf(m[h], mo);
            float ca = __expf(m[h]-mn2), cbb = __expf(mo-mn2);
            ss[h] = ss[h]*ca + so*cbb;
            #pragma unroll
            for (int ch=0;ch<8;ch++){
                int idx=h*8+ch;
                float ao = __shfl_xor(acc[idx], st);
                acc[idx] = acc[idx]*ca + ao*cbb;
            }
            m[h]=mn2;
        }
    }
    float nf2[32];
    #pragma unroll
    for (int h=0;h<4;h++){
        float den = ss[h] + 1e-16f;
        #pragma unroll
        for (int ch=0;ch<8;ch++){
            int idx=h*8+ch;
            nf2[idx] = relu(acc[idx]/den + sBias[idx]);
        }
    }
    #pragma unroll
    for (int u=0;u<4;u++){
        int o = g + 8*u;
        float a = sbn[o];
        #pragma unroll
        for (int k=0;k<32;k++) a += nf2[k]*sWn[k*32+o];
        nff[node*32+o] = relu(a);
    }
}

// ---------------- per-src softmax stats for score cols 0,1 ----------------
__global__ __launch_bounds__(256) void k_src(
    const int* __restrict__ cnt_s, const int* __restrict__ off_s,
    const int* __restrict__ bkts_d, const float* __restrict__ bkts_w,
    const float* __restrict__ nff,
    const float* __restrict__ We_fc, const float* __restrict__ be_fc,
    float* __restrict__ smax, float* __restrict__ sden)
{
    __shared__ float sWs[64], sWd[64], sW0[2], sbe[2];
    if (threadIdx.x < 32){
        sWs[threadIdx.x*2]   = We_fc[(1+threadIdx.x)*32];
        sWs[threadIdx.x*2+1] = We_fc[(1+threadIdx.x)*32+1];
        sWd[threadIdx.x*2]   = We_fc[(33+threadIdx.x)*32];
        sWd[threadIdx.x*2+1] = We_fc[(33+threadIdx.x)*32+1];
    }
    if (threadIdx.x < 2){ sW0[threadIdx.x]=We_fc[threadIdx.x]; sbe[threadIdx.x]=be_fc[threadIdx.x]; }
    __syncthreads();
    int node = blockIdx.x*32 + (threadIdx.x>>3);
    if (node >= NN) return;
    int g = threadIdx.x & 7;
    float nfs[32];
    #pragma unroll
    for (int k=0;k<8;k++){
        float4 v = *(const float4*)(nff + node*32 + k*4);
        nfs[k*4]=v.x; nfs[k*4+1]=v.y; nfs[k*4+2]=v.z; nfs[k*4+3]=v.w;
    }
    float base0 = sbe[0], base1 = sbe[1];
    #pragma unroll
    for (int k=0;k<32;k++){ base0 += nfs[k]*sWs[k*2]; base1 += nfs[k]*sWs[k*2+1]; }
    int deg = cnt_s[node], base = off_s[node];
    float m0=-1e30f, m1=-1e30f, s0=0.f, s1=0.f;
    for (int j=g; j<deg; j+=8){
        int d = bkts_d[base+j];
        float w = bkts_w[base+j];
        float a0 = base0 + w*sW0[0];
        float a1 = base1 + w*sW0[1];
        #pragma unroll
        for (int k=0;k<8;k++){
            float4 v = *(const float4*)(nff + d*32 + k*4);
            a0 += v.x*sWd[(k*4)*2]   + v.y*sWd[(k*4+1)*2]   + v.z*sWd[(k*4+2)*2]   + v.w*sWd[(k*4+3)*2];
            a1 += v.x*sWd[(k*4)*2+1] + v.y*sWd[(k*4+1)*2+1] + v.z*sWd[(k*4+2)*2+1] + v.w*sWd[(k*4+3)*2+1];
        }
        float mn0 = fmaxf(m0, a0);
        s0 = s0*__expf(m0-mn0) + __expf(a0-mn0); m0 = mn0;
        float mn1 = fmaxf(m1, a1);
        s1 = s1*__expf(m1-mn1) + __expf(a1-mn1); m1 = mn1;
    }
    #pragma unroll
    for (int st=1; st<8; st<<=1){
        float mo = __shfl_xor(m0, st), so = __shfl_xor(s0, st);
        float mn = fmaxf(m0, mo);
        s0 = s0*__expf(m0-mn) + so*__expf(mo-mn); m0 = mn;
        mo = __shfl_xor(m1, st); so = __shfl_xor(s1, st);
        mn = fmaxf(m1, mo);
        s1 = s1*__expf(m1-mn) + so*__expf(mo-mn); m1 = mn;
    }
    if (g==0){ smax[node*2]=m0; smax[node*2+1]=m1; sden[node*2]=s0; sden[node*2+1]=s1; }
}

// ---------------- final edge scores: 65x32 GEMM + softmax-normalize cols 0,1 ----------------
__global__ __launch_bounds__(256) void k_scC(const int* __restrict__ src, const int* __restrict__ dst,
                      const float* __restrict__ ea, const float* __restrict__ nff,
                      const float* __restrict__ We_fc, const float* __restrict__ be_fc,
                      const float* __restrict__ smax, const float* __restrict__ sden,
                      float* __restrict__ out){
    __shared__ float sW[65*32];
    __shared__ float sB[32];
    for (int t=threadIdx.x; t<65*32; t+=blockDim.x) sW[t]=We_fc[t];
    if (threadIdx.x < 32) sB[threadIdx.x]=be_fc[threadIdx.x];
    __syncthreads();
    int e = blockIdx.x*blockDim.x + threadIdx.x;
    if (e >= NE) return;
    int s = src[e], d = dst[e];
    float w = ea[e];
    float o[32];
    #pragma unroll
    for (int j=0;j<32;j++) o[j] = sB[j] + w*sW[j];
    #pragma unroll
    for (int k=0;k<32;k++){
        float v = nff[s*32+k];
        #pragma unroll
        for (int j=0;j<32;j++) o[j] += v*sW[(1+k)*32+j];
    }
    #pragma unroll
    for (int k=0;k<32;k++){
        float v = nff[d*32+k];
        #pragma unroll
        for (int j=0;j<32;j++) o[j] += v*sW[(33+k)*32+j];
    }
    o[0] = __expf(o[0] - smax[s*2])   / (sden[s*2]   + 1e-16f);
    o[1] = __expf(o[1] - smax[s*2+1]) / (sden[s*2+1] + 1e-16f);
    float* op = out + (size_t)e*32;
    #pragma unroll
    for (int j=0;j<8;j++){
        float4 v4; v4.x=o[j*4]; v4.y=o[j*4+1]; v4.z=o[j*4+2]; v4.w=o[j*4+3];
        *(float4*)(op + j*4) = v4;
    }
}

extern "C" void kernel_launch(void* const* d_in, const int* in_sizes, int n_in,
                              void* d_out, int out_size, void* d_ws, size_t ws_size,
                              hipStream_t stream) {
    const float* x     = (const float*)d_in[0];
    const int*   ei    = (const int*)  d_in[1];
    const float* ea    = (const float*)d_in[2];
    const float* W_ee  = (const float*)d_in[3];  const float* b_ee  = (const float*)d_in[4];
    const float* W_pre = (const float*)d_in[5];  const float* b_pre = (const float*)d_in[6];
    const float* W_post= (const float*)d_in[7];  const float* b_post= (const float*)d_in[8];
    const float* W_pna = (const float*)d_in[9];  const float* b_pna = (const float*)d_in[10];
    const float* W1l   = (const float*)d_in[11]; const float* b1l   = (const float*)d_in[12];
    const float* W1r   = (const float*)d_in[13]; const float* b1r   = (const float*)d_in[14];
    const float* W1e   = (const float*)d_in[15]; const float* att1  = (const float*)d_in[16];
    const float* bias1 = (const float*)d_in[17];
    const float* W2l   = (const float*)d_in[18]; const float* b2l   = (const float*)d_in[19];
    const float* W2r   = (const float*)d_in[20]; const float* b2r   = (const float*)d_in[21];
    const float* W2e   = (const float*)d_in[22]; const float* att2  = (const float*)d_in[23];
    const float* bias2 = (const float*)d_in[24];
    const float* Wn    = (const float*)d_in[25]; const float* bn    = (const float*)d_in[26];
    const float* We_fc = (const float*)d_in[27]; const float* be_fc = (const float*)d_in[28];
    const int* src = ei;
    const int* dst = ei + NE;
    float* out = (float*)d_out;

    float* ws = (float*)d_ws;
    size_t o = 0;
    auto A = [&](size_t n){ size_t r = o; o = (o + n + 63) & ~(size_t)63; return r; };
    int*   cnt_d  = (int*)(ws + A(NN));
    int*   off_d  = (int*)(ws + A(NN));
    int*   cur_d  = (int*)(ws + A(NN));
    int*   cnt_s  = (int*)(ws + A(NN));
    int*   off_s  = (int*)(ws + A(NN));
    int*   cur_s  = (int*)(ws + A(NN));
    int*   bktd_s = (int*)(ws + A(NE));
    float* bktd_w =        ws + A(NE);
    int*   bkts_d = (int*)(ws + A(NE));
    float* bkts_w =        ws + A(NE);
    float* xl1    =        ws + A((size_t)NN*16);
    float* xr1    =        ws + A((size_t)NN*16);
    float* xl2    =        ws + A((size_t)NN*32);
    float* xr2    =        ws + A((size_t)NN*32);
    float* nff    =        ws + A((size_t)NN*32);
    float* ea_mean=        ws + A(NN);
    float* smax   =        ws + A((size_t)NN*2);
    float* sden   =        ws + A((size_t)NN*2);
    if (ws_size < o * sizeof(float)) return;  // fail loudly (output stays poisoned)

    const int BS = 256;
    const int gridE = (NE + BS - 1)/BS;
    const int gridN = (NN + BS - 1)/BS;
    const int gridO = (NN + 31)/32;   // octet kernels: 32 nodes/block

    k_zero<<<gridN, BS, 0, stream>>>(cnt_d, cnt_s);
    k_count<<<gridE, BS, 0, stream>>>(src, dst, cnt_d, cnt_s);
    k_scan<<<1, 1024, 0, stream>>>(cnt_d, cnt_s, off_d, cur_d, off_s, cur_s);
    k_scatter<<<gridE, BS, 0, stream>>>(src, dst, ea, cur_d, cur_s, bktd_s, bktd_w, bkts_d, bkts_w);
    k_pna<<<gridO, BS, 0, stream>>>(x, cnt_d, off_d, bktd_s, bktd_w,
                                    W_ee, b_ee, W_pre, b_pre, W_post, b_post, W_pna, b_pna,
                                    W1l, b1l, W1r, b1r, xl1, xr1, ea_mean);
    k_gat1<<<gridO, BS, 0, stream>>>(cnt_d, off_d, bktd_s, bktd_w, xl1, xr1, ea_mean,
                                     W1e, att1, bias1, W2l, b2l, W2r, b2r, xl2, xr2);
    k_gat2<<<gridO, BS, 0, stream>>>(cnt_d, off_d, bktd_s, bktd_w, xl2, xr2, ea_mean,
                                     W2e, att2, bias2, Wn, bn, nff);
    k_src<<<gridO, BS, 0, stream>>>(cnt_s, off_s, bkts_d, bkts_w, nff, We_fc, be_fc, smax, sden);
    k_scC<<<gridE, BS, 0, stream>>>(src, dst, ea, nff, We_fc, be_fc, smax, sden, out);
}

// Round 3
// 622.656 us; speedup vs baseline: 11.6483x; 1.3025x over previous
//
#include <hip/hip_runtime.h>
#include <math.h>

#define NN 50000
#define NE 1600000
#define AVG_DEG_LOG 3.4965075614664802f

__device__ __forceinline__ float lrelu(float x){ return x > 0.f ? x : 0.2f*x; }
__device__ __forceinline__ float relu(float x){ return x > 0.f ? x : 0.f; }

// ---------------- CSR path: zero degree counters ----------------
__global__ void k_zero(int* cnt_d, int* cnt_s){
    int i = blockIdx.x*blockDim.x + threadIdx.x;
    if (i < NN){ cnt_d[i]=0; cnt_s[i]=0; }
}

// ---------------- CSR path: count degrees ----------------
__global__ void k_count(const int* __restrict__ src, const int* __restrict__ dst,
                        int* cnt_d, int* cnt_s){
    int e = blockIdx.x*blockDim.x + threadIdx.x;
    if (e >= NE) return;
    atomicAdd(&cnt_d[dst[e]], 1);
    atomicAdd(&cnt_s[src[e]], 1);
}

// ---------------- CSR path: exclusive scan (2 blocks: one per direction) ----------------
__global__ __launch_bounds__(1024) void k_scan(const int* __restrict__ cnt_d, const int* __restrict__ cnt_s,
                                               int* off_d, int* cur_d, int* off_s, int* cur_s){
    __shared__ int wsums[16];
    __shared__ int carry_s;
    const int tid = threadIdx.x;
    const int lane = tid & 63;
    const int wv = tid >> 6;
    const int pass = blockIdx.x;
    const int* cnt = pass ? cnt_s : cnt_d;
    int* off = pass ? off_s : off_d;
    int* cur = pass ? cur_s : cur_d;
    if (tid == 0) carry_s = 0;
    __syncthreads();
    for (int base = 0; base < NN; base += 4096){
        int i0 = base + tid*4;
        int v0 = (i0+0 < NN) ? cnt[i0+0] : 0;
        int v1 = (i0+1 < NN) ? cnt[i0+1] : 0;
        int v2 = (i0+2 < NN) ? cnt[i0+2] : 0;
        int v3 = (i0+3 < NN) ? cnt[i0+3] : 0;
        int tsum = v0+v1+v2+v3;
        int sc = tsum;
        for (int d = 1; d < 64; d <<= 1){
            int t = __shfl_up(sc, d, 64);
            if (lane >= d) sc += t;
        }
        if (lane == 63) wsums[wv] = sc;
        __syncthreads();
        int woff = 0;
        #pragma unroll
        for (int k = 0; k < 16; ++k) woff += (k < wv) ? wsums[k] : 0;
        int carry_in = carry_s;
        __syncthreads();
        if (tid == 1023) carry_s = carry_in + woff + sc;
        int excl = carry_in + woff + (sc - tsum);
        int e0 = excl, e1 = e0+v0, e2 = e1+v1, e3 = e2+v2;
        if (i0+0 < NN){ off[i0+0]=e0; cur[i0+0]=e0; }
        if (i0+1 < NN){ off[i0+1]=e1; cur[i0+1]=e1; }
        if (i0+2 < NN){ off[i0+2]=e2; cur[i0+2]=e2; }
        if (i0+3 < NN){ off[i0+3]=e3; cur[i0+3]=e3; }
        __syncthreads();
    }
}

// ---------------- CAP path: fill offsets/cursors ----------------
__global__ void k_fill(int* off_d, int* cur_d, int* off_s, int* cur_s, int cap){
    int i = blockIdx.x*blockDim.x + threadIdx.x;
    if (i < NN){ int v = i*cap; off_d[i]=v; cur_d[i]=v; off_s[i]=v; cur_s[i]=v; }
}

// ---------------- CAP path: recover degrees ----------------
__global__ void k_deg(const int* __restrict__ cur_d, const int* __restrict__ cur_s,
                      int* cnt_d, int* cnt_s, int cap){
    int i = blockIdx.x*blockDim.x + threadIdx.x;
    if (i < NN){
        cnt_d[i] = min(cur_d[i] - i*cap, cap);
        cnt_s[i] = min(cur_s[i] - i*cap, cap);
    }
}

// ---------------- scatter edges into packed buckets ----------------
__global__ void k_scatter(const int* __restrict__ src, const int* __restrict__ dst,
                          const float* __restrict__ ea,
                          int* cur_d, int* cur_s,
                          int2* bktd, int2* bkts, int cap){
    int e = blockIdx.x*blockDim.x + threadIdx.x;
    if (e >= NE) return;
    int s = src[e], d = dst[e];
    int wb = __float_as_int(ea[e]);
    int p = atomicAdd(&cur_d[d], 1);
    if (cap == 0 || (p - d*cap) < cap) bktd[p] = make_int2(s, wb);
    int q = atomicAdd(&cur_s[s], 1);
    if (cap == 0 || (q - s*cap) < cap) bkts[q] = make_int2(d, wb);
}

// ---------------- PNA gather + finalize + GAT1 transforms (8 lanes/node) ----------------
__global__ __launch_bounds__(256) void k_pna(
    const float* __restrict__ x,
    const int* __restrict__ cnt_d, const int* __restrict__ off_d,
    const int2* __restrict__ bktd,
    const float* __restrict__ W_ee, const float* __restrict__ b_ee,
    const float* __restrict__ W_pre, const float* __restrict__ b_pre,
    const float* __restrict__ W_post, const float* __restrict__ b_post,
    const float* __restrict__ W_pna, const float* __restrict__ b_pna,
    const float* __restrict__ W1l, const float* __restrict__ b1l,
    const float* __restrict__ W1r, const float* __restrict__ b1r,
    float* __restrict__ xl1, float* __restrict__ xr1, float* __restrict__ ea_mean)
{
    __shared__ float sWpre[75], sWpost[520], sWpna[64], sW1l[128], sW1r[128];
    __shared__ float sbpre[5], sWee[5], sbee[5], sbpost[8], sbpna[8], sb1l[16], sb1r[16];
    for (int t=threadIdx.x; t<75;  t+=256) sWpre[t]=W_pre[t];
    for (int t=threadIdx.x; t<520; t+=256) sWpost[t]=W_post[t];
    for (int t=threadIdx.x; t<64;  t+=256) sWpna[t]=W_pna[t];
    for (int t=threadIdx.x; t<128; t+=256){ sW1l[t]=W1l[t]; sW1r[t]=W1r[t]; }
    if (threadIdx.x<5){ sbpre[threadIdx.x]=b_pre[threadIdx.x]; sWee[threadIdx.x]=W_ee[threadIdx.x]; sbee[threadIdx.x]=b_ee[threadIdx.x]; }
    if (threadIdx.x<8){ sbpost[threadIdx.x]=b_post[threadIdx.x]; sbpna[threadIdx.x]=b_pna[threadIdx.x]; }
    if (threadIdx.x<16){ sb1l[threadIdx.x]=b1l[threadIdx.x]; sb1r[threadIdx.x]=b1r[threadIdx.x]; }
    __syncthreads();
    int node = blockIdx.x*32 + (threadIdx.x>>3);
    if (node >= NN) return;
    int g = threadIdx.x & 7;
    float xd[5];
    #pragma unroll
    for (int k=0;k<5;k++) xd[k] = x[node*5+k];
    float cb[5], c1v[5];
    #pragma unroll
    for (int c=0;c<5;c++){
        float a = sbpre[c], b = 0.f;
        #pragma unroll
        for (int k=0;k<5;k++){
            a += xd[k]*sWpre[k*5+c];
            a += sbee[k]*sWpre[(10+k)*5+c];
            b += sWee[k]*sWpre[(10+k)*5+c];
        }
        cb[c]=a; c1v[c]=b;
    }
    int deg = cnt_d[node], base = off_d[node];
    float sum[5], ssq[5], mn[5], mx[5];
    #pragma unroll
    for (int c=0;c<5;c++){ sum[c]=0.f; ssq[c]=0.f; mn[c]=1e30f; mx[c]=-1e30f; }
    float wsum = 0.f;
    for (int j=g; j<deg; j+=8){
        int2 ent = bktd[base+j];
        int s = ent.x;
        float w = __int_as_float(ent.y);
        wsum += w;
        float xs[5];
        #pragma unroll
        for (int k=0;k<5;k++) xs[k] = x[s*5+k];
        #pragma unroll
        for (int c=0;c<5;c++){
            float m = cb[c] + w*c1v[c];
            #pragma unroll
            for (int k=0;k<5;k++) m += xs[k]*sWpre[(5+k)*5+c];
            sum[c]+=m; ssq[c]+=m*m; mn[c]=fminf(mn[c],m); mx[c]=fmaxf(mx[c],m);
        }
    }
    #pragma unroll
    for (int st=1; st<8; st<<=1){
        #pragma unroll
        for (int c=0;c<5;c++){
            sum[c] += __shfl_xor(sum[c], st);
            ssq[c] += __shfl_xor(ssq[c], st);
            mn[c] = fminf(mn[c], __shfl_xor(mn[c], st));
            mx[c] = fmaxf(mx[c], __shfl_xor(mx[c], st));
        }
        wsum += __shfl_xor(wsum, st);
    }
    float c = (float)deg, cc = fmaxf(c, 1.f);
    float amp = __logf(cc+1.f) * (1.f/AVG_DEG_LOG);
    float feat[65];
    #pragma unroll
    for (int k=0;k<5;k++) feat[k]=xd[k];
    #pragma unroll
    for (int j=0;j<5;j++){
        float mean = sum[j]/cc, msq = ssq[j]/cc;
        float sd = sqrtf(fmaxf(msq - mean*mean, 0.f) + 1e-5f);
        feat[5+j]=mean;
        feat[10+j]= (deg>0)? mn[j] : 0.f;
        feat[15+j]= (deg>0)? mx[j] : 0.f;
        feat[20+j]=sd;
    }
    #pragma unroll
    for (int j=0;j<20;j++){ feat[25+j]=feat[5+j]*amp; feat[45+j]=feat[5+j]/amp; }
    float t = sbpost[g];
    #pragma unroll
    for (int k=0;k<65;k++) t += feat[k]*sWpost[k*8+g];
    float nf = sbpna[g];
    #pragma unroll
    for (int k=0;k<8;k++) nf += __shfl(t, k, 8) * sWpna[k*8+g];
    float nfk[8];
    #pragma unroll
    for (int k=0;k<8;k++) nfk[k] = __shfl(nf, k, 8);
    #pragma unroll
    for (int u=0;u<2;u++){
        int o = 2*g+u;
        float a=sb1l[o], b2=sb1r[o];
        #pragma unroll
        for (int k=0;k<8;k++){ a += nfk[k]*sW1l[k*16+o]; b2 += nfk[k]*sW1r[k*16+o]; }
        xl1[node*16+o]=a; xr1[node*16+o]=b2;
    }
    if (g==0) ea_mean[node] = wsum/cc;
}

// ---------------- GAT layer 1 gather (online softmax, self-loop as virtual edge) ----------------
__global__ __launch_bounds__(256) void k_gat1(
    const int* __restrict__ cnt_d, const int* __restrict__ off_d,
    const int2* __restrict__ bktd,
    const float* __restrict__ xl1, const float* __restrict__ xr1,
    const float* __restrict__ ea_mean,
    const float* __restrict__ We1, const float* __restrict__ att1, const float* __restrict__ bias1,
    const float* __restrict__ W2l, const float* __restrict__ b2l,
    const float* __restrict__ W2r, const float* __restrict__ b2r,
    float* __restrict__ xl2, float* __restrict__ xr2)
{
    __shared__ float sWe[16], sAtt[16], sBias[16], sW2l[512], sW2r[512], sb2l[32], sb2r[32];
    for (int t=threadIdx.x; t<512; t+=256){ sW2l[t]=W2l[t]; sW2r[t]=W2r[t]; }
    if (threadIdx.x<16){ sWe[threadIdx.x]=We1[threadIdx.x]; sAtt[threadIdx.x]=att1[threadIdx.x]; sBias[threadIdx.x]=bias1[threadIdx.x]; }
    if (threadIdx.x<32){ sb2l[threadIdx.x]=b2l[threadIdx.x]; sb2r[threadIdx.x]=b2r[threadIdx.x]; }
    __syncthreads();
    int node = blockIdx.x*32 + (threadIdx.x>>3);
    if (node >= NN) return;
    int g = threadIdx.x & 7;
    float xr[16];
    #pragma unroll
    for (int k=0;k<4;k++){
        float4 v = *(const float4*)(xr1 + node*16 + k*4);
        xr[k*4]=v.x; xr[k*4+1]=v.y; xr[k*4+2]=v.z; xr[k*4+3]=v.w;
    }
    int deg = cnt_d[node], base = off_d[node];
    float eam = ea_mean[node];
    float m[4], ss[4], acc[16];
    #pragma unroll
    for (int h=0;h<4;h++){ m[h]=-1e30f; ss[h]=0.f; }
    #pragma unroll
    for (int k=0;k<16;k++) acc[k]=0.f;
    for (int j=g; j<=deg; j+=8){
        bool selfe = (j==deg);
        int2 ent = selfe ? make_int2(node, __float_as_int(eam)) : bktd[base+j];
        int s = ent.x;
        float w = __int_as_float(ent.y);
        float xls[16];
        #pragma unroll
        for (int k=0;k<4;k++){
            float4 v = *(const float4*)(xl1 + s*16 + k*4);
            xls[k*4]=v.x; xls[k*4+1]=v.y; xls[k*4+2]=v.z; xls[k*4+3]=v.w;
        }
        #pragma unroll
        for (int h=0;h<4;h++){
            float a = 0.f;
            #pragma unroll
            for (int ch=0;ch<4;ch++){
                int idx = h*4+ch;
                a += lrelu(xls[idx] + xr[idx] + w*sWe[idx]) * sAtt[idx];
            }
            float mn2 = fmaxf(m[h], a);
            float corr = __expf(m[h]-mn2);
            float p = __expf(a-mn2);
            ss[h] = ss[h]*corr + p;
            #pragma unroll
            for (int ch=0;ch<4;ch++){
                int idx = h*4+ch;
                acc[idx] = acc[idx]*corr + p*xls[idx];
            }
            m[h] = mn2;
        }
    }
    #pragma unroll
    for (int st=1; st<8; st<<=1){
        #pragma unroll
        for (int h=0;h<4;h++){
            float mo = __shfl_xor(m[h], st);
            float so = __shfl_xor(ss[h], st);
            float mn2 = fmaxf(m[h], mo);
            float ca = __expf(m[h]-mn2), cbb = __expf(mo-mn2);
            ss[h] = ss[h]*ca + so*cbb;
            #pragma unroll
            for (int ch=0;ch<4;ch++){
                int idx=h*4+ch;
                float ao = __shfl_xor(acc[idx], st);
                acc[idx] = acc[idx]*ca + ao*cbb;
            }
            m[h]=mn2;
        }
    }
    float nf1[16];
    #pragma unroll
    for (int h=0;h<4;h++){
        float den = ss[h] + 1e-16f;
        #pragma unroll
        for (int ch=0;ch<4;ch++){
            int idx=h*4+ch;
            nf1[idx] = relu(acc[idx]/den + sBias[idx]);
        }
    }
    #pragma unroll
    for (int u=0;u<4;u++){
        int o = g + 8*u;
        float a=sb2l[o], b=sb2r[o];
        #pragma unroll
        for (int k=0;k<16;k++){ a += nf1[k]*sW2l[k*32+o]; b += nf1[k]*sW2r[k*32+o]; }
        xl2[node*32+o]=a; xr2[node*32+o]=b;
    }
}

// ---------------- GAT layer 2 gather + Wn MLP + We_fc projections ----------------
__global__ __launch_bounds__(256) void k_gat2(
    const int* __restrict__ cnt_d, const int* __restrict__ off_d,
    const int2* __restrict__ bktd,
    const float* __restrict__ xl2, const float* __restrict__ xr2,
    const float* __restrict__ ea_mean,
    const float* __restrict__ We2, const float* __restrict__ att2, const float* __restrict__ bias2,
    const float* __restrict__ Wn, const float* __restrict__ bn,
    const float* __restrict__ We_fc,
    float* __restrict__ Ps, float* __restrict__ Pd,
    float* __restrict__ Ps01, float* __restrict__ Pd01)
{
    __shared__ float sWe[32], sAtt[32], sBias[32], sWn[1024], sbn[32];
    __shared__ float sWsrc[1024], sWdst[1024];
    for (int t=threadIdx.x; t<1024; t+=256){
        sWn[t]=Wn[t];
        sWsrc[t]=We_fc[32 + t];       // rows 1..32  of We_fc
        sWdst[t]=We_fc[33*32 + t];    // rows 33..64 of We_fc
    }
    if (threadIdx.x<32){ sWe[threadIdx.x]=We2[threadIdx.x]; sAtt[threadIdx.x]=att2[threadIdx.x];
                         sBias[threadIdx.x]=bias2[threadIdx.x]; sbn[threadIdx.x]=bn[threadIdx.x]; }
    __syncthreads();
    int node = blockIdx.x*32 + (threadIdx.x>>3);
    if (node >= NN) return;
    int g = threadIdx.x & 7;
    float xr[32];
    #pragma unroll
    for (int k=0;k<8;k++){
        float4 v = *(const float4*)(xr2 + node*32 + k*4);
        xr[k*4]=v.x; xr[k*4+1]=v.y; xr[k*4+2]=v.z; xr[k*4+3]=v.w;
    }
    int deg = cnt_d[node], base = off_d[node];
    float eam = ea_mean[node];
    float m[4], ss[4], acc[32];
    #pragma unroll
    for (int h=0;h<4;h++){ m[h]=-1e30f; ss[h]=0.f; }
    #pragma unroll
    for (int k=0;k<32;k++) acc[k]=0.f;
    for (int j=g; j<=deg; j+=8){
        bool selfe = (j==deg);
        int2 ent = selfe ? make_int2(node, __float_as_int(eam)) : bktd[base+j];
        int s = ent.x;
        float w = __int_as_float(ent.y);
        float xls[32];
        #pragma unroll
        for (int k=0;k<8;k++){
            float4 v = *(const float4*)(xl2 + s*32 + k*4);
            xls[k*4]=v.x; xls[k*4+1]=v.y; xls[k*4+2]=v.z; xls[k*4+3]=v.w;
        }
        #pragma unroll
        for (int h=0;h<4;h++){
            float a = 0.f;
            #pragma unroll
            for (int ch=0;ch<8;ch++){
                int idx = h*8+ch;
                a += lrelu(xls[idx] + xr[idx] + w*sWe[idx]) * sAtt[idx];
            }
            float mn2 = fmaxf(m[h], a);
            float corr = __expf(m[h]-mn2);
            float p = __expf(a-mn2);
            ss[h] = ss[h]*corr + p;
            #pragma unroll
            for (int ch=0;ch<8;ch++){
                int idx = h*8+ch;
                acc[idx] = acc[idx]*corr + p*xls[idx];
            }
            m[h] = mn2;
        }
    }
    #pragma unroll
    for (int st=1; st<8; st<<=1){
        #pragma unroll
        for (int h=0;h<4;h++){
            float mo = __shfl_xor(m[h], st);
            float so = __shfl_xor(ss[h], st);
            float mn2 = fmaxf(m[h], mo);
            float ca = __expf(m[h]-mn2), cbb = __expf(mo-mn2);
            ss[h] = ss[h]*ca + so*cbb;
            #pragma unroll
            for (int ch=0;ch<8;ch++){
                int idx=h*8+ch;
                float ao = __shfl_xor(acc[idx], st);
                acc[idx] = acc[idx]*ca + ao*cbb;
            }
            m[h]=mn2;
        }
    }
    float nf2[32];
    #pragma unroll
    for (int h=0;h<4;h++){
        float den = ss[h] + 1e-16f;
        #pragma unroll
        for (int ch=0;ch<8;ch++){
            int idx=h*8+ch;
            nf2[idx] = relu(acc[idx]/den + sBias[idx]);
        }
    }
    // Wn MLP: lane g computes outputs g+8u, then broadcast full nfn
    float mine[4];
    #pragma unroll
    for (int u=0;u<4;u++){
        int oo = g + 8*u;
        float a = sbn[oo];
        #pragma unroll
        for (int k=0;k<32;k++) a += nf2[k]*sWn[k*32+oo];
        mine[u] = relu(a);
    }
    float nfn[32];
    #pragma unroll
    for (int k=0;k<32;k++) nfn[k] = __shfl(mine[k>>3], k&7, 8);
    // We_fc projections
    float pa[4], pb[4];
    #pragma unroll
    for (int u=0;u<4;u++){
        int oo = g + 8*u;
        float a=0.f, b=0.f;
        #pragma unroll
        for (int k=0;k<32;k++){ a += nfn[k]*sWsrc[k*32+oo]; b += nfn[k]*sWdst[k*32+oo]; }
        pa[u]=a; pb[u]=b;
        Ps[node*32+oo]=a; Pd[node*32+oo]=b;
    }
    float ps0=__shfl(pa[0],0,8), ps1=__shfl(pa[0],1,8);
    float pd0=__shfl(pb[0],0,8), pd1=__shfl(pb[0],1,8);
    if (g==0){
        *(float2*)(Ps01 + node*2) = make_float2(ps0, ps1);
        *(float2*)(Pd01 + node*2) = make_float2(pd0, pd1);
    }
}

// ---------------- per-src softmax stats (compact L2-resident gathers) ----------------
__global__ __launch_bounds__(256) void k_src(
    const int* __restrict__ cnt_s, const int* __restrict__ off_s,
    const int2* __restrict__ bkts,
    const float* __restrict__ Ps01, const float* __restrict__ Pd01,
    const float* __restrict__ We_fc, const float* __restrict__ be_fc,
    float* __restrict__ smax, float* __restrict__ sden)
{
    __shared__ float sW00, sW01, sbe0, sbe1;
    if (threadIdx.x == 0){ sW00=We_fc[0]; sW01=We_fc[1]; sbe0=be_fc[0]; sbe1=be_fc[1]; }
    __syncthreads();
    int node = blockIdx.x*32 + (threadIdx.x>>3);
    if (node >= NN) return;
    int g = threadIdx.x & 7;
    float2 p = *(const float2*)(Ps01 + node*2);
    float base0 = sbe0 + p.x, base1 = sbe1 + p.y;
    int deg = cnt_s[node], base = off_s[node];
    float m0=-1e30f, m1=-1e30f, s0=0.f, s1=0.f;
    for (int j=g; j<deg; j+=8){
        int2 ent = bkts[base+j];
        int d = ent.x;
        float w = __int_as_float(ent.y);
        float2 q = *(const float2*)(Pd01 + d*2);
        float a0 = base0 + w*sW00 + q.x;
        float a1 = base1 + w*sW01 + q.y;
        float mn0 = fmaxf(m0, a0);
        s0 = s0*__expf(m0-mn0) + __expf(a0-mn0); m0 = mn0;
        float mn1 = fmaxf(m1, a1);
        s1 = s1*__expf(m1-mn1) + __expf(a1-mn1); m1 = mn1;
    }
    #pragma unroll
    for (int st=1; st<8; st<<=1){
        float mo = __shfl_xor(m0, st), so = __shfl_xor(s0, st);
        float mn = fmaxf(m0, mo);
        s0 = s0*__expf(m0-mn) + so*__expf(mo-mn); m0 = mn;
        mo = __shfl_xor(m1, st); so = __shfl_xor(s1, st);
        mn = fmaxf(m1, mo);
        s1 = s1*__expf(m1-mn) + so*__expf(mo-mn); m1 = mn;
    }
    if (g==0){ smax[node*2]=m0; smax[node*2+1]=m1; sden[node*2]=s0; sden[node*2+1]=s1; }
}

// ---------------- final edge scores: Ps[s]+Pd[d] + normalize cols 0,1 ----------------
__global__ __launch_bounds__(256) void k_scC(const int* __restrict__ src, const int* __restrict__ dst,
                      const float* __restrict__ ea,
                      const float* __restrict__ Ps, const float* __restrict__ Pd,
                      const float* __restrict__ We_fc, const float* __restrict__ be_fc,
                      const float* __restrict__ smax, const float* __restrict__ sden,
                      float* __restrict__ out){
    __shared__ float sW0[32], sB[32];
    if (threadIdx.x < 32){ sW0[threadIdx.x]=We_fc[threadIdx.x]; sB[threadIdx.x]=be_fc[threadIdx.x]; }
    __syncthreads();
    int e = blockIdx.x*blockDim.x + threadIdx.x;
    if (e >= NE) return;
    int s = src[e], d = dst[e];
    float w = ea[e];
    const float4* ps4 = (const float4*)(Ps + (size_t)s*32);
    const float4* pd4 = (const float4*)(Pd + (size_t)d*32);
    float o[32];
    #pragma unroll
    for (int k=0;k<8;k++){
        float4 a = ps4[k];
        float4 b = pd4[k];
        o[k*4+0] = sB[k*4+0] + w*sW0[k*4+0] + a.x + b.x;
        o[k*4+1] = sB[k*4+1] + w*sW0[k*4+1] + a.y + b.y;
        o[k*4+2] = sB[k*4+2] + w*sW0[k*4+2] + a.z + b.z;
        o[k*4+3] = sB[k*4+3] + w*sW0[k*4+3] + a.w + b.w;
    }
    o[0] = __expf(o[0] - smax[s*2])   / (sden[s*2]   + 1e-16f);
    o[1] = __expf(o[1] - smax[s*2+1]) / (sden[s*2+1] + 1e-16f);
    float* op = out + (size_t)e*32;
    #pragma unroll
    for (int j=0;j<8;j++){
        float4 v4; v4.x=o[j*4]; v4.y=o[j*4+1]; v4.z=o[j*4+2]; v4.w=o[j*4+3];
        *(float4*)(op + j*4) = v4;
    }
}

extern "C" void kernel_launch(void* const* d_in, const int* in_sizes, int n_in,
                              void* d_out, int out_size, void* d_ws, size_t ws_size,
                              hipStream_t stream) {
    const float* x     = (const float*)d_in[0];
    const int*   ei    = (const int*)  d_in[1];
    const float* ea    = (const float*)d_in[2];
    const float* W_ee  = (const float*)d_in[3];  const float* b_ee  = (const float*)d_in[4];
    const float* W_pre = (const float*)d_in[5];  const float* b_pre = (const float*)d_in[6];
    const float* W_post= (const float*)d_in[7];  const float* b_post= (const float*)d_in[8];
    const float* W_pna = (const float*)d_in[9];  const float* b_pna = (const float*)d_in[10];
    const float* W1l   = (const float*)d_in[11]; const float* b1l   = (const float*)d_in[12];
    const float* W1r   = (const float*)d_in[13]; const float* b1r   = (const float*)d_in[14];
    const float* W1e   = (const float*)d_in[15]; const float* att1  = (const float*)d_in[16];
    const float* bias1 = (const float*)d_in[17];
    const float* W2l   = (const float*)d_in[18]; const float* b2l   = (const float*)d_in[19];
    const float* W2r   = (const float*)d_in[20]; const float* b2r   = (const float*)d_in[21];
    const float* W2e   = (const float*)d_in[22]; const float* att2  = (const float*)d_in[23];
    const float* bias2 = (const float*)d_in[24];
    const float* Wn    = (const float*)d_in[25]; const float* bn    = (const float*)d_in[26];
    const float* We_fc = (const float*)d_in[27]; const float* be_fc = (const float*)d_in[28];
    const int* src = ei;
    const int* dst = ei + NE;
    float* out = (float*)d_out;

    const int CAP = 80;
    float* ws = (float*)d_ws;
    size_t o = 0;
    auto A = [&](size_t n){ size_t r = o; o = (o + n + 63) & ~(size_t)63; return r; };
    int*   cnt_d  = (int*)(ws + A(NN));
    int*   off_d  = (int*)(ws + A(NN));
    int*   cur_d  = (int*)(ws + A(NN));
    int*   cnt_s  = (int*)(ws + A(NN));
    int*   off_s  = (int*)(ws + A(NN));
    int*   cur_s  = (int*)(ws + A(NN));
    float* xl1    =        ws + A((size_t)NN*16);
    float* xr1    =        ws + A((size_t)NN*16);
    float* xl2    =        ws + A((size_t)NN*32);
    float* xr2    =        ws + A((size_t)NN*32);
    float* Ps     =        ws + A((size_t)NN*32);
    float* Pd     =        ws + A((size_t)NN*32);
    float* ea_mean=        ws + A(NN);
    float* Ps01   =        ws + A((size_t)NN*2);
    float* Pd01   =        ws + A((size_t)NN*2);
    float* smax   =        ws + A((size_t)NN*2);
    float* sden   =        ws + A((size_t)NN*2);
    size_t fixed_end = o;
    size_t bkt_cap = 2*(size_t)NN*CAP;   // floats (int2 = 2 floats) per direction
    size_t bkt_csr = 2*(size_t)NE;
    size_t need_cap = (fixed_end + 2*(bkt_cap+64)) * sizeof(float);
    size_t need_csr = (fixed_end + 2*(bkt_csr+64)) * sizeof(float);
    bool capmode = (ws_size >= need_cap);
    size_t bkte = capmode ? bkt_cap : bkt_csr;
    int2* bktd = (int2*)(ws + A(bkte));
    int2* bkts = (int2*)(ws + A(bkte));
    if (!capmode && ws_size < need_csr) return;  // fail loudly (output stays poisoned)

    const int BS = 256;
    const int gridE = (NE + BS - 1)/BS;
    const int gridN = (NN + BS - 1)/BS;
    const int gridO = (NN + 31)/32;

    if (capmode){
        k_fill<<<gridN, BS, 0, stream>>>(off_d, cur_d, off_s, cur_s, CAP);
        k_scatter<<<gridE, BS, 0, stream>>>(src, dst, ea, cur_d, cur_s, bktd, bkts, CAP);
        k_deg<<<gridN, BS, 0, stream>>>(cur_d, cur_s, cnt_d, cnt_s, CAP);
    } else {
        k_zero<<<gridN, BS, 0, stream>>>(cnt_d, cnt_s);
        k_count<<<gridE, BS, 0, stream>>>(src, dst, cnt_d, cnt_s);
        k_scan<<<2, 1024, 0, stream>>>(cnt_d, cnt_s, off_d, cur_d, off_s, cur_s);
        k_scatter<<<gridE, BS, 0, stream>>>(src, dst, ea, cur_d, cur_s, bktd, bkts, 0);
    }
    k_pna<<<gridO, BS, 0, stream>>>(x, cnt_d, off_d, bktd,
                                    W_ee, b_ee, W_pre, b_pre, W_post, b_post, W_pna, b_pna,
                                    W1l, b1l, W1r, b1r, xl1, xr1, ea_mean);
    k_gat1<<<gridO, BS, 0, stream>>>(cnt_d, off_d, bktd, xl1, xr1, ea_mean,
                                     W1e, att1, bias1, W2l, b2l, W2r, b2r, xl2, xr2);
    k_gat2<<<gridO, BS, 0, stream>>>(cnt_d, off_d, bktd, xl2, xr2, ea_mean,
                                     W2e, att2, bias2, Wn, bn, We_fc,
                                     Ps, Pd, Ps01, Pd01);
    k_src<<<gridO, BS, 0, stream>>>(cnt_s, off_s, bkts, Ps01, Pd01, We_fc, be_fc, smax, sden);
    k_scC<<<gridE, BS, 0, stream>>>(src, dst, ea, Ps, Pd, We_fc, be_fc, smax, sden, out);
}

// Round 4
// 471.224 us; speedup vs baseline: 15.3916x; 1.3214x over previous
//
#include <hip/hip_runtime.h>
#include <math.h>

#define NN 50000
#define NE 1600000
#define AVG_DEG_LOG 3.4965075614664802f
#define NBIN 196            // (NN+255)/256
#define CHUNK 4096
#define NCHUNK 391          // (NE+CHUNK-1)/CHUNK

__device__ __forceinline__ float lrelu(float x){ return x > 0.f ? x : 0.2f*x; }
__device__ __forceinline__ float relu(float x){ return x > 0.f ? x : 0.f; }

// ================= two-level counting sort (no global atomics) =================

__global__ __launch_bounds__(256) void k_hist(const int* __restrict__ src, const int* __restrict__ dst,
                                              int* __restrict__ histD, int* __restrict__ histS){
    __shared__ int hd[NBIN], hs[NBIN];
    for (int t=threadIdx.x; t<NBIN; t+=256){ hd[t]=0; hs[t]=0; }
    __syncthreads();
    int chunk = blockIdx.x;
    int e0 = chunk*CHUNK, e1 = min(e0+CHUNK, NE);
    for (int e=e0+threadIdx.x; e<e1; e+=256){
        atomicAdd(&hd[dst[e]>>8], 1);
        atomicAdd(&hs[src[e]>>8], 1);
    }
    __syncthreads();
    for (int t=threadIdx.x; t<NBIN; t+=256){
        histD[t*NCHUNK+chunk] = hd[t];
        histS[t*NCHUNK+chunk] = hs[t];
    }
}

__global__ __launch_bounds__(1024) void k_scan2(const int* __restrict__ histD, const int* __restrict__ histS,
                                                int* baseD, int* baseS, int* binStartD, int* binStartS){
    __shared__ int wsums[16];
    __shared__ int carry_s;
    const int tid = threadIdx.x, lane = tid & 63, wv = tid >> 6;
    const int dir = blockIdx.x;
    const int* hist = dir ? histS : histD;
    int* base = dir ? baseS : baseD;
    int* binStart = dir ? binStartS : binStartD;
    const int M = NBIN*NCHUNK;
    if (tid == 0) carry_s = 0;
    __syncthreads();
    for (int t0 = 0; t0 < M; t0 += 1024){
        int idx = t0 + tid;
        int v = (idx < M) ? hist[idx] : 0;
        int sc = v;
        for (int d = 1; d < 64; d <<= 1){
            int t = __shfl_up(sc, d, 64);
            if (lane >= d) sc += t;
        }
        if (lane == 63) wsums[wv] = sc;
        __syncthreads();
        int woff = 0;
        #pragma unroll
        for (int k = 0; k < 16; ++k) woff += (k < wv) ? wsums[k] : 0;
        int carry_in = carry_s;
        __syncthreads();
        if (tid == 1023) carry_s = carry_in + woff + sc;
        int excl = carry_in + woff + sc - v;
        if (idx < M){
            base[idx] = excl;
            if ((idx % NCHUNK) == 0) binStart[idx / NCHUNK] = excl;
        }
        __syncthreads();
    }
    if (tid == 0) binStart[NBIN] = NE;
}

__global__ __launch_bounds__(256) void k_coarse(const int* __restrict__ src, const int* __restrict__ dst,
                                                const float* __restrict__ ea,
                                                const int* __restrict__ baseD, const int* __restrict__ baseS,
                                                int2* __restrict__ cD, int2* __restrict__ cS){
    __shared__ int curd[NBIN], curs[NBIN];
    int chunk = blockIdx.x;
    for (int t=threadIdx.x; t<NBIN; t+=256){
        curd[t] = baseD[t*NCHUNK+chunk];
        curs[t] = baseS[t*NCHUNK+chunk];
    }
    __syncthreads();
    int e0 = chunk*CHUNK, e1 = min(e0+CHUNK, NE);
    for (int e=e0+threadIdx.x; e<e1; e+=256){
        int s = src[e], d = dst[e];
        float w = ea[e];
        unsigned wq = (unsigned)(w * 16777216.f);
        wq = min(wq, 16777215u);
        int pd = atomicAdd(&curd[d>>8], 1);
        cD[pd] = make_int2(s, (int)(((unsigned)(d & 255) << 24) | wq));
        int ps = atomicAdd(&curs[s>>8], 1);
        cS[ps] = make_int2(d, (int)(((unsigned)(s & 255) << 24) | wq));
    }
}

__global__ __launch_bounds__(256) void k_fine(const int2* __restrict__ cin,
                                              const int* __restrict__ binStart,
                                              int2* __restrict__ bout,
                                              int* __restrict__ cnt, int* __restrict__ off){
    __shared__ int h[256], cur[256];
    __shared__ int ws4[4];
    int bin = blockIdx.x;
    int S = binStart[bin], E = binStart[bin+1];
    h[threadIdx.x] = 0;
    __syncthreads();
    for (int i = S + threadIdx.x; i < E; i += 256){
        unsigned y = (unsigned)cin[i].y;
        atomicAdd(&h[y >> 24], 1);
    }
    __syncthreads();
    int v = h[threadIdx.x];
    int lane = threadIdx.x & 63, wv = threadIdx.x >> 6;
    int sc = v;
    for (int d = 1; d < 64; d <<= 1){
        int t = __shfl_up(sc, d, 64);
        if (lane >= d) sc += t;
    }
    if (lane == 63) ws4[wv] = sc;
    __syncthreads();
    int woff = 0;
    #pragma unroll
    for (int k = 0; k < 4; ++k) woff += (k < wv) ? ws4[k] : 0;
    int excl = woff + sc - v;
    cur[threadIdx.x] = S + excl;
    int node = (bin << 8) + threadIdx.x;
    if (node < NN){ cnt[node] = v; off[node] = S + excl; }
    __syncthreads();
    for (int i = S + threadIdx.x; i < E; i += 256){
        int2 ent = cin[i];
        unsigned y = (unsigned)ent.y;
        int local = y >> 24;
        float w = ((float)(y & 0xFFFFFFu) + 0.5f) * (1.0f/16777216.f);
        int pos = atomicAdd(&cur[local], 1);
        bout[pos] = make_int2(ent.x, __float_as_int(w));
    }
}

// ================= fallback CSR path (atomic scatter) =================

__global__ void k_zero(int* cnt_d, int* cnt_s){
    int i = blockIdx.x*blockDim.x + threadIdx.x;
    if (i < NN){ cnt_d[i]=0; cnt_s[i]=0; }
}

__global__ void k_count(const int* __restrict__ src, const int* __restrict__ dst,
                        int* cnt_d, int* cnt_s){
    int e = blockIdx.x*blockDim.x + threadIdx.x;
    if (e >= NE) return;
    atomicAdd(&cnt_d[dst[e]], 1);
    atomicAdd(&cnt_s[src[e]], 1);
}

__global__ __launch_bounds__(1024) void k_scanCSR(const int* __restrict__ cnt_d, const int* __restrict__ cnt_s,
                                                  int* off_d, int* cur_d, int* off_s, int* cur_s){
    __shared__ int wsums[16];
    __shared__ int carry_s;
    const int tid = threadIdx.x, lane = tid & 63, wv = tid >> 6;
    const int pass = blockIdx.x;
    const int* cnt = pass ? cnt_s : cnt_d;
    int* off = pass ? off_s : off_d;
    int* cur = pass ? cur_s : cur_d;
    if (tid == 0) carry_s = 0;
    __syncthreads();
    for (int base = 0; base < NN; base += 4096){
        int i0 = base + tid*4;
        int v0 = (i0+0 < NN) ? cnt[i0+0] : 0;
        int v1 = (i0+1 < NN) ? cnt[i0+1] : 0;
        int v2 = (i0+2 < NN) ? cnt[i0+2] : 0;
        int v3 = (i0+3 < NN) ? cnt[i0+3] : 0;
        int tsum = v0+v1+v2+v3;
        int sc = tsum;
        for (int d = 1; d < 64; d <<= 1){
            int t = __shfl_up(sc, d, 64);
            if (lane >= d) sc += t;
        }
        if (lane == 63) wsums[wv] = sc;
        __syncthreads();
        int woff = 0;
        #pragma unroll
        for (int k = 0; k < 16; ++k) woff += (k < wv) ? wsums[k] : 0;
        int carry_in = carry_s;
        __syncthreads();
        if (tid == 1023) carry_s = carry_in + woff + sc;
        int excl = carry_in + woff + (sc - tsum);
        int e0 = excl, e1 = e0+v0, e2 = e1+v1, e3 = e2+v2;
        if (i0+0 < NN){ off[i0+0]=e0; cur[i0+0]=e0; }
        if (i0+1 < NN){ off[i0+1]=e1; cur[i0+1]=e1; }
        if (i0+2 < NN){ off[i0+2]=e2; cur[i0+2]=e2; }
        if (i0+3 < NN){ off[i0+3]=e3; cur[i0+3]=e3; }
        __syncthreads();
    }
}

__global__ void k_scatter(const int* __restrict__ src, const int* __restrict__ dst,
                          const float* __restrict__ ea,
                          int* cur_d, int* cur_s,
                          int2* bktd, int2* bkts){
    int e = blockIdx.x*blockDim.x + threadIdx.x;
    if (e >= NE) return;
    int s = src[e], d = dst[e];
    int wb = __float_as_int(ea[e]);
    int p = atomicAdd(&cur_d[d], 1);
    bktd[p] = make_int2(s, wb);
    int q = atomicAdd(&cur_s[s], 1);
    bkts[q] = make_int2(d, wb);
}

// ================= PNA gather + finalize + GAT1 transforms (8 lanes/node) =================
__global__ __launch_bounds__(256) void k_pna(
    const float* __restrict__ x,
    const int* __restrict__ cnt_d, const int* __restrict__ off_d,
    const int2* __restrict__ bktd,
    const float* __restrict__ W_ee, const float* __restrict__ b_ee,
    const float* __restrict__ W_pre, const float* __restrict__ b_pre,
    const float* __restrict__ W_post, const float* __restrict__ b_post,
    const float* __restrict__ W_pna, const float* __restrict__ b_pna,
    const float* __restrict__ W1l, const float* __restrict__ b1l,
    const float* __restrict__ W1r, const float* __restrict__ b1r,
    float* __restrict__ xl1, float* __restrict__ xr1, float* __restrict__ ea_mean)
{
    __shared__ float sWpre[75], sWpost[520], sWpna[64], sW1l[128], sW1r[128];
    __shared__ float sbpre[5], sWee[5], sbee[5], sbpost[8], sbpna[8], sb1l[16], sb1r[16];
    for (int t=threadIdx.x; t<75;  t+=256) sWpre[t]=W_pre[t];
    for (int t=threadIdx.x; t<520; t+=256) sWpost[t]=W_post[t];
    for (int t=threadIdx.x; t<64;  t+=256) sWpna[t]=W_pna[t];
    for (int t=threadIdx.x; t<128; t+=256){ sW1l[t]=W1l[t]; sW1r[t]=W1r[t]; }
    if (threadIdx.x<5){ sbpre[threadIdx.x]=b_pre[threadIdx.x]; sWee[threadIdx.x]=W_ee[threadIdx.x]; sbee[threadIdx.x]=b_ee[threadIdx.x]; }
    if (threadIdx.x<8){ sbpost[threadIdx.x]=b_post[threadIdx.x]; sbpna[threadIdx.x]=b_pna[threadIdx.x]; }
    if (threadIdx.x<16){ sb1l[threadIdx.x]=b1l[threadIdx.x]; sb1r[threadIdx.x]=b1r[threadIdx.x]; }
    __syncthreads();
    int node = blockIdx.x*32 + (threadIdx.x>>3);
    if (node >= NN) return;
    int g = threadIdx.x & 7;
    float xd[5];
    #pragma unroll
    for (int k=0;k<5;k++) xd[k] = x[node*5+k];
    float cb[5], c1v[5];
    #pragma unroll
    for (int c=0;c<5;c++){
        float a = sbpre[c], b = 0.f;
        #pragma unroll
        for (int k=0;k<5;k++){
            a += xd[k]*sWpre[k*5+c];
            a += sbee[k]*sWpre[(10+k)*5+c];
            b += sWee[k]*sWpre[(10+k)*5+c];
        }
        cb[c]=a; c1v[c]=b;
    }
    int deg = cnt_d[node], base = off_d[node];
    float sum[5], ssq[5], mn[5], mx[5];
    #pragma unroll
    for (int c=0;c<5;c++){ sum[c]=0.f; ssq[c]=0.f; mn[c]=1e30f; mx[c]=-1e30f; }
    float wsum = 0.f;
    for (int j=g; j<deg; j+=8){
        int2 ent = bktd[base+j];
        int s = ent.x;
        float w = __int_as_float(ent.y);
        wsum += w;
        float xs[5];
        #pragma unroll
        for (int k=0;k<5;k++) xs[k] = x[s*5+k];
        #pragma unroll
        for (int c=0;c<5;c++){
            float m = cb[c] + w*c1v[c];
            #pragma unroll
            for (int k=0;k<5;k++) m += xs[k]*sWpre[(5+k)*5+c];
            sum[c]+=m; ssq[c]+=m*m; mn[c]=fminf(mn[c],m); mx[c]=fmaxf(mx[c],m);
        }
    }
    #pragma unroll
    for (int st=1; st<8; st<<=1){
        #pragma unroll
        for (int c=0;c<5;c++){
            sum[c] += __shfl_xor(sum[c], st);
            ssq[c] += __shfl_xor(ssq[c], st);
            mn[c] = fminf(mn[c], __shfl_xor(mn[c], st));
            mx[c] = fmaxf(mx[c], __shfl_xor(mx[c], st));
        }
        wsum += __shfl_xor(wsum, st);
    }
    float c = (float)deg, cc = fmaxf(c, 1.f);
    float amp = __logf(cc+1.f) * (1.0f/AVG_DEG_LOG);
    float feat[65];
    #pragma unroll
    for (int k=0;k<5;k++) feat[k]=xd[k];
    #pragma unroll
    for (int j=0;j<5;j++){
        float mean = sum[j]/cc, msq = ssq[j]/cc;
        float sd = sqrtf(fmaxf(msq - mean*mean, 0.f) + 1e-5f);
        feat[5+j]=mean;
        feat[10+j]= (deg>0)? mn[j] : 0.f;
        feat[15+j]= (deg>0)? mx[j] : 0.f;
        feat[20+j]=sd;
    }
    #pragma unroll
    for (int j=0;j<20;j++){ feat[25+j]=feat[5+j]*amp; feat[45+j]=feat[5+j]/amp; }
    float t = sbpost[g];
    #pragma unroll
    for (int k=0;k<65;k++) t += feat[k]*sWpost[k*8+g];
    float nf = sbpna[g];
    #pragma unroll
    for (int k=0;k<8;k++) nf += __shfl(t, k, 8) * sWpna[k*8+g];
    float nfk[8];
    #pragma unroll
    for (int k=0;k<8;k++) nfk[k] = __shfl(nf, k, 8);
    #pragma unroll
    for (int u=0;u<2;u++){
        int o = 2*g+u;
        float a=sb1l[o], b2=sb1r[o];
        #pragma unroll
        for (int k=0;k<8;k++){ a += nfk[k]*sW1l[k*16+o]; b2 += nfk[k]*sW1r[k*16+o]; }
        xl1[node*16+o]=a; xr1[node*16+o]=b2;
    }
    if (g==0) ea_mean[node] = wsum/cc;
}

// ================= GAT layer 1 gather (online softmax, self-loop virtual edge) =================
__global__ __launch_bounds__(256) void k_gat1(
    const int* __restrict__ cnt_d, const int* __restrict__ off_d,
    const int2* __restrict__ bktd,
    const float* __restrict__ xl1, const float* __restrict__ xr1,
    const float* __restrict__ ea_mean,
    const float* __restrict__ We1, const float* __restrict__ att1, const float* __restrict__ bias1,
    const float* __restrict__ W2l, const float* __restrict__ b2l,
    const float* __restrict__ W2r, const float* __restrict__ b2r,
    float* __restrict__ xl2, float* __restrict__ xr2)
{
    __shared__ float sWe[16], sAtt[16], sBias[16], sW2l[512], sW2r[512], sb2l[32], sb2r[32];
    for (int t=threadIdx.x; t<512; t+=256){ sW2l[t]=W2l[t]; sW2r[t]=W2r[t]; }
    if (threadIdx.x<16){ sWe[threadIdx.x]=We1[threadIdx.x]; sAtt[threadIdx.x]=att1[threadIdx.x]; sBias[threadIdx.x]=bias1[threadIdx.x]; }
    if (threadIdx.x<32){ sb2l[threadIdx.x]=b2l[threadIdx.x]; sb2r[threadIdx.x]=b2r[threadIdx.x]; }
    __syncthreads();
    int node = blockIdx.x*32 + (threadIdx.x>>3);
    if (node >= NN) return;
    int g = threadIdx.x & 7;
    float xr[16];
    #pragma unroll
    for (int k=0;k<4;k++){
        float4 v = *(const float4*)(xr1 + node*16 + k*4);
        xr[k*4]=v.x; xr[k*4+1]=v.y; xr[k*4+2]=v.z; xr[k*4+3]=v.w;
    }
    int deg = cnt_d[node], base = off_d[node];
    float eam = ea_mean[node];
    float m[4], ss[4], acc[16];
    #pragma unroll
    for (int h=0;h<4;h++){ m[h]=-1e30f; ss[h]=0.f; }
    #pragma unroll
    for (int k=0;k<16;k++) acc[k]=0.f;
    for (int j=g; j<=deg; j+=8){
        bool selfe = (j==deg);
        int2 ent = selfe ? make_int2(node, __float_as_int(eam)) : bktd[base+j];
        int s = ent.x;
        float w = __int_as_float(ent.y);
        float xls[16];
        #pragma unroll
        for (int k=0;k<4;k++){
            float4 v = *(const float4*)(xl1 + s*16 + k*4);
            xls[k*4]=v.x; xls[k*4+1]=v.y; xls[k*4+2]=v.z; xls[k*4+3]=v.w;
        }
        #pragma unroll
        for (int h=0;h<4;h++){
            float a = 0.f;
            #pragma unroll
            for (int ch=0;ch<4;ch++){
                int idx = h*4+ch;
                a += lrelu(xls[idx] + xr[idx] + w*sWe[idx]) * sAtt[idx];
            }
            float mn2 = fmaxf(m[h], a);
            float corr = __expf(m[h]-mn2);
            float p = __expf(a-mn2);
            ss[h] = ss[h]*corr + p;
            #pragma unroll
            for (int ch=0;ch<4;ch++){
                int idx = h*4+ch;
                acc[idx] = acc[idx]*corr + p*xls[idx];
            }
            m[h] = mn2;
        }
    }
    #pragma unroll
    for (int st=1; st<8; st<<=1){
        #pragma unroll
        for (int h=0;h<4;h++){
            float mo = __shfl_xor(m[h], st);
            float so = __shfl_xor(ss[h], st);
            float mn2 = fmaxf(m[h], mo);
            float ca = __expf(m[h]-mn2), cbb = __expf(mo-mn2);
            ss[h] = ss[h]*ca + so*cbb;
            #pragma unroll
            for (int ch=0;ch<4;ch++){
                int idx=h*4+ch;
                float ao = __shfl_xor(acc[idx], st);
                acc[idx] = acc[idx]*ca + ao*cbb;
            }
            m[h]=mn2;
        }
    }
    float nf1[16];
    #pragma unroll
    for (int h=0;h<4;h++){
        float den = ss[h] + 1e-16f;
        #pragma unroll
        for (int ch=0;ch<4;ch++){
            int idx=h*4+ch;
            nf1[idx] = relu(acc[idx]/den + sBias[idx]);
        }
    }
    #pragma unroll
    for (int u=0;u<4;u++){
        int o = g + 8*u;
        float a=sb2l[o], b=sb2r[o];
        #pragma unroll
        for (int k=0;k<16;k++){ a += nf1[k]*sW2l[k*32+o]; b += nf1[k]*sW2r[k*32+o]; }
        xl2[node*32+o]=a; xr2[node*32+o]=b;
    }
}

// ================= GAT layer 2 gather + Wn MLP + We_fc projections =================
__global__ __launch_bounds__(256) void k_gat2(
    const int* __restrict__ cnt_d, const int* __restrict__ off_d,
    const int2* __restrict__ bktd,
    const float* __restrict__ xl2, const float* __restrict__ xr2,
    const float* __restrict__ ea_mean,
    const float* __restrict__ We2, const float* __restrict__ att2, const float* __restrict__ bias2,
    const float* __restrict__ Wn, const float* __restrict__ bn,
    const float* __restrict__ We_fc,
    float* __restrict__ Ps, float* __restrict__ Pd,
    float* __restrict__ Ps01, float* __restrict__ Pd01)
{
    __shared__ float sWe[32], sAtt[32], sBias[32], sWn[1024], sbn[32];
    __shared__ float sWsrc[1024], sWdst[1024];
    for (int t=threadIdx.x; t<1024; t+=256){
        sWn[t]=Wn[t];
        sWsrc[t]=We_fc[32 + t];
        sWdst[t]=We_fc[33*32 + t];
    }
    if (threadIdx.x<32){ sWe[threadIdx.x]=We2[threadIdx.x]; sAtt[threadIdx.x]=att2[threadIdx.x];
                         sBias[threadIdx.x]=bias2[threadIdx.x]; sbn[threadIdx.x]=bn[threadIdx.x]; }
    __syncthreads();
    int node = blockIdx.x*32 + (threadIdx.x>>3);
    if (node >= NN) return;
    int g = threadIdx.x & 7;
    float xr[32];
    #pragma unroll
    for (int k=0;k<8;k++){
        float4 v = *(const float4*)(xr2 + node*32 + k*4);
        xr[k*4]=v.x; xr[k*4+1]=v.y; xr[k*4+2]=v.z; xr[k*4+3]=v.w;
    }
    int deg = cnt_d[node], base = off_d[node];
    float eam = ea_mean[node];
    float m[4], ss[4], acc[32];
    #pragma unroll
    for (int h=0;h<4;h++){ m[h]=-1e30f; ss[h]=0.f; }
    #pragma unroll
    for (int k=0;k<32;k++) acc[k]=0.f;
    for (int j=g; j<=deg; j+=8){
        bool selfe = (j==deg);
        int2 ent = selfe ? make_int2(node, __float_as_int(eam)) : bktd[base+j];
        int s = ent.x;
        float w = __int_as_float(ent.y);
        float xls[32];
        #pragma unroll
        for (int k=0;k<8;k++){
            float4 v = *(const float4*)(xl2 + s*32 + k*4);
            xls[k*4]=v.x; xls[k*4+1]=v.y; xls[k*4+2]=v.z; xls[k*4+3]=v.w;
        }
        #pragma unroll
        for (int h=0;h<4;h++){
            float a = 0.f;
            #pragma unroll
            for (int ch=0;ch<8;ch++){
                int idx = h*8+ch;
                a += lrelu(xls[idx] + xr[idx] + w*sWe[idx]) * sAtt[idx];
            }
            float mn2 = fmaxf(m[h], a);
            float corr = __expf(m[h]-mn2);
            float p = __expf(a-mn2);
            ss[h] = ss[h]*corr + p;
            #pragma unroll
            for (int ch=0;ch<8;ch++){
                int idx = h*8+ch;
                acc[idx] = acc[idx]*corr + p*xls[idx];
            }
            m[h] = mn2;
        }
    }
    #pragma unroll
    for (int st=1; st<8; st<<=1){
        #pragma unroll
        for (int h=0;h<4;h++){
            float mo = __shfl_xor(m[h], st);
            float so = __shfl_xor(ss[h], st);
            float mn2 = fmaxf(m[h], mo);
            float ca = __expf(m[h]-mn2), cbb = __expf(mo-mn2);
            ss[h] = ss[h]*ca + so*cbb;
            #pragma unroll
            for (int ch=0;ch<8;ch++){
                int idx=h*8+ch;
                float ao = __shfl_xor(acc[idx], st);
                acc[idx] = acc[idx]*ca + ao*cbb;
            }
            m[h]=mn2;
        }
    }
    float nf2[32];
    #pragma unroll
    for (int h=0;h<4;h++){
        float den = ss[h] + 1e-16f;
        #pragma unroll
        for (int ch=0;ch<8;ch++){
            int idx=h*8+ch;
            nf2[idx] = relu(acc[idx]/den + sBias[idx]);
        }
    }
    float mine[4];
    #pragma unroll
    for (int u=0;u<4;u++){
        int oo = g + 8*u;
        float a = sbn[oo];
        #pragma unroll
        for (int k=0;k<32;k++) a += nf2[k]*sWn[k*32+oo];
        mine[u] = relu(a);
    }
    float nfn[32];
    #pragma unroll
    for (int k=0;k<32;k++) nfn[k] = __shfl(mine[k>>3], k&7, 8);
    float pa[4], pb[4];
    #pragma unroll
    for (int u=0;u<4;u++){
        int oo = g + 8*u;
        float a=0.f, b=0.f;
        #pragma unroll
        for (int k=0;k<32;k++){ a += nfn[k]*sWsrc[k*32+oo]; b += nfn[k]*sWdst[k*32+oo]; }
        pa[u]=a; pb[u]=b;
        Ps[node*32+oo]=a; Pd[node*32+oo]=b;
    }
    float ps0=__shfl(pa[0],0,8), ps1=__shfl(pa[0],1,8);
    float pd0=__shfl(pb[0],0,8), pd1=__shfl(pb[0],1,8);
    if (g==0){
        *(float2*)(Ps01 + node*2) = make_float2(ps0, ps1);
        *(float2*)(Pd01 + node*2) = make_float2(pd0, pd1);
    }
}

// ================= per-src softmax stats =================
__global__ __launch_bounds__(256) void k_src(
    const int* __restrict__ cnt_s, const int* __restrict__ off_s,
    const int2* __restrict__ bkts,
    const float* __restrict__ Ps01, const float* __restrict__ Pd01,
    const float* __restrict__ We_fc, const float* __restrict__ be_fc,
    float* __restrict__ smax, float* __restrict__ sden)
{
    __shared__ float sW00, sW01, sbe0, sbe1;
    if (threadIdx.x == 0){ sW00=We_fc[0]; sW01=We_fc[1]; sbe0=be_fc[0]; sbe1=be_fc[1]; }
    __syncthreads();
    int node = blockIdx.x*32 + (threadIdx.x>>3);
    if (node >= NN) return;
    int g = threadIdx.x & 7;
    float2 p = *(const float2*)(Ps01 + node*2);
    float base0 = sbe0 + p.x, base1 = sbe1 + p.y;
    int deg = cnt_s[node], base = off_s[node];
    float m0=-1e30f, m1=-1e30f, s0=0.f, s1=0.f;
    for (int j=g; j<deg; j+=8){
        int2 ent = bkts[base+j];
        int d = ent.x;
        float w = __int_as_float(ent.y);
        float2 q = *(const float2*)(Pd01 + d*2);
        float a0 = base0 + w*sW00 + q.x;
        float a1 = base1 + w*sW01 + q.y;
        float mn0 = fmaxf(m0, a0);
        s0 = s0*__expf(m0-mn0) + __expf(a0-mn0); m0 = mn0;
        float mn1 = fmaxf(m1, a1);
        s1 = s1*__expf(m1-mn1) + __expf(a1-mn1); m1 = mn1;
    }
    #pragma unroll
    for (int st=1; st<8; st<<=1){
        float mo = __shfl_xor(m0, st), so = __shfl_xor(s0, st);
        float mn = fmaxf(m0, mo);
        s0 = s0*__expf(m0-mn) + so*__expf(mo-mn); m0 = mn;
        mo = __shfl_xor(m1, st); so = __shfl_xor(s1, st);
        mn = fmaxf(m1, mo);
        s1 = s1*__expf(m1-mn) + so*__expf(mo-mn); m1 = mn;
    }
    if (g==0){ smax[node*2]=m0; smax[node*2+1]=m1; sden[node*2]=s0; sden[node*2+1]=s1; }
}

// ================= final edge scores =================
__global__ __launch_bounds__(256) void k_scC(const int* __restrict__ src, const int* __restrict__ dst,
                      const float* __restrict__ ea,
                      const float* __restrict__ Ps, const float* __restrict__ Pd,
                      const float* __restrict__ We_fc, const float* __restrict__ be_fc,
                      const float* __restrict__ smax, const float* __restrict__ sden,
                      float* __restrict__ out){
    __shared__ float sW0[32], sB[32];
    if (threadIdx.x < 32){ sW0[threadIdx.x]=We_fc[threadIdx.x]; sB[threadIdx.x]=be_fc[threadIdx.x]; }
    __syncthreads();
    int e = blockIdx.x*blockDim.x + threadIdx.x;
    if (e >= NE) return;
    int s = src[e], d = dst[e];
    float w = ea[e];
    const float4* ps4 = (const float4*)(Ps + (size_t)s*32);
    const float4* pd4 = (const float4*)(Pd + (size_t)d*32);
    float o[32];
    #pragma unroll
    for (int k=0;k<8;k++){
        float4 a = ps4[k];
        float4 b = pd4[k];
        o[k*4+0] = sB[k*4+0] + w*sW0[k*4+0] + a.x + b.x;
        o[k*4+1] = sB[k*4+1] + w*sW0[k*4+1] + a.y + b.y;
        o[k*4+2] = sB[k*4+2] + w*sW0[k*4+2] + a.z + b.z;
        o[k*4+3] = sB[k*4+3] + w*sW0[k*4+3] + a.w + b.w;
    }
    o[0] = __expf(o[0] - smax[s*2])   / (sden[s*2]   + 1e-16f);
    o[1] = __expf(o[1] - smax[s*2+1]) / (sden[s*2+1] + 1e-16f);
    float* op = out + (size_t)e*32;
    #pragma unroll
    for (int j=0;j<8;j++){
        float4 v4; v4.x=o[j*4]; v4.y=o[j*4+1]; v4.z=o[j*4+2]; v4.w=o[j*4+3];
        *(float4*)(op + j*4) = v4;
    }
}

extern "C" void kernel_launch(void* const* d_in, const int* in_sizes, int n_in,
                              void* d_out, int out_size, void* d_ws, size_t ws_size,
                              hipStream_t stream) {
    const float* x     = (const float*)d_in[0];
    const int*   ei    = (const int*)  d_in[1];
    const float* ea    = (const float*)d_in[2];
    const float* W_ee  = (const float*)d_in[3];  const float* b_ee  = (const float*)d_in[4];
    const float* W_pre = (const float*)d_in[5];  const float* b_pre = (const float*)d_in[6];
    const float* W_post= (const float*)d_in[7];  const float* b_post= (const float*)d_in[8];
    const float* W_pna = (const float*)d_in[9];  const float* b_pna = (const float*)d_in[10];
    const float* W1l   = (const float*)d_in[11]; const float* b1l   = (const float*)d_in[12];
    const float* W1r   = (const float*)d_in[13]; const float* b1r   = (const float*)d_in[14];
    const float* W1e   = (const float*)d_in[15]; const float* att1  = (const float*)d_in[16];
    const float* bias1 = (const float*)d_in[17];
    const float* W2l   = (const float*)d_in[18]; const float* b2l   = (const float*)d_in[19];
    const float* W2r   = (const float*)d_in[20]; const float* b2r   = (const float*)d_in[21];
    const float* W2e   = (const float*)d_in[22]; const float* att2  = (const float*)d_in[23];
    const float* bias2 = (const float*)d_in[24];
    const float* Wn    = (const float*)d_in[25]; const float* bn    = (const float*)d_in[26];
    const float* We_fc = (const float*)d_in[27]; const float* be_fc = (const float*)d_in[28];
    const int* src = ei;
    const int* dst = ei + NE;
    float* out = (float*)d_out;

    float* ws = (float*)d_ws;
    size_t o = 0;
    auto A = [&](size_t n){ size_t r = o; o = (o + n + 63) & ~(size_t)63; return r; };
    int*   cnt_d  = (int*)(ws + A(NN));
    int*   off_d  = (int*)(ws + A(NN));
    int*   cnt_s  = (int*)(ws + A(NN));
    int*   off_s  = (int*)(ws + A(NN));
    int*   cur_d  = (int*)(ws + A(NN));
    int*   cur_s  = (int*)(ws + A(NN));
    float* xl1    =        ws + A((size_t)NN*16);
    float* xr1    =        ws + A((size_t)NN*16);
    float* xl2    =        ws + A((size_t)NN*32);
    float* xr2    =        ws + A((size_t)NN*32);
    float* Ps     =        ws + A((size_t)NN*32);
    float* Pd     =        ws + A((size_t)NN*32);
    float* ea_mean=        ws + A(NN);
    float* Ps01   =        ws + A((size_t)NN*2);
    float* Pd01   =        ws + A((size_t)NN*2);
    float* smax   =        ws + A((size_t)NN*2);
    float* sden   =        ws + A((size_t)NN*2);
    int*   histD  = (int*)(ws + A((size_t)NBIN*NCHUNK));
    int*   histS  = (int*)(ws + A((size_t)NBIN*NCHUNK));
    int*   baseD  = (int*)(ws + A((size_t)NBIN*NCHUNK));
    int*   baseS  = (int*)(ws + A((size_t)NBIN*NCHUNK));
    int*   binStartD = (int*)(ws + A(NBIN+1));
    int*   binStartS = (int*)(ws + A(NBIN+1));
    int2*  bufX = (int2*)(ws + A(2*(size_t)NE));
    int2*  bufY = (int2*)(ws + A(2*(size_t)NE));
    size_t o_two = o;
    int2*  bufZ = (int2*)(ws + A(2*(size_t)NE));
    size_t o_three = o;
    bool sortmode = (ws_size >= o_three * sizeof(float));
    if (!sortmode && ws_size < o_two * sizeof(float)) return;  // fail loudly

    const int BS = 256;
    const int gridE = (NE + BS - 1)/BS;
    const int gridN = (NN + BS - 1)/BS;
    const int gridO = (NN + 31)/32;

    int2 *bktd, *bkts;
    if (sortmode){
        // two-level counting sort: coarse into bufX (dst) / bufY (src), then fine
        k_hist<<<NCHUNK, BS, 0, stream>>>(src, dst, histD, histS);
        k_scan2<<<2, 1024, 0, stream>>>(histD, histS, baseD, baseS, binStartD, binStartS);
        k_coarse<<<NCHUNK, BS, 0, stream>>>(src, dst, ea, baseD, baseS, bufX, bufY);
        k_fine<<<NBIN, BS, 0, stream>>>(bufY, binStartS, bufZ, cnt_s, off_s);  // src dir -> bufZ
        k_fine<<<NBIN, BS, 0, stream>>>(bufX, binStartD, bufY, cnt_d, off_d);  // dst dir -> bufY (reuse)
        bktd = bufY; bkts = bufZ;
    } else {
        bktd = bufX; bkts = bufY;
        k_zero<<<gridN, BS, 0, stream>>>(cnt_d, cnt_s);
        k_count<<<gridE, BS, 0, stream>>>(src, dst, cnt_d, cnt_s);
        k_scanCSR<<<2, 1024, 0, stream>>>(cnt_d, cnt_s, off_d, cur_d, off_s, cur_s);
        k_scatter<<<gridE, BS, 0, stream>>>(src, dst, ea, cur_d, cur_s, bktd, bkts);
    }
    k_pna<<<gridO, BS, 0, stream>>>(x, cnt_d, off_d, bktd,
                                    W_ee, b_ee, W_pre, b_pre, W_post, b_post, W_pna, b_pna,
                                    W1l, b1l, W1r, b1r, xl1, xr1, ea_mean);
    k_gat1<<<gridO, BS, 0, stream>>>(cnt_d, off_d, bktd, xl1, xr1, ea_mean,
                                     W1e, att1, bias1, W2l, b2l, W2r, b2r, xl2, xr2);
    k_gat2<<<gridO, BS, 0, stream>>>(cnt_d, off_d, bktd, xl2, xr2, ea_mean,
                                     W2e, att2, bias2, Wn, bn, We_fc,
                                     Ps, Pd, Ps01, Pd01);
    k_src<<<gridO, BS, 0, stream>>>(cnt_s, off_s, bkts, Ps01, Pd01, We_fc, be_fc, smax, sden);
    k_scC<<<gridE, BS, 0, stream>>>(src, dst, ea, Ps, Pd, We_fc, be_fc, smax, sden, out);
}

// Round 6
// 371.651 us; speedup vs baseline: 19.5153x; 1.2679x over previous
//
#include <hip/hip_runtime.h>
#include <math.h>

#define NN 50000
#define NE 1600000
#define AVG_DEG_LOG 3.4965075614664802f
#define NBIN 196            // (NN+255)/256
#define CHUNK 4096
#define NCHUNK 391          // (NE+CHUNK-1)/CHUNK

typedef float f4v __attribute__((ext_vector_type(4)));

__device__ __forceinline__ float lrelu(float x){ return x > 0.f ? x : 0.2f*x; }
__device__ __forceinline__ float relu(float x){ return x > 0.f ? x : 0.f; }

// bucket entry format (int2):
//   x = node(16b) | e_low16 << 16
//   y = [coarse only: local8 << 24] | e_hi5 << 19 | w_q19
__device__ __forceinline__ int ent_node(int2 ent){ return ent.x & 0xFFFF; }
__device__ __forceinline__ int ent_eid(int2 ent){
    return (int)(((unsigned)ent.x >> 16) | ((((unsigned)ent.y >> 19) & 31u) << 16));
}
__device__ __forceinline__ float ent_w(int2 ent){
    return ((float)((unsigned)ent.y & 0x7FFFFu) + 0.5f) * (1.0f/524288.0f);
}
__device__ __forceinline__ unsigned quant_w(float w){
    unsigned wq = (unsigned)(w * 524288.f);
    return wq > 524287u ? 524287u : wq;
}

// ================= two-level counting sort (no global atomics) =================

__global__ __launch_bounds__(256) void k_hist(const int* __restrict__ src, const int* __restrict__ dst,
                                              int* __restrict__ histD, int* __restrict__ histS){
    __shared__ int hd[NBIN], hs[NBIN];
    for (int t=threadIdx.x; t<NBIN; t+=256){ hd[t]=0; hs[t]=0; }
    __syncthreads();
    int chunk = blockIdx.x;
    int e0 = chunk*CHUNK, e1 = min(e0+CHUNK, NE);
    for (int e=e0+threadIdx.x; e<e1; e+=256){
        atomicAdd(&hd[dst[e]>>8], 1);
        atomicAdd(&hs[src[e]>>8], 1);
    }
    __syncthreads();
    for (int t=threadIdx.x; t<NBIN; t+=256){
        histD[t*NCHUNK+chunk] = hd[t];
        histS[t*NCHUNK+chunk] = hs[t];
    }
}

__global__ __launch_bounds__(1024) void k_scan2(const int* __restrict__ histD, const int* __restrict__ histS,
                                                int* baseD, int* baseS, int* binStartD, int* binStartS){
    __shared__ int wsums[16];
    __shared__ int carry_s;
    const int tid = threadIdx.x, lane = tid & 63, wv = tid >> 6;
    const int dir = blockIdx.x;
    const int* hist = dir ? histS : histD;
    int* base = dir ? baseS : baseD;
    int* binStart = dir ? binStartS : binStartD;
    const int M = NBIN*NCHUNK;
    if (tid == 0) carry_s = 0;
    __syncthreads();
    for (int t0 = 0; t0 < M; t0 += 1024){
        int idx = t0 + tid;
        int v = (idx < M) ? hist[idx] : 0;
        int sc = v;
        for (int d = 1; d < 64; d <<= 1){
            int t = __shfl_up(sc, d, 64);
            if (lane >= d) sc += t;
        }
        if (lane == 63) wsums[wv] = sc;
        __syncthreads();
        int woff = 0;
        #pragma unroll
        for (int k = 0; k < 16; ++k) woff += (k < wv) ? wsums[k] : 0;
        int carry_in = carry_s;
        __syncthreads();
        if (tid == 1023) carry_s = carry_in + woff + sc;
        int excl = carry_in + woff + sc - v;
        if (idx < M){
            base[idx] = excl;
            if ((idx % NCHUNK) == 0) binStart[idx / NCHUNK] = excl;
        }
        __syncthreads();
    }
    if (tid == 0) binStart[NBIN] = NE;
}

__global__ __launch_bounds__(256) void k_coarse(const int* __restrict__ src, const int* __restrict__ dst,
                                                const float* __restrict__ ea,
                                                const int* __restrict__ baseD, const int* __restrict__ baseS,
                                                int2* __restrict__ cD, int2* __restrict__ cS){
    __shared__ int curd[NBIN], curs[NBIN];
    int chunk = blockIdx.x;
    for (int t=threadIdx.x; t<NBIN; t+=256){
        curd[t] = baseD[t*NCHUNK+chunk];
        curs[t] = baseS[t*NCHUNK+chunk];
    }
    __syncthreads();
    int e0 = chunk*CHUNK, e1 = min(e0+CHUNK, NE);
    for (int e=e0+threadIdx.x; e<e1; e+=256){
        int s = src[e], d = dst[e];
        unsigned wq = quant_w(ea[e]);
        unsigned elo = (unsigned)(e & 0xFFFF) << 16;
        unsigned ehi = ((unsigned)e >> 16) << 19;
        int pd = atomicAdd(&curd[d>>8], 1);
        cD[pd] = make_int2((int)((unsigned)s | elo), (int)(((unsigned)(d & 255) << 24) | ehi | wq));
        int ps = atomicAdd(&curs[s>>8], 1);
        cS[ps] = make_int2((int)((unsigned)d | elo), (int)(((unsigned)(s & 255) << 24) | ehi | wq));
    }
}

__global__ __launch_bounds__(256) void k_fine(const int2* __restrict__ cin,
                                              const int* __restrict__ binStart,
                                              int2* __restrict__ bout,
                                              int* __restrict__ cnt, int* __restrict__ off){
    __shared__ int h[256], cur[256];
    __shared__ int ws4[4];
    int bin = blockIdx.x;
    int S = binStart[bin], E = binStart[bin+1];
    h[threadIdx.x] = 0;
    __syncthreads();
    for (int i = S + threadIdx.x; i < E; i += 256){
        unsigned y = (unsigned)cin[i].y;
        atomicAdd(&h[y >> 24], 1);
    }
    __syncthreads();
    int v = h[threadIdx.x];
    int lane = threadIdx.x & 63, wv = threadIdx.x >> 6;
    int sc = v;
    for (int d = 1; d < 64; d <<= 1){
        int t = __shfl_up(sc, d, 64);
        if (lane >= d) sc += t;
    }
    if (lane == 63) ws4[wv] = sc;
    __syncthreads();
    int woff = 0;
    #pragma unroll
    for (int k = 0; k < 4; ++k) woff += (k < wv) ? ws4[k] : 0;
    int excl = woff + sc - v;
    cur[threadIdx.x] = S + excl;
    int node = (bin << 8) + threadIdx.x;
    if (node < NN){ cnt[node] = v; off[node] = S + excl; }
    __syncthreads();
    for (int i = S + threadIdx.x; i < E; i += 256){
        int2 ent = cin[i];
        unsigned y = (unsigned)ent.y;
        int local = y >> 24;
        int pos = atomicAdd(&cur[local], 1);
        bout[pos] = make_int2(ent.x, (int)(y & 0x00FFFFFFu));
    }
}

// ================= fallback CSR path (atomic scatter) =================

__global__ void k_zero(int* cnt_d, int* cnt_s){
    int i = blockIdx.x*blockDim.x + threadIdx.x;
    if (i < NN){ cnt_d[i]=0; cnt_s[i]=0; }
}

__global__ void k_count(const int* __restrict__ src, const int* __restrict__ dst,
                        int* cnt_d, int* cnt_s){
    int e = blockIdx.x*blockDim.x + threadIdx.x;
    if (e >= NE) return;
    atomicAdd(&cnt_d[dst[e]], 1);
    atomicAdd(&cnt_s[src[e]], 1);
}

__global__ __launch_bounds__(1024) void k_scanCSR(const int* __restrict__ cnt_d, const int* __restrict__ cnt_s,
                                                  int* off_d, int* cur_d, int* off_s, int* cur_s){
    __shared__ int wsums[16];
    __shared__ int carry_s;
    const int tid = threadIdx.x, lane = tid & 63, wv = tid >> 6;
    const int pass = blockIdx.x;
    const int* cnt = pass ? cnt_s : cnt_d;
    int* off = pass ? off_s : off_d;
    int* cur = pass ? cur_s : cur_d;
    if (tid == 0) carry_s = 0;
    __syncthreads();
    for (int base = 0; base < NN; base += 4096){
        int i0 = base + tid*4;
        int v0 = (i0+0 < NN) ? cnt[i0+0] : 0;
        int v1 = (i0+1 < NN) ? cnt[i0+1] : 0;
        int v2 = (i0+2 < NN) ? cnt[i0+2] : 0;
        int v3 = (i0+3 < NN) ? cnt[i0+3] : 0;
        int tsum = v0+v1+v2+v3;
        int sc = tsum;
        for (int d = 1; d < 64; d <<= 1){
            int t = __shfl_up(sc, d, 64);
            if (lane >= d) sc += t;
        }
        if (lane == 63) wsums[wv] = sc;
        __syncthreads();
        int woff = 0;
        #pragma unroll
        for (int k = 0; k < 16; ++k) woff += (k < wv) ? wsums[k] : 0;
        int carry_in = carry_s;
        __syncthreads();
        if (tid == 1023) carry_s = carry_in + woff + sc;
        int excl = carry_in + woff + (sc - tsum);
        int e0 = excl, e1 = e0+v0, e2 = e1+v1, e3 = e2+v2;
        if (i0+0 < NN){ off[i0+0]=e0; cur[i0+0]=e0; }
        if (i0+1 < NN){ off[i0+1]=e1; cur[i0+1]=e1; }
        if (i0+2 < NN){ off[i0+2]=e2; cur[i0+2]=e2; }
        if (i0+3 < NN){ off[i0+3]=e3; cur[i0+3]=e3; }
        __syncthreads();
    }
}

__global__ void k_scatter(const int* __restrict__ src, const int* __restrict__ dst,
                          const float* __restrict__ ea,
                          int* cur_d, int* cur_s,
                          int2* bktd, int2* bkts){
    int e = blockIdx.x*blockDim.x + threadIdx.x;
    if (e >= NE) return;
    int s = src[e], d = dst[e];
    unsigned wq = quant_w(ea[e]);
    unsigned elo = (unsigned)(e & 0xFFFF) << 16;
    unsigned yv  = (((unsigned)e >> 16) << 19) | wq;
    int p = atomicAdd(&cur_d[d], 1);
    bktd[p] = make_int2((int)((unsigned)s | elo), (int)yv);
    int q = atomicAdd(&cur_s[s], 1);
    bkts[q] = make_int2((int)((unsigned)d | elo), (int)yv);
}

// ================= PNA gather + finalize + GAT1 transforms (8 lanes/node) =================
__global__ __launch_bounds__(256) void k_pna(
    const float* __restrict__ x,
    const int* __restrict__ cnt_d, const int* __restrict__ off_d,
    const int2* __restrict__ bktd,
    const float* __restrict__ W_ee, const float* __restrict__ b_ee,
    const float* __restrict__ W_pre, const float* __restrict__ b_pre,
    const float* __restrict__ W_post, const float* __restrict__ b_post,
    const float* __restrict__ W_pna, const float* __restrict__ b_pna,
    const float* __restrict__ W1l, const float* __restrict__ b1l,
    const float* __restrict__ W1r, const float* __restrict__ b1r,
    float* __restrict__ xl1, float* __restrict__ xr1, float* __restrict__ ea_mean)
{
    __shared__ float sWpre[75], sWpost[520], sWpna[64], sW1l[128], sW1r[128];
    __shared__ float sbpre[5], sWee[5], sbee[5], sbpost[8], sbpna[8], sb1l[16], sb1r[16];
    for (int t=threadIdx.x; t<75;  t+=256) sWpre[t]=W_pre[t];
    for (int t=threadIdx.x; t<520; t+=256) sWpost[t]=W_post[t];
    for (int t=threadIdx.x; t<64;  t+=256) sWpna[t]=W_pna[t];
    for (int t=threadIdx.x; t<128; t+=256){ sW1l[t]=W1l[t]; sW1r[t]=W1r[t]; }
    if (threadIdx.x<5){ sbpre[threadIdx.x]=b_pre[threadIdx.x]; sWee[threadIdx.x]=W_ee[threadIdx.x]; sbee[threadIdx.x]=b_ee[threadIdx.x]; }
    if (threadIdx.x<8){ sbpost[threadIdx.x]=b_post[threadIdx.x]; sbpna[threadIdx.x]=b_pna[threadIdx.x]; }
    if (threadIdx.x<16){ sb1l[threadIdx.x]=b1l[threadIdx.x]; sb1r[threadIdx.x]=b1r[threadIdx.x]; }
    __syncthreads();
    int node = blockIdx.x*32 + (threadIdx.x>>3);
    if (node >= NN) return;
    int g = threadIdx.x & 7;
    float xd[5];
    #pragma unroll
    for (int k=0;k<5;k++) xd[k] = x[node*5+k];
    float cb[5], c1v[5];
    #pragma unroll
    for (int c=0;c<5;c++){
        float a = sbpre[c], b = 0.f;
        #pragma unroll
        for (int k=0;k<5;k++){
            a += xd[k]*sWpre[k*5+c];
            a += sbee[k]*sWpre[(10+k)*5+c];
            b += sWee[k]*sWpre[(10+k)*5+c];
        }
        cb[c]=a; c1v[c]=b;
    }
    int deg = cnt_d[node], base = off_d[node];
    float sum[5], ssq[5], mn[5], mx[5];
    #pragma unroll
    for (int c=0;c<5;c++){ sum[c]=0.f; ssq[c]=0.f; mn[c]=1e30f; mx[c]=-1e30f; }
    float wsum = 0.f;
    for (int j=g; j<deg; j+=8){
        int2 ent = bktd[base+j];
        int s = ent_node(ent);
        float w = ent_w(ent);
        wsum += w;
        float xs[5];
        #pragma unroll
        for (int k=0;k<5;k++) xs[k] = x[s*5+k];
        #pragma unroll
        for (int c=0;c<5;c++){
            float m = cb[c] + w*c1v[c];
            #pragma unroll
            for (int k=0;k<5;k++) m += xs[k]*sWpre[(5+k)*5+c];
            sum[c]+=m; ssq[c]+=m*m; mn[c]=fminf(mn[c],m); mx[c]=fmaxf(mx[c],m);
        }
    }
    #pragma unroll
    for (int st=1; st<8; st<<=1){
        #pragma unroll
        for (int c=0;c<5;c++){
            sum[c] += __shfl_xor(sum[c], st);
            ssq[c] += __shfl_xor(ssq[c], st);
            mn[c] = fminf(mn[c], __shfl_xor(mn[c], st));
            mx[c] = fmaxf(mx[c], __shfl_xor(mx[c], st));
        }
        wsum += __shfl_xor(wsum, st);
    }
    float c = (float)deg, cc = fmaxf(c, 1.f);
    float amp = __logf(cc+1.f) * (1.0f/AVG_DEG_LOG);
    float feat[65];
    #pragma unroll
    for (int k=0;k<5;k++) feat[k]=xd[k];
    #pragma unroll
    for (int j=0;j<5;j++){
        float mean = sum[j]/cc, msq = ssq[j]/cc;
        float sd = sqrtf(fmaxf(msq - mean*mean, 0.f) + 1e-5f);
        feat[5+j]=mean;
        feat[10+j]= (deg>0)? mn[j] : 0.f;
        feat[15+j]= (deg>0)? mx[j] : 0.f;
        feat[20+j]=sd;
    }
    #pragma unroll
    for (int j=0;j<20;j++){ feat[25+j]=feat[5+j]*amp; feat[45+j]=feat[5+j]/amp; }
    float t = sbpost[g];
    #pragma unroll
    for (int k=0;k<65;k++) t += feat[k]*sWpost[k*8+g];
    float nf = sbpna[g];
    #pragma unroll
    for (int k=0;k<8;k++) nf += __shfl(t, k, 8) * sWpna[k*8+g];
    float nfk[8];
    #pragma unroll
    for (int k=0;k<8;k++) nfk[k] = __shfl(nf, k, 8);
    #pragma unroll
    for (int u=0;u<2;u++){
        int o = 2*g+u;
        float a=sb1l[o], b2=sb1r[o];
        #pragma unroll
        for (int k=0;k<8;k++){ a += nfk[k]*sW1l[k*16+o]; b2 += nfk[k]*sW1r[k*16+o]; }
        xl1[node*16+o]=a; xr1[node*16+o]=b2;
    }
    if (g==0) ea_mean[node] = wsum/cc;
}

// ================= GAT layer 1 gather (online softmax, self-loop virtual edge) =================
__global__ __launch_bounds__(256) void k_gat1(
    const int* __restrict__ cnt_d, const int* __restrict__ off_d,
    const int2* __restrict__ bktd,
    const float* __restrict__ xl1, const float* __restrict__ xr1,
    const float* __restrict__ ea_mean,
    const float* __restrict__ We1, const float* __restrict__ att1, const float* __restrict__ bias1,
    const float* __restrict__ W2l, const float* __restrict__ b2l,
    const float* __restrict__ W2r, const float* __restrict__ b2r,
    float* __restrict__ xl2, float* __restrict__ xr2)
{
    __shared__ float sWe[16], sAtt[16], sBias[16], sW2l[512], sW2r[512], sb2l[32], sb2r[32];
    for (int t=threadIdx.x; t<512; t+=256){ sW2l[t]=W2l[t]; sW2r[t]=W2r[t]; }
    if (threadIdx.x<16){ sWe[threadIdx.x]=We1[threadIdx.x]; sAtt[threadIdx.x]=att1[threadIdx.x]; sBias[threadIdx.x]=bias1[threadIdx.x]; }
    if (threadIdx.x<32){ sb2l[threadIdx.x]=b2l[threadIdx.x]; sb2r[threadIdx.x]=b2r[threadIdx.x]; }
    __syncthreads();
    int node = blockIdx.x*32 + (threadIdx.x>>3);
    if (node >= NN) return;
    int g = threadIdx.x & 7;
    float xr[16];
    #pragma unroll
    for (int k=0;k<4;k++){
        float4 v = *(const float4*)(xr1 + node*16 + k*4);
        xr[k*4]=v.x; xr[k*4+1]=v.y; xr[k*4+2]=v.z; xr[k*4+3]=v.w;
    }
    int deg = cnt_d[node], base = off_d[node];
    float eam = ea_mean[node];
    float m[4], ss[4], acc[16];
    #pragma unroll
    for (int h=0;h<4;h++){ m[h]=-1e30f; ss[h]=0.f; }
    #pragma unroll
    for (int k=0;k<16;k++) acc[k]=0.f;
    for (int j=g; j<=deg; j+=8){
        bool selfe = (j==deg);
        int s; float w;
        if (selfe){ s = node; w = eam; }
        else { int2 ent = bktd[base+j]; s = ent_node(ent); w = ent_w(ent); }
        float xls[16];
        #pragma unroll
        for (int k=0;k<4;k++){
            float4 v = *(const float4*)(xl1 + s*16 + k*4);
            xls[k*4]=v.x; xls[k*4+1]=v.y; xls[k*4+2]=v.z; xls[k*4+3]=v.w;
        }
        #pragma unroll
        for (int h=0;h<4;h++){
            float a = 0.f;
            #pragma unroll
            for (int ch=0;ch<4;ch++){
                int idx = h*4+ch;
                a += lrelu(xls[idx] + xr[idx] + w*sWe[idx]) * sAtt[idx];
            }
            float mn2 = fmaxf(m[h], a);
            float corr = __expf(m[h]-mn2);
            float p = __expf(a-mn2);
            ss[h] = ss[h]*corr + p;
            #pragma unroll
            for (int ch=0;ch<4;ch++){
                int idx = h*4+ch;
                acc[idx] = acc[idx]*corr + p*xls[idx];
            }
            m[h] = mn2;
        }
    }
    #pragma unroll
    for (int st=1; st<8; st<<=1){
        #pragma unroll
        for (int h=0;h<4;h++){
            float mo = __shfl_xor(m[h], st);
            float so = __shfl_xor(ss[h], st);
            float mn2 = fmaxf(m[h], mo);
            float ca = __expf(m[h]-mn2), cbb = __expf(mo-mn2);
            ss[h] = ss[h]*ca + so*cbb;
            #pragma unroll
            for (int ch=0;ch<4;ch++){
                int idx=h*4+ch;
                float ao = __shfl_xor(acc[idx], st);
                acc[idx] = acc[idx]*ca + ao*cbb;
            }
            m[h]=mn2;
        }
    }
    float nf1[16];
    #pragma unroll
    for (int h=0;h<4;h++){
        float den = ss[h] + 1e-16f;
        #pragma unroll
        for (int ch=0;ch<4;ch++){
            int idx=h*4+ch;
            nf1[idx] = relu(acc[idx]/den + sBias[idx]);
        }
    }
    #pragma unroll
    for (int u=0;u<4;u++){
        int o = g + 8*u;
        float a=sb2l[o], b=sb2r[o];
        #pragma unroll
        for (int k=0;k<16;k++){ a += nf1[k]*sW2l[k*32+o]; b += nf1[k]*sW2r[k*32+o]; }
        xl2[node*32+o]=a; xr2[node*32+o]=b;
    }
}

// ================= GAT layer 2 gather + Wn MLP + We_fc projections =================
__global__ __launch_bounds__(256) void k_gat2(
    const int* __restrict__ cnt_d, const int* __restrict__ off_d,
    const int2* __restrict__ bktd,
    const float* __restrict__ xl2, const float* __restrict__ xr2,
    const float* __restrict__ ea_mean,
    const float* __restrict__ We2, const float* __restrict__ att2, const float* __restrict__ bias2,
    const float* __restrict__ Wn, const float* __restrict__ bn,
    const float* __restrict__ We_fc,
    float* __restrict__ Ps, float* __restrict__ Pd,
    float* __restrict__ Ps01, float* __restrict__ Pd01)
{
    __shared__ float sWe[32], sAtt[32], sBias[32], sWn[1024], sbn[32];
    __shared__ float sWsrc[1024], sWdst[1024];
    for (int t=threadIdx.x; t<1024; t+=256){
        sWn[t]=Wn[t];
        sWsrc[t]=We_fc[32 + t];
        sWdst[t]=We_fc[33*32 + t];
    }
    if (threadIdx.x<32){ sWe[threadIdx.x]=We2[threadIdx.x]; sAtt[threadIdx.x]=att2[threadIdx.x];
                         sBias[threadIdx.x]=bias2[threadIdx.x]; sbn[threadIdx.x]=bn[threadIdx.x]; }
    __syncthreads();
    int node = blockIdx.x*32 + (threadIdx.x>>3);
    if (node >= NN) return;
    int g = threadIdx.x & 7;
    float xr[32];
    #pragma unroll
    for (int k=0;k<8;k++){
        float4 v = *(const float4*)(xr2 + node*32 + k*4);
        xr[k*4]=v.x; xr[k*4+1]=v.y; xr[k*4+2]=v.z; xr[k*4+3]=v.w;
    }
    int deg = cnt_d[node], base = off_d[node];
    float eam = ea_mean[node];
    float m[4], ss[4], acc[32];
    #pragma unroll
    for (int h=0;h<4;h++){ m[h]=-1e30f; ss[h]=0.f; }
    #pragma unroll
    for (int k=0;k<32;k++) acc[k]=0.f;
    for (int j=g; j<=deg; j+=8){
        bool selfe = (j==deg);
        int s; float w;
        if (selfe){ s = node; w = eam; }
        else { int2 ent = bktd[base+j]; s = ent_node(ent); w = ent_w(ent); }
        float xls[32];
        #pragma unroll
        for (int k=0;k<8;k++){
            float4 v = *(const float4*)(xl2 + s*32 + k*4);
            xls[k*4]=v.x; xls[k*4+1]=v.y; xls[k*4+2]=v.z; xls[k*4+3]=v.w;
        }
        #pragma unroll
        for (int h=0;h<4;h++){
            float a = 0.f;
            #pragma unroll
            for (int ch=0;ch<8;ch++){
                int idx = h*8+ch;
                a += lrelu(xls[idx] + xr[idx] + w*sWe[idx]) * sAtt[idx];
            }
            float mn2 = fmaxf(m[h], a);
            float corr = __expf(m[h]-mn2);
            float p = __expf(a-mn2);
            ss[h] = ss[h]*corr + p;
            #pragma unroll
            for (int ch=0;ch<8;ch++){
                int idx = h*8+ch;
                acc[idx] = acc[idx]*corr + p*xls[idx];
            }
            m[h] = mn2;
        }
    }
    #pragma unroll
    for (int st=1; st<8; st<<=1){
        #pragma unroll
        for (int h=0;h<4;h++){
            float mo = __shfl_xor(m[h], st);
            float so = __shfl_xor(ss[h], st);
            float mn2 = fmaxf(m[h], mo);
            float ca = __expf(m[h]-mn2), cbb = __expf(mo-mn2);
            ss[h] = ss[h]*ca + so*cbb;
            #pragma unroll
            for (int ch=0;ch<8;ch++){
                int idx=h*8+ch;
                float ao = __shfl_xor(acc[idx], st);
                acc[idx] = acc[idx]*ca + ao*cbb;
            }
            m[h]=mn2;
        }
    }
    float nf2[32];
    #pragma unroll
    for (int h=0;h<4;h++){
        float den = ss[h] + 1e-16f;
        #pragma unroll
        for (int ch=0;ch<8;ch++){
            int idx=h*8+ch;
            nf2[idx] = relu(acc[idx]/den + sBias[idx]);
        }
    }
    float mine[4];
    #pragma unroll
    for (int u=0;u<4;u++){
        int oo = g + 8*u;
        float a = sbn[oo];
        #pragma unroll
        for (int k=0;k<32;k++) a += nf2[k]*sWn[k*32+oo];
        mine[u] = relu(a);
    }
    float nfn[32];
    #pragma unroll
    for (int k=0;k<32;k++) nfn[k] = __shfl(mine[k>>3], k&7, 8);
    float pa[4], pb[4];
    #pragma unroll
    for (int u=0;u<4;u++){
        int oo = g + 8*u;
        float a=0.f, b=0.f;
        #pragma unroll
        for (int k=0;k<32;k++){ a += nfn[k]*sWsrc[k*32+oo]; b += nfn[k]*sWdst[k*32+oo]; }
        pa[u]=a; pb[u]=b;
        Ps[node*32+oo]=a; Pd[node*32+oo]=b;
    }
    float ps0=__shfl(pa[0],0,8), ps1=__shfl(pa[0],1,8);
    float pd0=__shfl(pb[0],0,8), pd1=__shfl(pb[0],1,8);
    if (g==0){
        *(float2*)(Ps01 + node*2) = make_float2(ps0, ps1);
        *(float2*)(Pd01 + node*2) = make_float2(pd0, pd1);
    }
}

// ================= per-src softmax stats =================
__global__ __launch_bounds__(256) void k_src(
    const int* __restrict__ cnt_s, const int* __restrict__ off_s,
    const int2* __restrict__ bkts,
    const float* __restrict__ Ps01, const float* __restrict__ Pd01,
    const float* __restrict__ We_fc, const float* __restrict__ be_fc,
    float* __restrict__ smax, float* __restrict__ sden)
{
    __shared__ float sW00, sW01, sbe0, sbe1;
    if (threadIdx.x == 0){ sW00=We_fc[0]; sW01=We_fc[1]; sbe0=be_fc[0]; sbe1=be_fc[1]; }
    __syncthreads();
    int node = blockIdx.x*32 + (threadIdx.x>>3);
    if (node >= NN) return;
    int g = threadIdx.x & 7;
    float2 p = *(const float2*)(Ps01 + node*2);
    float base0 = sbe0 + p.x, base1 = sbe1 + p.y;
    int deg = cnt_s[node], base = off_s[node];
    float m0=-1e30f, m1=-1e30f, s0=0.f, s1=0.f;
    for (int j=g; j<deg; j+=8){
        int2 ent = bkts[base+j];
        int d = ent_node(ent);
        float w = ent_w(ent);
        float2 q = *(const float2*)(Pd01 + d*2);
        float a0 = base0 + w*sW00 + q.x;
        float a1 = base1 + w*sW01 + q.y;
        float mn0 = fmaxf(m0, a0);
        s0 = s0*__expf(m0-mn0) + __expf(a0-mn0); m0 = mn0;
        float mn1 = fmaxf(m1, a1);
        s1 = s1*__expf(m1-mn1) + __expf(a1-mn1); m1 = mn1;
    }
    #pragma unroll
    for (int st=1; st<8; st<<=1){
        float mo = __shfl_xor(m0, st), so = __shfl_xor(s0, st);
        float mn = fmaxf(m0, mo);
        s0 = s0*__expf(m0-mn) + so*__expf(mo-mn); m0 = mn;
        mo = __shfl_xor(m1, st); so = __shfl_xor(s1, st);
        mn = fmaxf(m1, mo);
        s1 = s1*__expf(m1-mn) + so*__expf(mo-mn); m1 = mn;
    }
    if (g==0){ smax[node*2]=m0; smax[node*2+1]=m1; sden[node*2]=s0; sden[node*2+1]=s1; }
}

// ================= final edge scores (dst-sorted; Pd streams, Ps random) =================
__global__ __launch_bounds__(256) void k_scC2(
    const int* __restrict__ cnt_d, const int* __restrict__ off_d,
    const int2* __restrict__ bktd,
    const float* __restrict__ Ps, const float* __restrict__ Pd,
    const float* __restrict__ We_fc, const float* __restrict__ be_fc,
    const float* __restrict__ smax, const float* __restrict__ sden,
    float* __restrict__ out)
{
    __shared__ float sW0[32], sB[32];
    if (threadIdx.x < 32){ sW0[threadIdx.x]=We_fc[threadIdx.x]; sB[threadIdx.x]=be_fc[threadIdx.x]; }
    __syncthreads();
    int node = blockIdx.x*32 + (threadIdx.x>>3);
    if (node >= NN) return;
    int g = threadIdx.x & 7;
    float4 pd = *(const float4*)(Pd + (size_t)node*32 + g*4);
    float4 w0 = *(const float4*)(sW0 + g*4);
    float4 b0 = *(const float4*)(sB + g*4);
    // fold Pd into the bias: per-edge work = w*W0 + Ps[s]
    b0.x += pd.x; b0.y += pd.y; b0.z += pd.z; b0.w += pd.w;
    int deg = cnt_d[node], base = off_d[node];
    for (int j=0; j<deg; ++j){
        int2 ent = bktd[base+j];
        int s = ent_node(ent);
        int e = ent_eid(ent);
        float w = ent_w(ent);
        const float4 ps = *(const float4*)(Ps + (size_t)s*32 + g*4);
        float ox = b0.x + w*w0.x + ps.x;
        float oy = b0.y + w*w0.y + ps.y;
        float oz = b0.z + w*w0.z + ps.z;
        float ow = b0.w + w*w0.w + ps.w;
        if (g == 0){
            float2 sm = *(const float2*)(smax + s*2);
            float2 sd = *(const float2*)(sden + s*2);
            ox = __expf(ox - sm.x) / (sd.x + 1e-16f);
            oy = __expf(oy - sm.y) / (sd.y + 1e-16f);
        }
        f4v ov; ov.x = ox; ov.y = oy; ov.z = oz; ov.w = ow;
        __builtin_nontemporal_store(ov, (f4v*)(out + (size_t)e*32 + g*4));
    }
}

extern "C" void kernel_launch(void* const* d_in, const int* in_sizes, int n_in,
                              void* d_out, int out_size, void* d_ws, size_t ws_size,
                              hipStream_t stream) {
    const float* x     = (const float*)d_in[0];
    const int*   ei    = (const int*)  d_in[1];
    const float* ea    = (const float*)d_in[2];
    const float* W_ee  = (const float*)d_in[3];  const float* b_ee  = (const float*)d_in[4];
    const float* W_pre = (const float*)d_in[5];  const float* b_pre = (const float*)d_in[6];
    const float* W_post= (const float*)d_in[7];  const float* b_post= (const float*)d_in[8];
    const float* W_pna = (const float*)d_in[9];  const float* b_pna = (const float*)d_in[10];
    const float* W1l   = (const float*)d_in[11]; const float* b1l   = (const float*)d_in[12];
    const float* W1r   = (const float*)d_in[13]; const float* b1r   = (const float*)d_in[14];
    const float* W1e   = (const float*)d_in[15]; const float* att1  = (const float*)d_in[16];
    const float* bias1 = (const float*)d_in[17];
    const float* W2l   = (const float*)d_in[18]; const float* b2l   = (const float*)d_in[19];
    const float* W2r   = (const float*)d_in[20]; const float* b2r   = (const float*)d_in[21];
    const float* W2e   = (const float*)d_in[22]; const float* att2  = (const float*)d_in[23];
    const float* bias2 = (const float*)d_in[24];
    const float* Wn    = (const float*)d_in[25]; const float* bn    = (const float*)d_in[26];
    const float* We_fc = (const float*)d_in[27]; const float* be_fc = (const float*)d_in[28];
    const int* src = ei;
    const int* dst = ei + NE;
    float* out = (float*)d_out;

    float* ws = (float*)d_ws;
    size_t o = 0;
    auto A = [&](size_t n){ size_t r = o; o = (o + n + 63) & ~(size_t)63; return r; };
    int*   cnt_d  = (int*)(ws + A(NN));
    int*   off_d  = (int*)(ws + A(NN));
    int*   cnt_s  = (int*)(ws + A(NN));
    int*   off_s  = (int*)(ws + A(NN));
    int*   cur_d  = (int*)(ws + A(NN));
    int*   cur_s  = (int*)(ws + A(NN));
    float* xl1    =        ws + A((size_t)NN*16);
    float* xr1    =        ws + A((size_t)NN*16);
    float* xl2    =        ws + A((size_t)NN*32);
    float* xr2    =        ws + A((size_t)NN*32);
    float* Ps     =        ws + A((size_t)NN*32);
    float* Pd     =        ws + A((size_t)NN*32);
    float* ea_mean=        ws + A(NN);
    float* Ps01   =        ws + A((size_t)NN*2);
    float* Pd01   =        ws + A((size_t)NN*2);
    float* smax   =        ws + A((size_t)NN*2);
    float* sden   =        ws + A((size_t)NN*2);
    int*   histD  = (int*)(ws + A((size_t)NBIN*NCHUNK));
    int*   histS  = (int*)(ws + A((size_t)NBIN*NCHUNK));
    int*   baseD  = (int*)(ws + A((size_t)NBIN*NCHUNK));
    int*   baseS  = (int*)(ws + A((size_t)NBIN*NCHUNK));
    int*   binStartD = (int*)(ws + A(NBIN+1));
    int*   binStartS = (int*)(ws + A(NBIN+1));
    int2*  bufX = (int2*)(ws + A(2*(size_t)NE));
    int2*  bufY = (int2*)(ws + A(2*(size_t)NE));
    size_t o_two = o;
    int2*  bufZ = (int2*)(ws + A(2*(size_t)NE));
    size_t o_three = o;
    bool sortmode = (ws_size >= o_three * sizeof(float));
    if (!sortmode && ws_size < o_two * sizeof(float)) return;  // fail loudly

    const int BS = 256;
    const int gridE = (NE + BS - 1)/BS;
    const int gridN = (NN + BS - 1)/BS;
    const int gridO = (NN + 31)/32;

    int2 *bktd, *bkts;
    if (sortmode){
        k_hist<<<NCHUNK, BS, 0, stream>>>(src, dst, histD, histS);
        k_scan2<<<2, 1024, 0, stream>>>(histD, histS, baseD, baseS, binStartD, binStartS);
        k_coarse<<<NCHUNK, BS, 0, stream>>>(src, dst, ea, baseD, baseS, bufX, bufY);
        k_fine<<<NBIN, BS, 0, stream>>>(bufY, binStartS, bufZ, cnt_s, off_s);  // src dir -> bufZ
        k_fine<<<NBIN, BS, 0, stream>>>(bufX, binStartD, bufY, cnt_d, off_d);  // dst dir -> bufY (reuse)
        bktd = bufY; bkts = bufZ;
    } else {
        bktd = bufX; bkts = bufY;
        k_zero<<<gridN, BS, 0, stream>>>(cnt_d, cnt_s);
        k_count<<<gridE, BS, 0, stream>>>(src, dst, cnt_d, cnt_s);
        k_scanCSR<<<2, 1024, 0, stream>>>(cnt_d, cnt_s, off_d, cur_d, off_s, cur_s);
        k_scatter<<<gridE, BS, 0, stream>>>(src, dst, ea, cur_d, cur_s, bktd, bkts);
    }
    k_pna<<<gridO, BS, 0, stream>>>(x, cnt_d, off_d, bktd,
                                    W_ee, b_ee, W_pre, b_pre, W_post, b_post, W_pna, b_pna,
                                    W1l, b1l, W1r, b1r, xl1, xr1, ea_mean);
    k_gat1<<<gridO, BS, 0, stream>>>(cnt_d, off_d, bktd, xl1, xr1, ea_mean,
                                     W1e, att1, bias1, W2l, b2l, W2r, b2r, xl2, xr2);
    k_gat2<<<gridO, BS, 0, stream>>>(cnt_d, off_d, bktd, xl2, xr2, ea_mean,
                                     W2e, att2, bias2, Wn, bn, We_fc,
                                     Ps, Pd, Ps01, Pd01);
    k_src<<<gridO, BS, 0, stream>>>(cnt_s, off_s, bkts, Ps01, Pd01, We_fc, be_fc, smax, sden);
    k_scC2<<<gridO, BS, 0, stream>>>(cnt_d, off_d, bktd, Ps, Pd, We_fc, be_fc, smax, sden, out);
}

// Round 7
// 365.089 us; speedup vs baseline: 19.8661x; 1.0180x over previous
//
#include <hip/hip_runtime.h>
#include <math.h>

#define NN 50000
#define NE 1600000
#define AVG_DEG_LOG 3.4965075614664802f
#define NBIN 196            // (NN+255)/256
#define CHUNK 4096
#define NCHUNK 391          // (NE+CHUNK-1)/CHUNK

typedef float f4v __attribute__((ext_vector_type(4)));
typedef _Float16 h4v __attribute__((ext_vector_type(4)));

__device__ __forceinline__ float lrelu(float x){ return x > 0.f ? x : 0.2f*x; }
__device__ __forceinline__ float relu(float x){ return x > 0.f ? x : 0.f; }

// 8-byte bucket entry (dst direction, post-fine):
//   x = node(16b) | e_low16 << 16
//   y = [coarse only: local8 << 24] | e_hi5 << 19 | w_q19
__device__ __forceinline__ int ent_node(int2 ent){ return ent.x & 0xFFFF; }
__device__ __forceinline__ int ent_eid(int2 ent){
    return (int)(((unsigned)ent.x >> 16) | ((((unsigned)ent.y >> 19) & 31u) << 16));
}
__device__ __forceinline__ float ent_w(int2 ent){
    return ((float)((unsigned)ent.y & 0x7FFFFu) + 0.5f) * (1.0f/524288.0f);
}
__device__ __forceinline__ unsigned quant_w(float w){
    unsigned wq = (unsigned)(w * 524288.f);
    return wq > 524287u ? 524287u : wq;
}
// 4-byte compact entry (src direction): node16 | wq16<<16
__device__ __forceinline__ int cent_node(int e){ return e & 0xFFFF; }
__device__ __forceinline__ float cent_w(int e){
    return ((float)(((unsigned)e >> 16) & 0xFFFFu) + 0.5f) * (1.0f/65536.0f);
}

// ================= two-level counting sort (no global atomics) =================

__global__ __launch_bounds__(256) void k_hist(const int* __restrict__ src, const int* __restrict__ dst,
                                              int* __restrict__ histD, int* __restrict__ histS){
    __shared__ int hd[NBIN], hs[NBIN];
    for (int t=threadIdx.x; t<NBIN; t+=256){ hd[t]=0; hs[t]=0; }
    __syncthreads();
    int chunk = blockIdx.x;
    int e0 = chunk*CHUNK, e1 = min(e0+CHUNK, NE);
    for (int e=e0+threadIdx.x; e<e1; e+=256){
        atomicAdd(&hd[dst[e]>>8], 1);
        atomicAdd(&hs[src[e]>>8], 1);
    }
    __syncthreads();
    for (int t=threadIdx.x; t<NBIN; t+=256){
        histD[t*NCHUNK+chunk] = hd[t];
        histS[t*NCHUNK+chunk] = hs[t];
    }
}

__global__ __launch_bounds__(1024) void k_scan2(const int* __restrict__ histD, const int* __restrict__ histS,
                                                int* baseD, int* baseS, int* binStartD, int* binStartS){
    __shared__ int wsums[16];
    __shared__ int carry_s;
    const int tid = threadIdx.x, lane = tid & 63, wv = tid >> 6;
    const int dir = blockIdx.x;
    const int* hist = dir ? histS : histD;
    int* base = dir ? baseS : baseD;
    int* binStart = dir ? binStartS : binStartD;
    const int M = NBIN*NCHUNK;
    if (tid == 0) carry_s = 0;
    __syncthreads();
    for (int t0 = 0; t0 < M; t0 += 1024){
        int idx = t0 + tid;
        int v = (idx < M) ? hist[idx] : 0;
        int sc = v;
        for (int d = 1; d < 64; d <<= 1){
            int t = __shfl_up(sc, d, 64);
            if (lane >= d) sc += t;
        }
        if (lane == 63) wsums[wv] = sc;
        __syncthreads();
        int woff = 0;
        #pragma unroll
        for (int k = 0; k < 16; ++k) woff += (k < wv) ? wsums[k] : 0;
        int carry_in = carry_s;
        __syncthreads();
        if (tid == 1023) carry_s = carry_in + woff + sc;
        int excl = carry_in + woff + sc - v;
        if (idx < M){
            base[idx] = excl;
            if ((idx % NCHUNK) == 0) binStart[idx / NCHUNK] = excl;
        }
        __syncthreads();
    }
    if (tid == 0) binStart[NBIN] = NE;
}

__global__ __launch_bounds__(256) void k_coarse(const int* __restrict__ src, const int* __restrict__ dst,
                                                const float* __restrict__ ea,
                                                const int* __restrict__ baseD, const int* __restrict__ baseS,
                                                int2* __restrict__ cD, int2* __restrict__ cS){
    __shared__ int curd[NBIN], curs[NBIN];
    int chunk = blockIdx.x;
    for (int t=threadIdx.x; t<NBIN; t+=256){
        curd[t] = baseD[t*NCHUNK+chunk];
        curs[t] = baseS[t*NCHUNK+chunk];
    }
    __syncthreads();
    int e0 = chunk*CHUNK, e1 = min(e0+CHUNK, NE);
    for (int e=e0+threadIdx.x; e<e1; e+=256){
        int s = src[e], d = dst[e];
        unsigned wq = quant_w(ea[e]);
        unsigned elo = (unsigned)(e & 0xFFFF) << 16;
        unsigned ehi = ((unsigned)e >> 16) << 19;
        int pd = atomicAdd(&curd[d>>8], 1);
        cD[pd] = make_int2((int)((unsigned)s | elo), (int)(((unsigned)(d & 255) << 24) | ehi | wq));
        int ps = atomicAdd(&curs[s>>8], 1);
        cS[ps] = make_int2((int)((unsigned)d | elo), (int)(((unsigned)(s & 255) << 24) | ehi | wq));
    }
}

// fine sort, dst direction: 8B entries out (keeps eid)
__global__ __launch_bounds__(256) void k_fine_d(const int2* __restrict__ cin,
                                                const int* __restrict__ binStart,
                                                int2* __restrict__ bout,
                                                int* __restrict__ cnt, int* __restrict__ off){
    __shared__ int h[256], cur[256];
    __shared__ int ws4[4];
    int bin = blockIdx.x;
    int S = binStart[bin], E = binStart[bin+1];
    h[threadIdx.x] = 0;
    __syncthreads();
    for (int i = S + threadIdx.x; i < E; i += 256){
        unsigned y = (unsigned)cin[i].y;
        atomicAdd(&h[y >> 24], 1);
    }
    __syncthreads();
    int v = h[threadIdx.x];
    int lane = threadIdx.x & 63, wv = threadIdx.x >> 6;
    int sc = v;
    for (int d = 1; d < 64; d <<= 1){
        int t = __shfl_up(sc, d, 64);
        if (lane >= d) sc += t;
    }
    if (lane == 63) ws4[wv] = sc;
    __syncthreads();
    int woff = 0;
    #pragma unroll
    for (int k = 0; k < 4; ++k) woff += (k < wv) ? ws4[k] : 0;
    int excl = woff + sc - v;
    cur[threadIdx.x] = S + excl;
    int node = (bin << 8) + threadIdx.x;
    if (node < NN){ cnt[node] = v; off[node] = S + excl; }
    __syncthreads();
    for (int i = S + threadIdx.x; i < E; i += 256){
        int2 ent = cin[i];
        unsigned y = (unsigned)ent.y;
        int local = y >> 24;
        int pos = atomicAdd(&cur[local], 1);
        bout[pos] = make_int2(ent.x, (int)(y & 0x00FFFFFFu));
    }
}

// fine sort, src direction: compact 4B entries out (no eid needed)
__global__ __launch_bounds__(256) void k_fine_c(const int2* __restrict__ cin,
                                                const int* __restrict__ binStart,
                                                int* __restrict__ bout,
                                                int* __restrict__ cnt, int* __restrict__ off){
    __shared__ int h[256], cur[256];
    __shared__ int ws4[4];
    int bin = blockIdx.x;
    int S = binStart[bin], E = binStart[bin+1];
    h[threadIdx.x] = 0;
    __syncthreads();
    for (int i = S + threadIdx.x; i < E; i += 256){
        unsigned y = (unsigned)cin[i].y;
        atomicAdd(&h[y >> 24], 1);
    }
    __syncthreads();
    int v = h[threadIdx.x];
    int lane = threadIdx.x & 63, wv = threadIdx.x >> 6;
    int sc = v;
    for (int d = 1; d < 64; d <<= 1){
        int t = __shfl_up(sc, d, 64);
        if (lane >= d) sc += t;
    }
    if (lane == 63) ws4[wv] = sc;
    __syncthreads();
    int woff = 0;
    #pragma unroll
    for (int k = 0; k < 4; ++k) woff += (k < wv) ? ws4[k] : 0;
    int excl = woff + sc - v;
    cur[threadIdx.x] = S + excl;
    int node = (bin << 8) + threadIdx.x;
    if (node < NN){ cnt[node] = v; off[node] = S + excl; }
    __syncthreads();
    for (int i = S + threadIdx.x; i < E; i += 256){
        int2 ent = cin[i];
        unsigned y = (unsigned)ent.y;
        int local = y >> 24;
        int pos = atomicAdd(&cur[local], 1);
        unsigned wq16 = (y & 0x7FFFFu) >> 3;
        bout[pos] = (int)(((unsigned)ent.x & 0xFFFFu) | (wq16 << 16));
    }
}

// ================= fallback CSR path (atomic scatter) =================

__global__ void k_zero(int* cnt_d, int* cnt_s){
    int i = blockIdx.x*blockDim.x + threadIdx.x;
    if (i < NN){ cnt_d[i]=0; cnt_s[i]=0; }
}

__global__ void k_count(const int* __restrict__ src, const int* __restrict__ dst,
                        int* cnt_d, int* cnt_s){
    int e = blockIdx.x*blockDim.x + threadIdx.x;
    if (e >= NE) return;
    atomicAdd(&cnt_d[dst[e]], 1);
    atomicAdd(&cnt_s[src[e]], 1);
}

__global__ __launch_bounds__(1024) void k_scanCSR(const int* __restrict__ cnt_d, const int* __restrict__ cnt_s,
                                                  int* off_d, int* cur_d, int* off_s, int* cur_s){
    __shared__ int wsums[16];
    __shared__ int carry_s;
    const int tid = threadIdx.x, lane = tid & 63, wv = tid >> 6;
    const int pass = blockIdx.x;
    const int* cnt = pass ? cnt_s : cnt_d;
    int* off = pass ? off_s : off_d;
    int* cur = pass ? cur_s : cur_d;
    if (tid == 0) carry_s = 0;
    __syncthreads();
    for (int base = 0; base < NN; base += 4096){
        int i0 = base + tid*4;
        int v0 = (i0+0 < NN) ? cnt[i0+0] : 0;
        int v1 = (i0+1 < NN) ? cnt[i0+1] : 0;
        int v2 = (i0+2 < NN) ? cnt[i0+2] : 0;
        int v3 = (i0+3 < NN) ? cnt[i0+3] : 0;
        int tsum = v0+v1+v2+v3;
        int sc = tsum;
        for (int d = 1; d < 64; d <<= 1){
            int t = __shfl_up(sc, d, 64);
            if (lane >= d) sc += t;
        }
        if (lane == 63) wsums[wv] = sc;
        __syncthreads();
        int woff = 0;
        #pragma unroll
        for (int k = 0; k < 16; ++k) woff += (k < wv) ? wsums[k] : 0;
        int carry_in = carry_s;
        __syncthreads();
        if (tid == 1023) carry_s = carry_in + woff + sc;
        int excl = carry_in + woff + (sc - tsum);
        int e0 = excl, e1 = e0+v0, e2 = e1+v1, e3 = e2+v2;
        if (i0+0 < NN){ off[i0+0]=e0; cur[i0+0]=e0; }
        if (i0+1 < NN){ off[i0+1]=e1; cur[i0+1]=e1; }
        if (i0+2 < NN){ off[i0+2]=e2; cur[i0+2]=e2; }
        if (i0+3 < NN){ off[i0+3]=e3; cur[i0+3]=e3; }
        __syncthreads();
    }
}

__global__ void k_scatter(const int* __restrict__ src, const int* __restrict__ dst,
                          const float* __restrict__ ea,
                          int* cur_d, int* cur_s,
                          int2* bktd, int* bkts){
    int e = blockIdx.x*blockDim.x + threadIdx.x;
    if (e >= NE) return;
    int s = src[e], d = dst[e];
    unsigned wq = quant_w(ea[e]);
    unsigned elo = (unsigned)(e & 0xFFFF) << 16;
    unsigned yv  = (((unsigned)e >> 16) << 19) | wq;
    int p = atomicAdd(&cur_d[d], 1);
    bktd[p] = make_int2((int)((unsigned)s | elo), (int)yv);
    int q = atomicAdd(&cur_s[s], 1);
    bkts[q] = (int)(((unsigned)d & 0xFFFFu) | ((wq >> 3) << 16));
}

// ================= PNA gather + finalize + GAT1 transforms (8 lanes/node) =================
__global__ __launch_bounds__(256) void k_pna(
    const float* __restrict__ x,
    const int* __restrict__ cnt_d, const int* __restrict__ off_d,
    const int2* __restrict__ bktd,
    const float* __restrict__ W_ee, const float* __restrict__ b_ee,
    const float* __restrict__ W_pre, const float* __restrict__ b_pre,
    const float* __restrict__ W_post, const float* __restrict__ b_post,
    const float* __restrict__ W_pna, const float* __restrict__ b_pna,
    const float* __restrict__ W1l, const float* __restrict__ b1l,
    const float* __restrict__ W1r, const float* __restrict__ b1r,
    float* __restrict__ xl1, float* __restrict__ xr1, float* __restrict__ ea_mean)
{
    __shared__ float sWpre[75], sWpost[520], sWpna[64], sW1l[128], sW1r[128];
    __shared__ float sbpre[5], sWee[5], sbee[5], sbpost[8], sbpna[8], sb1l[16], sb1r[16];
    for (int t=threadIdx.x; t<75;  t+=256) sWpre[t]=W_pre[t];
    for (int t=threadIdx.x; t<520; t+=256) sWpost[t]=W_post[t];
    for (int t=threadIdx.x; t<64;  t+=256) sWpna[t]=W_pna[t];
    for (int t=threadIdx.x; t<128; t+=256){ sW1l[t]=W1l[t]; sW1r[t]=W1r[t]; }
    if (threadIdx.x<5){ sbpre[threadIdx.x]=b_pre[threadIdx.x]; sWee[threadIdx.x]=W_ee[threadIdx.x]; sbee[threadIdx.x]=b_ee[threadIdx.x]; }
    if (threadIdx.x<8){ sbpost[threadIdx.x]=b_post[threadIdx.x]; sbpna[threadIdx.x]=b_pna[threadIdx.x]; }
    if (threadIdx.x<16){ sb1l[threadIdx.x]=b1l[threadIdx.x]; sb1r[threadIdx.x]=b1r[threadIdx.x]; }
    __syncthreads();
    int node = blockIdx.x*32 + (threadIdx.x>>3);
    if (node >= NN) return;
    int g = threadIdx.x & 7;
    float xd[5];
    #pragma unroll
    for (int k=0;k<5;k++) xd[k] = x[node*5+k];
    float cb[5], c1v[5];
    #pragma unroll
    for (int c=0;c<5;c++){
        float a = sbpre[c], b = 0.f;
        #pragma unroll
        for (int k=0;k<5;k++){
            a += xd[k]*sWpre[k*5+c];
            a += sbee[k]*sWpre[(10+k)*5+c];
            b += sWee[k]*sWpre[(10+k)*5+c];
        }
        cb[c]=a; c1v[c]=b;
    }
    int deg = cnt_d[node], base = off_d[node];
    float sum[5], ssq[5], mn[5], mx[5];
    #pragma unroll
    for (int c=0;c<5;c++){ sum[c]=0.f; ssq[c]=0.f; mn[c]=1e30f; mx[c]=-1e30f; }
    float wsum = 0.f;
    for (int j=g; j<deg; j+=8){
        int2 ent = bktd[base+j];
        int s = ent_node(ent);
        float w = ent_w(ent);
        wsum += w;
        float xs[5];
        #pragma unroll
        for (int k=0;k<5;k++) xs[k] = x[s*5+k];
        #pragma unroll
        for (int c=0;c<5;c++){
            float m = cb[c] + w*c1v[c];
            #pragma unroll
            for (int k=0;k<5;k++) m += xs[k]*sWpre[(5+k)*5+c];
            sum[c]+=m; ssq[c]+=m*m; mn[c]=fminf(mn[c],m); mx[c]=fmaxf(mx[c],m);
        }
    }
    #pragma unroll
    for (int st=1; st<8; st<<=1){
        #pragma unroll
        for (int c=0;c<5;c++){
            sum[c] += __shfl_xor(sum[c], st);
            ssq[c] += __shfl_xor(ssq[c], st);
            mn[c] = fminf(mn[c], __shfl_xor(mn[c], st));
            mx[c] = fmaxf(mx[c], __shfl_xor(mx[c], st));
        }
        wsum += __shfl_xor(wsum, st);
    }
    float c = (float)deg, cc = fmaxf(c, 1.f);
    float amp = __logf(cc+1.f) * (1.0f/AVG_DEG_LOG);
    float feat[65];
    #pragma unroll
    for (int k=0;k<5;k++) feat[k]=xd[k];
    #pragma unroll
    for (int j=0;j<5;j++){
        float mean = sum[j]/cc, msq = ssq[j]/cc;
        float sd = sqrtf(fmaxf(msq - mean*mean, 0.f) + 1e-5f);
        feat[5+j]=mean;
        feat[10+j]= (deg>0)? mn[j] : 0.f;
        feat[15+j]= (deg>0)? mx[j] : 0.f;
        feat[20+j]=sd;
    }
    #pragma unroll
    for (int j=0;j<20;j++){ feat[25+j]=feat[5+j]*amp; feat[45+j]=feat[5+j]/amp; }
    float t = sbpost[g];
    #pragma unroll
    for (int k=0;k<65;k++) t += feat[k]*sWpost[k*8+g];
    float nf = sbpna[g];
    #pragma unroll
    for (int k=0;k<8;k++) nf += __shfl(t, k, 8) * sWpna[k*8+g];
    float nfk[8];
    #pragma unroll
    for (int k=0;k<8;k++) nfk[k] = __shfl(nf, k, 8);
    #pragma unroll
    for (int u=0;u<2;u++){
        int o = 2*g+u;
        float a=sb1l[o], b2=sb1r[o];
        #pragma unroll
        for (int k=0;k<8;k++){ a += nfk[k]*sW1l[k*16+o]; b2 += nfk[k]*sW1r[k*16+o]; }
        xl1[node*16+o]=a; xr1[node*16+o]=b2;
    }
    if (g==0) ea_mean[node] = wsum/cc;
}

// ================= GAT layer 1 gather (online softmax, self-loop virtual edge) =================
__global__ __launch_bounds__(256) void k_gat1(
    const int* __restrict__ cnt_d, const int* __restrict__ off_d,
    const int2* __restrict__ bktd,
    const float* __restrict__ xl1, const float* __restrict__ xr1,
    const float* __restrict__ ea_mean,
    const float* __restrict__ We1, const float* __restrict__ att1, const float* __restrict__ bias1,
    const float* __restrict__ W2l, const float* __restrict__ b2l,
    const float* __restrict__ W2r, const float* __restrict__ b2r,
    _Float16* __restrict__ xl2h, float* __restrict__ xr2)
{
    __shared__ float sWe[16], sAtt[16], sBias[16], sW2l[512], sW2r[512], sb2l[32], sb2r[32];
    for (int t=threadIdx.x; t<512; t+=256){ sW2l[t]=W2l[t]; sW2r[t]=W2r[t]; }
    if (threadIdx.x<16){ sWe[threadIdx.x]=We1[threadIdx.x]; sAtt[threadIdx.x]=att1[threadIdx.x]; sBias[threadIdx.x]=bias1[threadIdx.x]; }
    if (threadIdx.x<32){ sb2l[threadIdx.x]=b2l[threadIdx.x]; sb2r[threadIdx.x]=b2r[threadIdx.x]; }
    __syncthreads();
    int node = blockIdx.x*32 + (threadIdx.x>>3);
    if (node >= NN) return;
    int g = threadIdx.x & 7;
    float xr[16];
    #pragma unroll
    for (int k=0;k<4;k++){
        float4 v = *(const float4*)(xr1 + node*16 + k*4);
        xr[k*4]=v.x; xr[k*4+1]=v.y; xr[k*4+2]=v.z; xr[k*4+3]=v.w;
    }
    int deg = cnt_d[node], base = off_d[node];
    float eam = ea_mean[node];
    float m[4], ss[4], acc[16];
    #pragma unroll
    for (int h=0;h<4;h++){ m[h]=-1e30f; ss[h]=0.f; }
    #pragma unroll
    for (int k=0;k<16;k++) acc[k]=0.f;
    for (int j=g; j<=deg; j+=8){
        bool selfe = (j==deg);
        int s; float w;
        if (selfe){ s = node; w = eam; }
        else { int2 ent = bktd[base+j]; s = ent_node(ent); w = ent_w(ent); }
        float xls[16];
        #pragma unroll
        for (int k=0;k<4;k++){
            float4 v = *(const float4*)(xl1 + s*16 + k*4);
            xls[k*4]=v.x; xls[k*4+1]=v.y; xls[k*4+2]=v.z; xls[k*4+3]=v.w;
        }
        #pragma unroll
        for (int h=0;h<4;h++){
            float a = 0.f;
            #pragma unroll
            for (int ch=0;ch<4;ch++){
                int idx = h*4+ch;
                a += lrelu(xls[idx] + xr[idx] + w*sWe[idx]) * sAtt[idx];
            }
            float mn2 = fmaxf(m[h], a);
            float corr = __expf(m[h]-mn2);
            float p = __expf(a-mn2);
            ss[h] = ss[h]*corr + p;
            #pragma unroll
            for (int ch=0;ch<4;ch++){
                int idx = h*4+ch;
                acc[idx] = acc[idx]*corr + p*xls[idx];
            }
            m[h] = mn2;
        }
    }
    #pragma unroll
    for (int st=1; st<8; st<<=1){
        #pragma unroll
        for (int h=0;h<4;h++){
            float mo = __shfl_xor(m[h], st);
            float so = __shfl_xor(ss[h], st);
            float mn2 = fmaxf(m[h], mo);
            float ca = __expf(m[h]-mn2), cbb = __expf(mo-mn2);
            ss[h] = ss[h]*ca + so*cbb;
            #pragma unroll
            for (int ch=0;ch<4;ch++){
                int idx=h*4+ch;
                float ao = __shfl_xor(acc[idx], st);
                acc[idx] = acc[idx]*ca + ao*cbb;
            }
            m[h]=mn2;
        }
    }
    float nf1[16];
    #pragma unroll
    for (int h=0;h<4;h++){
        float den = ss[h] + 1e-16f;
        #pragma unroll
        for (int ch=0;ch<4;ch++){
            int idx=h*4+ch;
            nf1[idx] = relu(acc[idx]/den + sBias[idx]);
        }
    }
    #pragma unroll
    for (int u=0;u<4;u++){
        int o = g + 8*u;
        float a=sb2l[o], b=sb2r[o];
        #pragma unroll
        for (int k=0;k<16;k++){ a += nf1[k]*sW2l[k*32+o]; b += nf1[k]*sW2r[k*32+o]; }
        xl2h[(size_t)node*32+o] = (_Float16)a;
        xr2[node*32+o]=b;
    }
}

// ================= GAT layer 2 gather + Wn MLP + We_fc projections =================
__global__ __launch_bounds__(256) void k_gat2(
    const int* __restrict__ cnt_d, const int* __restrict__ off_d,
    const int2* __restrict__ bktd,
    const _Float16* __restrict__ xl2h, const float* __restrict__ xr2,
    const float* __restrict__ ea_mean,
    const float* __restrict__ We2, const float* __restrict__ att2, const float* __restrict__ bias2,
    const float* __restrict__ Wn, const float* __restrict__ bn,
    const float* __restrict__ We_fc,
    _Float16* __restrict__ Ps16, float* __restrict__ Pd,
    float* __restrict__ Ps01, float* __restrict__ Pd01)
{
    __shared__ float sWe[32], sAtt[32], sBias[32], sWn[1024], sbn[32];
    __shared__ float sWsrc[1024], sWdst[1024];
    for (int t=threadIdx.x; t<1024; t+=256){
        sWn[t]=Wn[t];
        sWsrc[t]=We_fc[32 + t];
        sWdst[t]=We_fc[33*32 + t];
    }
    if (threadIdx.x<32){ sWe[threadIdx.x]=We2[threadIdx.x]; sAtt[threadIdx.x]=att2[threadIdx.x];
                         sBias[threadIdx.x]=bias2[threadIdx.x]; sbn[threadIdx.x]=bn[threadIdx.x]; }
    __syncthreads();
    int node = blockIdx.x*32 + (threadIdx.x>>3);
    if (node >= NN) return;
    int g = threadIdx.x & 7;
    float xr[32];
    #pragma unroll
    for (int k=0;k<8;k++){
        float4 v = *(const float4*)(xr2 + node*32 + k*4);
        xr[k*4]=v.x; xr[k*4+1]=v.y; xr[k*4+2]=v.z; xr[k*4+3]=v.w;
    }
    int deg = cnt_d[node], base = off_d[node];
    float eam = ea_mean[node];
    float m[4], ss[4], acc[32];
    #pragma unroll
    for (int h=0;h<4;h++){ m[h]=-1e30f; ss[h]=0.f; }
    #pragma unroll
    for (int k=0;k<32;k++) acc[k]=0.f;
    for (int j=g; j<=deg; j+=8){
        bool selfe = (j==deg);
        int s; float w;
        if (selfe){ s = node; w = eam; }
        else { int2 ent = bktd[base+j]; s = ent_node(ent); w = ent_w(ent); }
        float xls[32];
        const h4v* xp = (const h4v*)(xl2h + (size_t)s*32);
        #pragma unroll
        for (int k=0;k<8;k++){
            h4v hv = xp[k];
            xls[k*4]   = (float)hv.x;
            xls[k*4+1] = (float)hv.y;
            xls[k*4+2] = (float)hv.z;
            xls[k*4+3] = (float)hv.w;
        }
        #pragma unroll
        for (int h=0;h<4;h++){
            float a = 0.f;
            #pragma unroll
            for (int ch=0;ch<8;ch++){
                int idx = h*8+ch;
                a += lrelu(xls[idx] + xr[idx] + w*sWe[idx]) * sAtt[idx];
            }
            float mn2 = fmaxf(m[h], a);
            float corr = __expf(m[h]-mn2);
            float p = __expf(a-mn2);
            ss[h] = ss[h]*corr + p;
            #pragma unroll
            for (int ch=0;ch<8;ch++){
                int idx = h*8+ch;
                acc[idx] = acc[idx]*corr + p*xls[idx];
            }
            m[h] = mn2;
        }
    }
    #pragma unroll
    for (int st=1; st<8; st<<=1){
        #pragma unroll
        for (int h=0;h<4;h++){
            float mo = __shfl_xor(m[h], st);
            float so = __shfl_xor(ss[h], st);
            float mn2 = fmaxf(m[h], mo);
            float ca = __expf(m[h]-mn2), cbb = __expf(mo-mn2);
            ss[h] = ss[h]*ca + so*cbb;
            #pragma unroll
            for (int ch=0;ch<8;ch++){
                int idx=h*8+ch;
                float ao = __shfl_xor(acc[idx], st);
                acc[idx] = acc[idx]*ca + ao*cbb;
            }
            m[h]=mn2;
        }
    }
    float nf2[32];
    #pragma unroll
    for (int h=0;h<4;h++){
        float den = ss[h] + 1e-16f;
        #pragma unroll
        for (int ch=0;ch<8;ch++){
            int idx=h*8+ch;
            nf2[idx] = relu(acc[idx]/den + sBias[idx]);
        }
    }
    float mine[4];
    #pragma unroll
    for (int u=0;u<4;u++){
        int oo = g + 8*u;
        float a = sbn[oo];
        #pragma unroll
        for (int k=0;k<32;k++) a += nf2[k]*sWn[k*32+oo];
        mine[u] = relu(a);
    }
    float nfn[32];
    #pragma unroll
    for (int k=0;k<32;k++) nfn[k] = __shfl(mine[k>>3], k&7, 8);
    float pa[4], pb[4];
    #pragma unroll
    for (int u=0;u<4;u++){
        int oo = g + 8*u;
        float a=0.f, b=0.f;
        #pragma unroll
        for (int k=0;k<32;k++){ a += nfn[k]*sWsrc[k*32+oo]; b += nfn[k]*sWdst[k*32+oo]; }
        pa[u]=a; pb[u]=b;
        Ps16[(size_t)node*32+oo] = (_Float16)a;
        Pd[node*32+oo]=b;
    }
    float ps0=__shfl(pa[0],0,8), ps1=__shfl(pa[0],1,8);
    float pd0=__shfl(pb[0],0,8), pd1=__shfl(pb[0],1,8);
    if (g==0){
        *(float2*)(Ps01 + node*2) = make_float2(ps0, ps1);
        *(float2*)(Pd01 + node*2) = make_float2(pd0, pd1);
    }
}

// ================= per-src softmax stats (compact 4B entries) =================
__global__ __launch_bounds__(256) void k_src(
    const int* __restrict__ cnt_s, const int* __restrict__ off_s,
    const int* __restrict__ bkts,
    const float* __restrict__ Ps01, const float* __restrict__ Pd01,
    const float* __restrict__ We_fc, const float* __restrict__ be_fc,
    float* __restrict__ smax, float* __restrict__ sden)
{
    __shared__ float sW00, sW01, sbe0, sbe1;
    if (threadIdx.x == 0){ sW00=We_fc[0]; sW01=We_fc[1]; sbe0=be_fc[0]; sbe1=be_fc[1]; }
    __syncthreads();
    int node = blockIdx.x*32 + (threadIdx.x>>3);
    if (node >= NN) return;
    int g = threadIdx.x & 7;
    float2 p = *(const float2*)(Ps01 + node*2);
    float base0 = sbe0 + p.x, base1 = sbe1 + p.y;
    int deg = cnt_s[node], base = off_s[node];
    float m0=-1e30f, m1=-1e30f, s0=0.f, s1=0.f;
    for (int j=g; j<deg; j+=8){
        int ent = bkts[base+j];
        int d = cent_node(ent);
        float w = cent_w(ent);
        float2 q = *(const float2*)(Pd01 + d*2);
        float a0 = base0 + w*sW00 + q.x;
        float a1 = base1 + w*sW01 + q.y;
        float mn0 = fmaxf(m0, a0);
        s0 = s0*__expf(m0-mn0) + __expf(a0-mn0); m0 = mn0;
        float mn1 = fmaxf(m1, a1);
        s1 = s1*__expf(m1-mn1) + __expf(a1-mn1); m1 = mn1;
    }
    #pragma unroll
    for (int st=1; st<8; st<<=1){
        float mo = __shfl_xor(m0, st), so = __shfl_xor(s0, st);
        float mn = fmaxf(m0, mo);
        s0 = s0*__expf(m0-mn) + so*__expf(mo-mn); m0 = mn;
        mo = __shfl_xor(m1, st); so = __shfl_xor(s1, st);
        mn = fmaxf(m1, mo);
        s1 = s1*__expf(m1-mn) + so*__expf(mo-mn); m1 = mn;
    }
    if (g==0){ smax[node*2]=m0; smax[node*2+1]=m1; sden[node*2]=s0; sden[node*2+1]=s1; }
}

// ================= final edge scores (dst-sorted; Pd streams, Ps16 random) =================
__global__ __launch_bounds__(256) void k_scC2(
    const int* __restrict__ cnt_d, const int* __restrict__ off_d,
    const int2* __restrict__ bktd,
    const _Float16* __restrict__ Ps16, const float* __restrict__ Pd,
    const float* __restrict__ We_fc, const float* __restrict__ be_fc,
    const float* __restrict__ smax, const float* __restrict__ sden,
    float* __restrict__ out)
{
    __shared__ float sW0[32], sB[32];
    if (threadIdx.x < 32){ sW0[threadIdx.x]=We_fc[threadIdx.x]; sB[threadIdx.x]=be_fc[threadIdx.x]; }
    __syncthreads();
    int node = blockIdx.x*32 + (threadIdx.x>>3);
    if (node >= NN) return;
    int g = threadIdx.x & 7;
    float4 pd = *(const float4*)(Pd + (size_t)node*32 + g*4);
    float4 w0 = *(const float4*)(sW0 + g*4);
    float4 b0 = *(const float4*)(sB + g*4);
    b0.x += pd.x; b0.y += pd.y; b0.z += pd.z; b0.w += pd.w;
    int deg = cnt_d[node], base = off_d[node];
    for (int j=0; j<deg; ++j){
        int2 ent = bktd[base+j];
        int s = ent_node(ent);
        int e = ent_eid(ent);
        float w = ent_w(ent);
        h4v hv = *(const h4v*)(Ps16 + (size_t)s*32 + g*4);
        float ox = b0.x + w*w0.x + (float)hv.x;
        float oy = b0.y + w*w0.y + (float)hv.y;
        float oz = b0.z + w*w0.z + (float)hv.z;
        float ow = b0.w + w*w0.w + (float)hv.w;
        if (g == 0){
            float2 sm = *(const float2*)(smax + s*2);
            float2 sd = *(const float2*)(sden + s*2);
            ox = __expf(ox - sm.x) / (sd.x + 1e-16f);
            oy = __expf(oy - sm.y) / (sd.y + 1e-16f);
        }
        f4v ov; ov.x = ox; ov.y = oy; ov.z = oz; ov.w = ow;
        __builtin_nontemporal_store(ov, (f4v*)(out + (size_t)e*32 + g*4));
    }
}

extern "C" void kernel_launch(void* const* d_in, const int* in_sizes, int n_in,
                              void* d_out, int out_size, void* d_ws, size_t ws_size,
                              hipStream_t stream) {
    const float* x     = (const float*)d_in[0];
    const int*   ei    = (const int*)  d_in[1];
    const float* ea    = (const float*)d_in[2];
    const float* W_ee  = (const float*)d_in[3];  const float* b_ee  = (const float*)d_in[4];
    const float* W_pre = (const float*)d_in[5];  const float* b_pre = (const float*)d_in[6];
    const float* W_post= (const float*)d_in[7];  const float* b_post= (const float*)d_in[8];
    const float* W_pna = (const float*)d_in[9];  const float* b_pna = (const float*)d_in[10];
    const float* W1l   = (const float*)d_in[11]; const float* b1l   = (const float*)d_in[12];
    const float* W1r   = (const float*)d_in[13]; const float* b1r   = (const float*)d_in[14];
    const float* W1e   = (const float*)d_in[15]; const float* att1  = (const float*)d_in[16];
    const float* bias1 = (const float*)d_in[17];
    const float* W2l   = (const float*)d_in[18]; const float* b2l   = (const float*)d_in[19];
    const float* W2r   = (const float*)d_in[20]; const float* b2r   = (const float*)d_in[21];
    const float* W2e   = (const float*)d_in[22]; const float* att2  = (const float*)d_in[23];
    const float* bias2 = (const float*)d_in[24];
    const float* Wn    = (const float*)d_in[25]; const float* bn    = (const float*)d_in[26];
    const float* We_fc = (const float*)d_in[27]; const float* be_fc = (const float*)d_in[28];
    const int* src = ei;
    const int* dst = ei + NE;
    float* out = (float*)d_out;

    float* ws = (float*)d_ws;
    size_t o = 0;
    auto A = [&](size_t n){ size_t r = o; o = (o + n + 63) & ~(size_t)63; return r; };
    int*   cnt_d  = (int*)(ws + A(NN));
    int*   off_d  = (int*)(ws + A(NN));
    int*   cnt_s  = (int*)(ws + A(NN));
    int*   off_s  = (int*)(ws + A(NN));
    int*   cur_d  = (int*)(ws + A(NN));
    int*   cur_s  = (int*)(ws + A(NN));
    float* xl1    =        ws + A((size_t)NN*16);
    float* xr1    =        ws + A((size_t)NN*16);
    _Float16* xl2h = (_Float16*)(ws + A((size_t)NN*16));   // NN*32 halfs
    float* xr2    =        ws + A((size_t)NN*32);
    _Float16* Ps16 = (_Float16*)(ws + A((size_t)NN*16));   // NN*32 halfs
    float* Pd     =        ws + A((size_t)NN*32);
    float* ea_mean=        ws + A(NN);
    float* Ps01   =        ws + A((size_t)NN*2);
    float* Pd01   =        ws + A((size_t)NN*2);
    float* smax   =        ws + A((size_t)NN*2);
    float* sden   =        ws + A((size_t)NN*2);
    int*   histD  = (int*)(ws + A((size_t)NBIN*NCHUNK));
    int*   histS  = (int*)(ws + A((size_t)NBIN*NCHUNK));
    int*   baseD  = (int*)(ws + A((size_t)NBIN*NCHUNK));
    int*   baseS  = (int*)(ws + A((size_t)NBIN*NCHUNK));
    int*   binStartD = (int*)(ws + A(NBIN+1));
    int*   binStartS = (int*)(ws + A(NBIN+1));
    int2*  bufX = (int2*)(ws + A(2*(size_t)NE));   // final dst adjacency (8B)
    int*   bktsC = (int*)(ws + A((size_t)NE));     // final src adjacency (4B)
    size_t o_fallback = o;
    int2*  bufY = (int2*)(ws + A(2*(size_t)NE));   // coarse dst
    int2*  bufZ = (int2*)(ws + A(2*(size_t)NE));   // coarse src
    size_t o_sort = o;
    bool sortmode = (ws_size >= o_sort * sizeof(float));
    if (!sortmode && ws_size < o_fallback * sizeof(float)) return;  // fail loudly

    const int BS = 256;
    const int gridE = (NE + BS - 1)/BS;
    const int gridN = (NN + BS - 1)/BS;
    const int gridO = (NN + 31)/32;

    int2* bktd = bufX;
    int*  bkts = bktsC;
    if (sortmode){
        k_hist<<<NCHUNK, BS, 0, stream>>>(src, dst, histD, histS);
        k_scan2<<<2, 1024, 0, stream>>>(histD, histS, baseD, baseS, binStartD, binStartS);
        k_coarse<<<NCHUNK, BS, 0, stream>>>(src, dst, ea, baseD, baseS, bufY, bufZ);
        k_fine_d<<<NBIN, BS, 0, stream>>>(bufY, binStartD, bufX, cnt_d, off_d);
        k_fine_c<<<NBIN, BS, 0, stream>>>(bufZ, binStartS, bktsC, cnt_s, off_s);
    } else {
        k_zero<<<gridN, BS, 0, stream>>>(cnt_d, cnt_s);
        k_count<<<gridE, BS, 0, stream>>>(src, dst, cnt_d, cnt_s);
        k_scanCSR<<<2, 1024, 0, stream>>>(cnt_d, cnt_s, off_d, cur_d, off_s, cur_s);
        k_scatter<<<gridE, BS, 0, stream>>>(src, dst, ea, cur_d, cur_s, bufX, bktsC);
    }
    k_pna<<<gridO, BS, 0, stream>>>(x, cnt_d, off_d, bktd,
                                    W_ee, b_ee, W_pre, b_pre, W_post, b_post, W_pna, b_pna,
                                    W1l, b1l, W1r, b1r, xl1, xr1, ea_mean);
    k_gat1<<<gridO, BS, 0, stream>>>(cnt_d, off_d, bktd, xl1, xr1, ea_mean,
                                     W1e, att1, bias1, W2l, b2l, W2r, b2r, xl2h, xr2);
    k_gat2<<<gridO, BS, 0, stream>>>(cnt_d, off_d, bktd, xl2h, xr2, ea_mean,
                                     W2e, att2, bias2, Wn, bn, We_fc,
                                     Ps16, Pd, Ps01, Pd01);
    k_src<<<gridO, BS, 0, stream>>>(cnt_s, off_s, bkts, Ps01, Pd01, We_fc, be_fc, smax, sden);
    k_scC2<<<gridO, BS, 0, stream>>>(cnt_d, off_d, bktd, Ps16, Pd, We_fc, be_fc, smax, sden, out);
}

// Round 8
// 298.814 us; speedup vs baseline: 24.2722x; 1.2218x over previous
//
#include <hip/hip_runtime.h>
#include <math.h>

#define NN 50000
#define NE 1600000
#define AVG_DEG_LOG 3.4965075614664802f
#define NBIN 196            // (NN+255)/256
#define CHUNK 4096
#define NCHUNK 391          // (NE+CHUNK-1)/CHUNK

typedef float f4v __attribute__((ext_vector_type(4)));
typedef _Float16 h4v __attribute__((ext_vector_type(4)));

__device__ __forceinline__ float lrelu(float x){ return x > 0.f ? x : 0.2f*x; }
__device__ __forceinline__ float relu(float x){ return x > 0.f ? x : 0.f; }

// 8-byte bucket entry (dst direction, post-fine):
//   x = node(16b) | e_low16 << 16
//   y = [coarse only: local8 << 24] | e_hi5 << 19 | w_q19
__device__ __forceinline__ int ent_node(int2 ent){ return ent.x & 0xFFFF; }
__device__ __forceinline__ int ent_eid(int2 ent){
    return (int)(((unsigned)ent.x >> 16) | ((((unsigned)ent.y >> 19) & 31u) << 16));
}
__device__ __forceinline__ float ent_w(int2 ent){
    return ((float)((unsigned)ent.y & 0x7FFFFu) + 0.5f) * (1.0f/524288.0f);
}
__device__ __forceinline__ unsigned quant_w(float w){
    unsigned wq = (unsigned)(w * 524288.f);
    return wq > 524287u ? 524287u : wq;
}
// 4-byte compact entry (src direction, fallback path): node16 | wq16<<16
__device__ __forceinline__ int cent_node(int e){ return e & 0xFFFF; }
__device__ __forceinline__ float cent_w(int e){
    return ((float)(((unsigned)e >> 16) & 0xFFFFu) + 0.5f) * (1.0f/65536.0f);
}
// order-preserving float<->uint encoding (for LDS atomicMax on floats)
__device__ __forceinline__ unsigned fenc(float f){
    unsigned b = __float_as_uint(f);
    return (b & 0x80000000u) ? ~b : (b | 0x80000000u);
}
__device__ __forceinline__ float fdec(unsigned u){
    unsigned b = (u & 0x80000000u) ? (u & 0x7FFFFFFFu) : ~u;
    return __uint_as_float(b);
}

// ================= two-level counting sort (no global atomics) =================

__global__ __launch_bounds__(256) void k_hist(const int* __restrict__ src, const int* __restrict__ dst,
                                              int* __restrict__ histD, int* __restrict__ histS){
    __shared__ int hd[NBIN], hs[NBIN];
    for (int t=threadIdx.x; t<NBIN; t+=256){ hd[t]=0; hs[t]=0; }
    __syncthreads();
    int chunk = blockIdx.x;
    int e0 = chunk*CHUNK, e1 = min(e0+CHUNK, NE);
    for (int e=e0+threadIdx.x; e<e1; e+=256){
        atomicAdd(&hd[dst[e]>>8], 1);
        atomicAdd(&hs[src[e]>>8], 1);
    }
    __syncthreads();
    for (int t=threadIdx.x; t<NBIN; t+=256){
        histD[t*NCHUNK+chunk] = hd[t];
        histS[t*NCHUNK+chunk] = hs[t];
    }
}

// stage 1: per-bin totals (grid = 2*NBIN)
__global__ __launch_bounds__(256) void k_binsum(const int* __restrict__ histD, const int* __restrict__ histS,
                                                int* __restrict__ binTotal){
    __shared__ int wsum[4];
    int dir = blockIdx.x / NBIN, bin = blockIdx.x % NBIN;
    const int* hist = dir ? histS : histD;
    int s = 0;
    for (int t=threadIdx.x; t<NCHUNK; t+=256) s += hist[bin*NCHUNK + t];
    #pragma unroll
    for (int st=32; st>=1; st>>=1) s += __shfl_xor(s, st);
    if ((threadIdx.x & 63) == 0) wsum[threadIdx.x>>6] = s;
    __syncthreads();
    if (threadIdx.x == 0) binTotal[dir*NBIN + bin] = wsum[0]+wsum[1]+wsum[2]+wsum[3];
}

// stage 2: scan bin totals (1 block, both directions)
__global__ __launch_bounds__(256) void k_scanbins(const int* __restrict__ binTotal,
                                                  int* __restrict__ binStartD, int* __restrict__ binStartS){
    __shared__ int wsums[4];
    int tid = threadIdx.x, lane = tid & 63, wv = tid >> 6;
    for (int dir = 0; dir < 2; ++dir){
        int* binStart = dir ? binStartS : binStartD;
        int v = (tid < NBIN) ? binTotal[dir*NBIN + tid] : 0;
        int sc = v;
        for (int d = 1; d < 64; d <<= 1){
            int t = __shfl_up(sc, d, 64);
            if (lane >= d) sc += t;
        }
        if (lane == 63) wsums[wv] = sc;
        __syncthreads();
        int woff = 0;
        #pragma unroll
        for (int k = 0; k < 4; ++k) woff += (k < wv) ? wsums[k] : 0;
        int excl = woff + sc - v;
        if (tid < NBIN) binStart[tid] = excl;
        if (tid == 0) binStart[NBIN] = NE;
        __syncthreads();
    }
}

// stage 3: per-bin prefix over chunks (grid = 2*NBIN)
__global__ __launch_bounds__(256) void k_chunkpfx(const int* __restrict__ histD, const int* __restrict__ histS,
                                                  const int* __restrict__ binStartD, const int* __restrict__ binStartS,
                                                  int* __restrict__ baseD, int* __restrict__ baseS){
    __shared__ int wsums[4];
    int dir = blockIdx.x / NBIN, bin = blockIdx.x % NBIN;
    const int* hist = dir ? histS : histD;
    const int* binStart = dir ? binStartS : binStartD;
    int* base = dir ? baseS : baseD;
    int tid = threadIdx.x, lane = tid & 63, wv = tid >> 6;
    int i0 = tid*2, i1 = tid*2+1;
    int a = (i0 < NCHUNK) ? hist[bin*NCHUNK + i0] : 0;
    int b = (i1 < NCHUNK) ? hist[bin*NCHUNK + i1] : 0;
    int v = a + b;
    int sc = v;
    for (int d = 1; d < 64; d <<= 1){
        int t = __shfl_up(sc, d, 64);
        if (lane >= d) sc += t;
    }
    if (lane == 63) wsums[wv] = sc;
    __syncthreads();
    int woff = 0;
    #pragma unroll
    for (int k = 0; k < 4; ++k) woff += (k < wv) ? wsums[k] : 0;
    int excl = binStart[bin] + woff + sc - v;
    if (i0 < NCHUNK) base[bin*NCHUNK + i0] = excl;
    if (i1 < NCHUNK) base[bin*NCHUNK + i1] = excl + a;
}

__global__ __launch_bounds__(256) void k_coarse(const int* __restrict__ src, const int* __restrict__ dst,
                                                const float* __restrict__ ea,
                                                const int* __restrict__ baseD, const int* __restrict__ baseS,
                                                int2* __restrict__ cD, int2* __restrict__ cS){
    __shared__ int curd[NBIN], curs[NBIN];
    int chunk = blockIdx.x;
    for (int t=threadIdx.x; t<NBIN; t+=256){
        curd[t] = baseD[t*NCHUNK+chunk];
        curs[t] = baseS[t*NCHUNK+chunk];
    }
    __syncthreads();
    int e0 = chunk*CHUNK, e1 = min(e0+CHUNK, NE);
    for (int e=e0+threadIdx.x; e<e1; e+=256){
        int s = src[e], d = dst[e];
        unsigned wq = quant_w(ea[e]);
        unsigned elo = (unsigned)(e & 0xFFFF) << 16;
        unsigned ehi = ((unsigned)e >> 16) << 19;
        int pd = atomicAdd(&curd[d>>8], 1);
        cD[pd] = make_int2((int)((unsigned)s | elo), (int)(((unsigned)(d & 255) << 24) | ehi | wq));
        int ps = atomicAdd(&curs[s>>8], 1);
        cS[ps] = make_int2((int)((unsigned)d | elo), (int)(((unsigned)(s & 255) << 24) | ehi | wq));
    }
}

// fine sort, dst direction: 8B entries out (keeps eid)
__global__ __launch_bounds__(256) void k_fine_d(const int2* __restrict__ cin,
                                                const int* __restrict__ binStart,
                                                int2* __restrict__ bout,
                                                int* __restrict__ cnt, int* __restrict__ off){
    __shared__ int h[256], cur[256];
    __shared__ int ws4[4];
    int bin = blockIdx.x;
    int S = binStart[bin], E = binStart[bin+1];
    h[threadIdx.x] = 0;
    __syncthreads();
    for (int i = S + threadIdx.x; i < E; i += 256){
        unsigned y = (unsigned)cin[i].y;
        atomicAdd(&h[y >> 24], 1);
    }
    __syncthreads();
    int v = h[threadIdx.x];
    int lane = threadIdx.x & 63, wv = threadIdx.x >> 6;
    int sc = v;
    for (int d = 1; d < 64; d <<= 1){
        int t = __shfl_up(sc, d, 64);
        if (lane >= d) sc += t;
    }
    if (lane == 63) ws4[wv] = sc;
    __syncthreads();
    int woff = 0;
    #pragma unroll
    for (int k = 0; k < 4; ++k) woff += (k < wv) ? ws4[k] : 0;
    int excl = woff + sc - v;
    cur[threadIdx.x] = S + excl;
    int node = (bin << 8) + threadIdx.x;
    if (node < NN){ cnt[node] = v; off[node] = S + excl; }
    __syncthreads();
    for (int i = S + threadIdx.x; i < E; i += 256){
        int2 ent = cin[i];
        unsigned y = (unsigned)ent.y;
        int local = y >> 24;
        int pos = atomicAdd(&cur[local], 1);
        bout[pos] = make_int2(ent.x, (int)(y & 0x00FFFFFFu));
    }
}

// ================= fallback CSR path (atomic scatter) =================

__global__ void k_zero(int* cnt_d, int* cnt_s){
    int i = blockIdx.x*blockDim.x + threadIdx.x;
    if (i < NN){ cnt_d[i]=0; cnt_s[i]=0; }
}

__global__ void k_count(const int* __restrict__ src, const int* __restrict__ dst,
                        int* cnt_d, int* cnt_s){
    int e = blockIdx.x*blockDim.x + threadIdx.x;
    if (e >= NE) return;
    atomicAdd(&cnt_d[dst[e]], 1);
    atomicAdd(&cnt_s[src[e]], 1);
}

__global__ __launch_bounds__(1024) void k_scanCSR(const int* __restrict__ cnt_d, const int* __restrict__ cnt_s,
                                                  int* off_d, int* cur_d, int* off_s, int* cur_s){
    __shared__ int wsums[16];
    __shared__ int carry_s;
    const int tid = threadIdx.x, lane = tid & 63, wv = tid >> 6;
    const int pass = blockIdx.x;
    const int* cnt = pass ? cnt_s : cnt_d;
    int* off = pass ? off_s : off_d;
    int* cur = pass ? cur_s : cur_d;
    if (tid == 0) carry_s = 0;
    __syncthreads();
    for (int base = 0; base < NN; base += 4096){
        int i0 = base + tid*4;
        int v0 = (i0+0 < NN) ? cnt[i0+0] : 0;
        int v1 = (i0+1 < NN) ? cnt[i0+1] : 0;
        int v2 = (i0+2 < NN) ? cnt[i0+2] : 0;
        int v3 = (i0+3 < NN) ? cnt[i0+3] : 0;
        int tsum = v0+v1+v2+v3;
        int sc = tsum;
        for (int d = 1; d < 64; d <<= 1){
            int t = __shfl_up(sc, d, 64);
            if (lane >= d) sc += t;
        }
        if (lane == 63) wsums[wv] = sc;
        __syncthreads();
        int woff = 0;
        #pragma unroll
        for (int k = 0; k < 16; ++k) woff += (k < wv) ? wsums[k] : 0;
        int carry_in = carry_s;
        __syncthreads();
        if (tid == 1023) carry_s = carry_in + woff + sc;
        int excl = carry_in + woff + (sc - tsum);
        int e0 = excl, e1 = e0+v0, e2 = e1+v1, e3 = e2+v2;
        if (i0+0 < NN){ off[i0+0]=e0; cur[i0+0]=e0; }
        if (i0+1 < NN){ off[i0+1]=e1; cur[i0+1]=e1; }
        if (i0+2 < NN){ off[i0+2]=e2; cur[i0+2]=e2; }
        if (i0+3 < NN){ off[i0+3]=e3; cur[i0+3]=e3; }
        __syncthreads();
    }
}

__global__ void k_scatter(const int* __restrict__ src, const int* __restrict__ dst,
                          const float* __restrict__ ea,
                          int* cur_d, int* cur_s,
                          int2* bktd, int* bkts){
    int e = blockIdx.x*blockDim.x + threadIdx.x;
    if (e >= NE) return;
    int s = src[e], d = dst[e];
    unsigned wq = quant_w(ea[e]);
    unsigned elo = (unsigned)(e & 0xFFFF) << 16;
    unsigned yv  = (((unsigned)e >> 16) << 19) | wq;
    int p = atomicAdd(&cur_d[d], 1);
    bktd[p] = make_int2((int)((unsigned)s | elo), (int)yv);
    int q = atomicAdd(&cur_s[s], 1);
    bkts[q] = (int)(((unsigned)d & 0xFFFFu) | ((wq >> 3) << 16));
}

// ================= PNA gather + finalize + GAT1 transforms (8 lanes/node) =================
__global__ __launch_bounds__(256) void k_pna(
    const float* __restrict__ x,
    const int* __restrict__ cnt_d, const int* __restrict__ off_d,
    const int2* __restrict__ bktd,
    const float* __restrict__ W_ee, const float* __restrict__ b_ee,
    const float* __restrict__ W_pre, const float* __restrict__ b_pre,
    const float* __restrict__ W_post, const float* __restrict__ b_post,
    const float* __restrict__ W_pna, const float* __restrict__ b_pna,
    const float* __restrict__ W1l, const float* __restrict__ b1l,
    const float* __restrict__ W1r, const float* __restrict__ b1r,
    float* __restrict__ xl1, float* __restrict__ xr1, float* __restrict__ ea_mean)
{
    __shared__ float sWpre[75], sWpost[520], sWpna[64], sW1l[128], sW1r[128];
    __shared__ float sbpre[5], sWee[5], sbee[5], sbpost[8], sbpna[8], sb1l[16], sb1r[16];
    for (int t=threadIdx.x; t<75;  t+=256) sWpre[t]=W_pre[t];
    for (int t=threadIdx.x; t<520; t+=256) sWpost[t]=W_post[t];
    for (int t=threadIdx.x; t<64;  t+=256) sWpna[t]=W_pna[t];
    for (int t=threadIdx.x; t<128; t+=256){ sW1l[t]=W1l[t]; sW1r[t]=W1r[t]; }
    if (threadIdx.x<5){ sbpre[threadIdx.x]=b_pre[threadIdx.x]; sWee[threadIdx.x]=W_ee[threadIdx.x]; sbee[threadIdx.x]=b_ee[threadIdx.x]; }
    if (threadIdx.x<8){ sbpost[threadIdx.x]=b_post[threadIdx.x]; sbpna[threadIdx.x]=b_pna[threadIdx.x]; }
    if (threadIdx.x<16){ sb1l[threadIdx.x]=b1l[threadIdx.x]; sb1r[threadIdx.x]=b1r[threadIdx.x]; }
    __syncthreads();
    int node = blockIdx.x*32 + (threadIdx.x>>3);
    if (node >= NN) return;
    int g = threadIdx.x & 7;
    float xd[5];
    #pragma unroll
    for (int k=0;k<5;k++) xd[k] = x[node*5+k];
    float cb[5], c1v[5];
    #pragma unroll
    for (int c=0;c<5;c++){
        float a = sbpre[c], b = 0.f;
        #pragma unroll
        for (int k=0;k<5;k++){
            a += xd[k]*sWpre[k*5+c];
            a += sbee[k]*sWpre[(10+k)*5+c];
            b += sWee[k]*sWpre[(10+k)*5+c];
        }
        cb[c]=a; c1v[c]=b;
    }
    int deg = cnt_d[node], base = off_d[node];
    float sum[5], ssq[5], mn[5], mx[5];
    #pragma unroll
    for (int c=0;c<5;c++){ sum[c]=0.f; ssq[c]=0.f; mn[c]=1e30f; mx[c]=-1e30f; }
    float wsum = 0.f;
    for (int j=g; j<deg; j+=8){
        int2 ent = bktd[base+j];
        int s = ent_node(ent);
        float w = ent_w(ent);
        wsum += w;
        float xs[5];
        #pragma unroll
        for (int k=0;k<5;k++) xs[k] = x[s*5+k];
        #pragma unroll
        for (int c=0;c<5;c++){
            float m = cb[c] + w*c1v[c];
            #pragma unroll
            for (int k=0;k<5;k++) m += xs[k]*sWpre[(5+k)*5+c];
            sum[c]+=m; ssq[c]+=m*m; mn[c]=fminf(mn[c],m); mx[c]=fmaxf(mx[c],m);
        }
    }
    #pragma unroll
    for (int st=1; st<8; st<<=1){
        #pragma unroll
        for (int c=0;c<5;c++){
            sum[c] += __shfl_xor(sum[c], st);
            ssq[c] += __shfl_xor(ssq[c], st);
            mn[c] = fminf(mn[c], __shfl_xor(mn[c], st));
            mx[c] = fmaxf(mx[c], __shfl_xor(mx[c], st));
        }
        wsum += __shfl_xor(wsum, st);
    }
    float c = (float)deg, cc = fmaxf(c, 1.f);
    float amp = __logf(cc+1.f) * (1.0f/AVG_DEG_LOG);
    float feat[65];
    #pragma unroll
    for (int k=0;k<5;k++) feat[k]=xd[k];
    #pragma unroll
    for (int j=0;j<5;j++){
        float mean = sum[j]/cc, msq = ssq[j]/cc;
        float sd = sqrtf(fmaxf(msq - mean*mean, 0.f) + 1e-5f);
        feat[5+j]=mean;
        feat[10+j]= (deg>0)? mn[j] : 0.f;
        feat[15+j]= (deg>0)? mx[j] : 0.f;
        feat[20+j]=sd;
    }
    #pragma unroll
    for (int j=0;j<20;j++){ feat[25+j]=feat[5+j]*amp; feat[45+j]=feat[5+j]/amp; }
    float t = sbpost[g];
    #pragma unroll
    for (int k=0;k<65;k++) t += feat[k]*sWpost[k*8+g];
    float nf = sbpna[g];
    #pragma unroll
    for (int k=0;k<8;k++) nf += __shfl(t, k, 8) * sWpna[k*8+g];
    float nfk[8];
    #pragma unroll
    for (int k=0;k<8;k++) nfk[k] = __shfl(nf, k, 8);
    #pragma unroll
    for (int u=0;u<2;u++){
        int o = 2*g+u;
        float a=sb1l[o], b2=sb1r[o];
        #pragma unroll
        for (int k=0;k<8;k++){ a += nfk[k]*sW1l[k*16+o]; b2 += nfk[k]*sW1r[k*16+o]; }
        xl1[node*16+o]=a; xr1[node*16+o]=b2;
    }
    if (g==0) ea_mean[node] = wsum/cc;
}

// ================= GAT layer 1 gather (online softmax, self-loop virtual edge) =================
__global__ __launch_bounds__(256) void k_gat1(
    const int* __restrict__ cnt_d, const int* __restrict__ off_d,
    const int2* __restrict__ bktd,
    const float* __restrict__ xl1, const float* __restrict__ xr1,
    const float* __restrict__ ea_mean,
    const float* __restrict__ We1, const float* __restrict__ att1, const float* __restrict__ bias1,
    const float* __restrict__ W2l, const float* __restrict__ b2l,
    const float* __restrict__ W2r, const float* __restrict__ b2r,
    _Float16* __restrict__ xl2h, float* __restrict__ xr2)
{
    __shared__ float sWe[16], sAtt[16], sBias[16], sW2l[512], sW2r[512], sb2l[32], sb2r[32];
    for (int t=threadIdx.x; t<512; t+=256){ sW2l[t]=W2l[t]; sW2r[t]=W2r[t]; }
    if (threadIdx.x<16){ sWe[threadIdx.x]=We1[threadIdx.x]; sAtt[threadIdx.x]=att1[threadIdx.x]; sBias[threadIdx.x]=bias1[threadIdx.x]; }
    if (threadIdx.x<32){ sb2l[threadIdx.x]=b2l[threadIdx.x]; sb2r[threadIdx.x]=b2r[threadIdx.x]; }
    __syncthreads();
    int node = blockIdx.x*32 + (threadIdx.x>>3);
    if (node >= NN) return;
    int g = threadIdx.x & 7;
    float xr[16];
    #pragma unroll
    for (int k=0;k<4;k++){
        float4 v = *(const float4*)(xr1 + node*16 + k*4);
        xr[k*4]=v.x; xr[k*4+1]=v.y; xr[k*4+2]=v.z; xr[k*4+3]=v.w;
    }
    int deg = cnt_d[node], base = off_d[node];
    float eam = ea_mean[node];
    float m[4], ss[4], acc[16];
    #pragma unroll
    for (int h=0;h<4;h++){ m[h]=-1e30f; ss[h]=0.f; }
    #pragma unroll
    for (int k=0;k<16;k++) acc[k]=0.f;
    for (int j=g; j<=deg; j+=8){
        bool selfe = (j==deg);
        int s; float w;
        if (selfe){ s = node; w = eam; }
        else { int2 ent = bktd[base+j]; s = ent_node(ent); w = ent_w(ent); }
        float xls[16];
        #pragma unroll
        for (int k=0;k<4;k++){
            float4 v = *(const float4*)(xl1 + s*16 + k*4);
            xls[k*4]=v.x; xls[k*4+1]=v.y; xls[k*4+2]=v.z; xls[k*4+3]=v.w;
        }
        #pragma unroll
        for (int h=0;h<4;h++){
            float a = 0.f;
            #pragma unroll
            for (int ch=0;ch<4;ch++){
                int idx = h*4+ch;
                a += lrelu(xls[idx] + xr[idx] + w*sWe[idx]) * sAtt[idx];
            }
            float mn2 = fmaxf(m[h], a);
            float corr = __expf(m[h]-mn2);
            float p = __expf(a-mn2);
            ss[h] = ss[h]*corr + p;
            #pragma unroll
            for (int ch=0;ch<4;ch++){
                int idx = h*4+ch;
                acc[idx] = acc[idx]*corr + p*xls[idx];
            }
            m[h] = mn2;
        }
    }
    #pragma unroll
    for (int st=1; st<8; st<<=1){
        #pragma unroll
        for (int h=0;h<4;h++){
            float mo = __shfl_xor(m[h], st);
            float so = __shfl_xor(ss[h], st);
            float mn2 = fmaxf(m[h], mo);
            float ca = __expf(m[h]-mn2), cbb = __expf(mo-mn2);
            ss[h] = ss[h]*ca + so*cbb;
            #pragma unroll
            for (int ch=0;ch<4;ch++){
                int idx=h*4+ch;
                float ao = __shfl_xor(acc[idx], st);
                acc[idx] = acc[idx]*ca + ao*cbb;
            }
            m[h]=mn2;
        }
    }
    float nf1[16];
    #pragma unroll
    for (int h=0;h<4;h++){
        float den = ss[h] + 1e-16f;
        #pragma unroll
        for (int ch=0;ch<4;ch++){
            int idx=h*4+ch;
            nf1[idx] = relu(acc[idx]/den + sBias[idx]);
        }
    }
    #pragma unroll
    for (int u=0;u<4;u++){
        int o = g + 8*u;
        float a=sb2l[o], b=sb2r[o];
        #pragma unroll
        for (int k=0;k<16;k++){ a += nf1[k]*sW2l[k*32+o]; b += nf1[k]*sW2r[k*32+o]; }
        xl2h[(size_t)node*32+o] = (_Float16)a;
        xr2[node*32+o]=b;
    }
}

// ================= GAT layer 2 gather + Wn MLP + We_fc projections =================
__global__ __launch_bounds__(256) void k_gat2(
    const int* __restrict__ cnt_d, const int* __restrict__ off_d,
    const int2* __restrict__ bktd,
    const _Float16* __restrict__ xl2h, const float* __restrict__ xr2,
    const float* __restrict__ ea_mean,
    const float* __restrict__ We2, const float* __restrict__ att2, const float* __restrict__ bias2,
    const float* __restrict__ Wn, const float* __restrict__ bn,
    const float* __restrict__ We_fc,
    _Float16* __restrict__ Ps16, float* __restrict__ Pd,
    float* __restrict__ Ps01, float* __restrict__ Pd01)
{
    __shared__ float sWe[32], sAtt[32], sBias[32], sWn[1024], sbn[32];
    __shared__ float sWsrc[1024], sWdst[1024];
    for (int t=threadIdx.x; t<1024; t+=256){
        sWn[t]=Wn[t];
        sWsrc[t]=We_fc[32 + t];
        sWdst[t]=We_fc[33*32 + t];
    }
    if (threadIdx.x<32){ sWe[threadIdx.x]=We2[threadIdx.x]; sAtt[threadIdx.x]=att2[threadIdx.x];
                         sBias[threadIdx.x]=bias2[threadIdx.x]; sbn[threadIdx.x]=bn[threadIdx.x]; }
    __syncthreads();
    int node = blockIdx.x*32 + (threadIdx.x>>3);
    if (node >= NN) return;
    int g = threadIdx.x & 7;
    float xr[32];
    #pragma unroll
    for (int k=0;k<8;k++){
        float4 v = *(const float4*)(xr2 + node*32 + k*4);
        xr[k*4]=v.x; xr[k*4+1]=v.y; xr[k*4+2]=v.z; xr[k*4+3]=v.w;
    }
    int deg = cnt_d[node], base = off_d[node];
    float eam = ea_mean[node];
    float m[4], ss[4], acc[32];
    #pragma unroll
    for (int h=0;h<4;h++){ m[h]=-1e30f; ss[h]=0.f; }
    #pragma unroll
    for (int k=0;k<32;k++) acc[k]=0.f;
    for (int j=g; j<=deg; j+=8){
        bool selfe = (j==deg);
        int s; float w;
        if (selfe){ s = node; w = eam; }
        else { int2 ent = bktd[base+j]; s = ent_node(ent); w = ent_w(ent); }
        float xls[32];
        const h4v* xp = (const h4v*)(xl2h + (size_t)s*32);
        #pragma unroll
        for (int k=0;k<8;k++){
            h4v hv = xp[k];
            xls[k*4]   = (float)hv.x;
            xls[k*4+1] = (float)hv.y;
            xls[k*4+2] = (float)hv.z;
            xls[k*4+3] = (float)hv.w;
        }
        #pragma unroll
        for (int h=0;h<4;h++){
            float a = 0.f;
            #pragma unroll
            for (int ch=0;ch<8;ch++){
                int idx = h*8+ch;
                a += lrelu(xls[idx] + xr[idx] + w*sWe[idx]) * sAtt[idx];
            }
            float mn2 = fmaxf(m[h], a);
            float corr = __expf(m[h]-mn2);
            float p = __expf(a-mn2);
            ss[h] = ss[h]*corr + p;
            #pragma unroll
            for (int ch=0;ch<8;ch++){
                int idx = h*8+ch;
                acc[idx] = acc[idx]*corr + p*xls[idx];
            }
            m[h] = mn2;
        }
    }
    #pragma unroll
    for (int st=1; st<8; st<<=1){
        #pragma unroll
        for (int h=0;h<4;h++){
            float mo = __shfl_xor(m[h], st);
            float so = __shfl_xor(ss[h], st);
            float mn2 = fmaxf(m[h], mo);
            float ca = __expf(m[h]-mn2), cbb = __expf(mo-mn2);
            ss[h] = ss[h]*ca + so*cbb;
            #pragma unroll
            for (int ch=0;ch<8;ch++){
                int idx=h*8+ch;
                float ao = __shfl_xor(acc[idx], st);
                acc[idx] = acc[idx]*ca + ao*cbb;
            }
            m[h]=mn2;
        }
    }
    float nf2[32];
    #pragma unroll
    for (int h=0;h<4;h++){
        float den = ss[h] + 1e-16f;
        #pragma unroll
        for (int ch=0;ch<8;ch++){
            int idx=h*8+ch;
            nf2[idx] = relu(acc[idx]/den + sBias[idx]);
        }
    }
    float mine[4];
    #pragma unroll
    for (int u=0;u<4;u++){
        int oo = g + 8*u;
        float a = sbn[oo];
        #pragma unroll
        for (int k=0;k<32;k++) a += nf2[k]*sWn[k*32+oo];
        mine[u] = relu(a);
    }
    float nfn[32];
    #pragma unroll
    for (int k=0;k<32;k++) nfn[k] = __shfl(mine[k>>3], k&7, 8);
    float pa[4], pb[4];
    #pragma unroll
    for (int u=0;u<4;u++){
        int oo = g + 8*u;
        float a=0.f, b=0.f;
        #pragma unroll
        for (int k=0;k<32;k++){ a += nfn[k]*sWsrc[k*32+oo]; b += nfn[k]*sWdst[k*32+oo]; }
        pa[u]=a; pb[u]=b;
        Ps16[(size_t)node*32+oo] = (_Float16)a;
        Pd[node*32+oo]=b;
    }
    float ps0=__shfl(pa[0],0,8), ps1=__shfl(pa[0],1,8);
    float pd0=__shfl(pb[0],0,8), pd1=__shfl(pb[0],1,8);
    if (g==0){
        *(float2*)(Ps01 + node*2) = make_float2(ps0, ps1);
        *(float2*)(Pd01 + node*2) = make_float2(pd0, pd1);
    }
}

// ================= per-src softmax stats from COARSE src buffer (sortmode) =================
__global__ __launch_bounds__(1024) void k_src_bins(
    const int2* __restrict__ cS, const int* __restrict__ binStartS,
    const float* __restrict__ Ps01, const float* __restrict__ Pd01,
    const float* __restrict__ We_fc, const float* __restrict__ be_fc,
    float* __restrict__ smax, float* __restrict__ sden)
{
    __shared__ float sPs0[256], sPs1[256];
    __shared__ unsigned sM0[256], sM1[256];
    __shared__ float sS0[256], sS1[256];
    __shared__ float cW00, cW01, cbe0, cbe1;
    int bin = blockIdx.x, tid = threadIdx.x;
    if (tid == 0){ cW00=We_fc[0]; cW01=We_fc[1]; cbe0=be_fc[0]; cbe1=be_fc[1]; }
    if (tid < 256){
        int node = (bin<<8) + tid;
        float2 p = (node < NN) ? *(const float2*)(Ps01 + node*2) : make_float2(0.f,0.f);
        sPs0[tid]=p.x; sPs1[tid]=p.y;
        sM0[tid]=fenc(-1e30f); sM1[tid]=fenc(-1e30f);
        sS0[tid]=0.f; sS1[tid]=0.f;
    }
    __syncthreads();
    int S = binStartS[bin], E = binStartS[bin+1];
    // pass 1: per-node max
    for (int i = S + tid; i < E; i += 1024){
        int2 ent = cS[i];
        unsigned y = (unsigned)ent.y;
        int local = y >> 24;
        int d = ent.x & 0xFFFF;
        float w = ((float)(y & 0x7FFFFu) + 0.5f) * (1.0f/524288.0f);
        float2 q = *(const float2*)(Pd01 + d*2);
        float a0 = cbe0 + sPs0[local] + w*cW00 + q.x;
        float a1 = cbe1 + sPs1[local] + w*cW01 + q.y;
        atomicMax(&sM0[local], fenc(a0));
        atomicMax(&sM1[local], fenc(a1));
    }
    __syncthreads();
    // pass 2: exp-sum
    for (int i = S + tid; i < E; i += 1024){
        int2 ent = cS[i];
        unsigned y = (unsigned)ent.y;
        int local = y >> 24;
        int d = ent.x & 0xFFFF;
        float w = ((float)(y & 0x7FFFFu) + 0.5f) * (1.0f/524288.0f);
        float2 q = *(const float2*)(Pd01 + d*2);
        float a0 = cbe0 + sPs0[local] + w*cW00 + q.x;
        float a1 = cbe1 + sPs1[local] + w*cW01 + q.y;
        atomicAdd(&sS0[local], __expf(a0 - fdec(sM0[local])));
        atomicAdd(&sS1[local], __expf(a1 - fdec(sM1[local])));
    }
    __syncthreads();
    if (tid < 256){
        int node = (bin<<8) + tid;
        if (node < NN){
            smax[node*2]   = fdec(sM0[tid]);
            smax[node*2+1] = fdec(sM1[tid]);
            sden[node*2]   = sS0[tid];
            sden[node*2+1] = sS1[tid];
        }
    }
}

// ================= per-src softmax stats (fallback: compact 4B entries) =================
__global__ __launch_bounds__(256) void k_src(
    const int* __restrict__ cnt_s, const int* __restrict__ off_s,
    const int* __restrict__ bkts,
    const float* __restrict__ Ps01, const float* __restrict__ Pd01,
    const float* __restrict__ We_fc, const float* __restrict__ be_fc,
    float* __restrict__ smax, float* __restrict__ sden)
{
    __shared__ float sW00, sW01, sbe0, sbe1;
    if (threadIdx.x == 0){ sW00=We_fc[0]; sW01=We_fc[1]; sbe0=be_fc[0]; sbe1=be_fc[1]; }
    __syncthreads();
    int node = blockIdx.x*32 + (threadIdx.x>>3);
    if (node >= NN) return;
    int g = threadIdx.x & 7;
    float2 p = *(const float2*)(Ps01 + node*2);
    float base0 = sbe0 + p.x, base1 = sbe1 + p.y;
    int deg = cnt_s[node], base = off_s[node];
    float m0=-1e30f, m1=-1e30f, s0=0.f, s1=0.f;
    for (int j=g; j<deg; j+=8){
        int ent = bkts[base+j];
        int d = cent_node(ent);
        float w = cent_w(ent);
        float2 q = *(const float2*)(Pd01 + d*2);
        float a0 = base0 + w*sW00 + q.x;
        float a1 = base1 + w*sW01 + q.y;
        float mn0 = fmaxf(m0, a0);
        s0 = s0*__expf(m0-mn0) + __expf(a0-mn0); m0 = mn0;
        float mn1 = fmaxf(m1, a1);
        s1 = s1*__expf(m1-mn1) + __expf(a1-mn1); m1 = mn1;
    }
    #pragma unroll
    for (int st=1; st<8; st<<=1){
        float mo = __shfl_xor(m0, st), so = __shfl_xor(s0, st);
        float mn = fmaxf(m0, mo);
        s0 = s0*__expf(m0-mn) + so*__expf(mo-mn); m0 = mn;
        mo = __shfl_xor(m1, st); so = __shfl_xor(s1, st);
        mn = fmaxf(m1, mo);
        s1 = s1*__expf(m1-mn) + so*__expf(mo-mn); m1 = mn;
    }
    if (g==0){ smax[node*2]=m0; smax[node*2+1]=m1; sden[node*2]=s0; sden[node*2+1]=s1; }
}

// ================= final edge scores (dst-sorted; Pd streams, Ps16 random) =================
__global__ __launch_bounds__(256) void k_scC2(
    const int* __restrict__ cnt_d, const int* __restrict__ off_d,
    const int2* __restrict__ bktd,
    const _Float16* __restrict__ Ps16, const float* __restrict__ Pd,
    const float* __restrict__ We_fc, const float* __restrict__ be_fc,
    const float* __restrict__ smax, const float* __restrict__ sden,
    float* __restrict__ out)
{
    __shared__ float sW0[32], sB[32];
    if (threadIdx.x < 32){ sW0[threadIdx.x]=We_fc[threadIdx.x]; sB[threadIdx.x]=be_fc[threadIdx.x]; }
    __syncthreads();
    int node = blockIdx.x*32 + (threadIdx.x>>3);
    if (node >= NN) return;
    int g = threadIdx.x & 7;
    float4 pd = *(const float4*)(Pd + (size_t)node*32 + g*4);
    float4 w0 = *(const float4*)(sW0 + g*4);
    float4 b0 = *(const float4*)(sB + g*4);
    b0.x += pd.x; b0.y += pd.y; b0.z += pd.z; b0.w += pd.w;
    int deg = cnt_d[node], base = off_d[node];
    for (int j=0; j<deg; ++j){
        int2 ent = bktd[base+j];
        int s = ent_node(ent);
        int e = ent_eid(ent);
        float w = ent_w(ent);
        h4v hv = *(const h4v*)(Ps16 + (size_t)s*32 + g*4);
        float ox = b0.x + w*w0.x + (float)hv.x;
        float oy = b0.y + w*w0.y + (float)hv.y;
        float oz = b0.z + w*w0.z + (float)hv.z;
        float ow = b0.w + w*w0.w + (float)hv.w;
        if (g == 0){
            float2 sm = *(const float2*)(smax + s*2);
            float2 sd = *(const float2*)(sden + s*2);
            ox = __expf(ox - sm.x) / (sd.x + 1e-16f);
            oy = __expf(oy - sm.y) / (sd.y + 1e-16f);
        }
        f4v ov; ov.x = ox; ov.y = oy; ov.z = oz; ov.w = ow;
        __builtin_nontemporal_store(ov, (f4v*)(out + (size_t)e*32 + g*4));
    }
}

extern "C" void kernel_launch(void* const* d_in, const int* in_sizes, int n_in,
                              void* d_out, int out_size, void* d_ws, size_t ws_size,
                              hipStream_t stream) {
    const float* x     = (const float*)d_in[0];
    const int*   ei    = (const int*)  d_in[1];
    const float* ea    = (const float*)d_in[2];
    const float* W_ee  = (const float*)d_in[3];  const float* b_ee  = (const float*)d_in[4];
    const float* W_pre = (const float*)d_in[5];  const float* b_pre = (const float*)d_in[6];
    const float* W_post= (const float*)d_in[7];  const float* b_post= (const float*)d_in[8];
    const float* W_pna = (const float*)d_in[9];  const float* b_pna = (const float*)d_in[10];
    const float* W1l   = (const float*)d_in[11]; const float* b1l   = (const float*)d_in[12];
    const float* W1r   = (const float*)d_in[13]; const float* b1r   = (const float*)d_in[14];
    const float* W1e   = (const float*)d_in[15]; const float* att1  = (const float*)d_in[16];
    const float* bias1 = (const float*)d_in[17];
    const float* W2l   = (const float*)d_in[18]; const float* b2l   = (const float*)d_in[19];
    const float* W2r   = (const float*)d_in[20]; const float* b2r   = (const float*)d_in[21];
    const float* W2e   = (const float*)d_in[22]; const float* att2  = (const float*)d_in[23];
    const float* bias2 = (const float*)d_in[24];
    const float* Wn    = (const float*)d_in[25]; const float* bn    = (const float*)d_in[26];
    const float* We_fc = (const float*)d_in[27]; const float* be_fc = (const float*)d_in[28];
    const int* src = ei;
    const int* dst = ei + NE;
    float* out = (float*)d_out;

    float* ws = (float*)d_ws;
    size_t o = 0;
    auto A = [&](size_t n){ size_t r = o; o = (o + n + 63) & ~(size_t)63; return r; };
    int*   cnt_d  = (int*)(ws + A(NN));
    int*   off_d  = (int*)(ws + A(NN));
    int*   cnt_s  = (int*)(ws + A(NN));
    int*   off_s  = (int*)(ws + A(NN));
    int*   cur_d  = (int*)(ws + A(NN));
    int*   cur_s  = (int*)(ws + A(NN));
    float* xl1    =        ws + A((size_t)NN*16);
    float* xr1    =        ws + A((size_t)NN*16);
    _Float16* xl2h = (_Float16*)(ws + A((size_t)NN*16));   // NN*32 halfs
    float* xr2    =        ws + A((size_t)NN*32);
    _Float16* Ps16 = (_Float16*)(ws + A((size_t)NN*16));   // NN*32 halfs
    float* Pd     =        ws + A((size_t)NN*32);
    float* ea_mean=        ws + A(NN);
    float* Ps01   =        ws + A((size_t)NN*2);
    float* Pd01   =        ws + A((size_t)NN*2);
    float* smax   =        ws + A((size_t)NN*2);
    float* sden   =        ws + A((size_t)NN*2);
    int*   histD  = (int*)(ws + A((size_t)NBIN*NCHUNK));
    int*   histS  = (int*)(ws + A((size_t)NBIN*NCHUNK));
    int*   baseD  = (int*)(ws + A((size_t)NBIN*NCHUNK));
    int*   baseS  = (int*)(ws + A((size_t)NBIN*NCHUNK));
    int*   binTotal  = (int*)(ws + A(2*NBIN));
    int*   binStartD = (int*)(ws + A(NBIN+1));
    int*   binStartS = (int*)(ws + A(NBIN+1));
    int2*  bufX = (int2*)(ws + A(2*(size_t)NE));   // final dst adjacency (8B)
    int*   bktsC = (int*)(ws + A((size_t)NE));     // fallback src adjacency (4B)
    size_t o_fallback = o;
    int2*  bufY = (int2*)(ws + A(2*(size_t)NE));   // coarse dst
    int2*  bufZ = (int2*)(ws + A(2*(size_t)NE));   // coarse src (persists to k_src_bins)
    size_t o_sort = o;
    bool sortmode = (ws_size >= o_sort * sizeof(float));
    if (!sortmode && ws_size < o_fallback * sizeof(float)) return;  // fail loudly

    const int BS = 256;
    const int gridE = (NE + BS - 1)/BS;
    const int gridN = (NN + BS - 1)/BS;
    const int gridO = (NN + 31)/32;

    int2* bktd = bufX;
    if (sortmode){
        k_hist<<<NCHUNK, BS, 0, stream>>>(src, dst, histD, histS);
        k_binsum<<<2*NBIN, BS, 0, stream>>>(histD, histS, binTotal);
        k_scanbins<<<1, BS, 0, stream>>>(binTotal, binStartD, binStartS);
        k_chunkpfx<<<2*NBIN, BS, 0, stream>>>(histD, histS, binStartD, binStartS, baseD, baseS);
        k_coarse<<<NCHUNK, BS, 0, stream>>>(src, dst, ea, baseD, baseS, bufY, bufZ);
        k_fine_d<<<NBIN, BS, 0, stream>>>(bufY, binStartD, bufX, cnt_d, off_d);
    } else {
        k_zero<<<gridN, BS, 0, stream>>>(cnt_d, cnt_s);
        k_count<<<gridE, BS, 0, stream>>>(src, dst, cnt_d, cnt_s);
        k_scanCSR<<<2, 1024, 0, stream>>>(cnt_d, cnt_s, off_d, cur_d, off_s, cur_s);
        k_scatter<<<gridE, BS, 0, stream>>>(src, dst, ea, cur_d, cur_s, bufX, bktsC);
    }
    k_pna<<<gridO, BS, 0, stream>>>(x, cnt_d, off_d, bktd,
                                    W_ee, b_ee, W_pre, b_pre, W_post, b_post, W_pna, b_pna,
                                    W1l, b1l, W1r, b1r, xl1, xr1, ea_mean);
    k_gat1<<<gridO, BS, 0, stream>>>(cnt_d, off_d, bktd, xl1, xr1, ea_mean,
                                     W1e, att1, bias1, W2l, b2l, W2r, b2r, xl2h, xr2);
    k_gat2<<<gridO, BS, 0, stream>>>(cnt_d, off_d, bktd, xl2h, xr2, ea_mean,
                                     W2e, att2, bias2, Wn, bn, We_fc,
                                     Ps16, Pd, Ps01, Pd01);
    if (sortmode){
        k_src_bins<<<NBIN, 1024, 0, stream>>>(bufZ, binStartS, Ps01, Pd01, We_fc, be_fc, smax, sden);
    } else {
        k_src<<<gridO, BS, 0, stream>>>(cnt_s, off_s, bktsC, Ps01, Pd01, We_fc, be_fc, smax, sden);
    }
    k_scC2<<<gridO, BS, 0, stream>>>(cnt_d, off_d, bktd, Ps16, Pd, We_fc, be_fc, smax, sden, out);
}